// Round 2
// baseline (4811.609 us; speedup 1.0000x reference)
//
#include <hip/hip_runtime.h>

typedef __attribute__((ext_vector_type(4))) float f32x4;

#define HID 780
#define NH 10
#define FO 78

// ---------------- GEMM: C[M,N] = act(A[M,K] @ B[K,N] (+bias)) ----------------
// tile 64(M) x 128(N), BK=16, 256 threads, micro 4x8. M must be multiple of 64.
template<bool RELU, bool BIAS>
__global__ __launch_bounds__(256) void gemm_f32(const float* __restrict__ A,
    const float* __restrict__ B, const float* __restrict__ bias,
    float* __restrict__ C, int M, int N, int K)
{
  __shared__ __align__(16) float As[16][68];
  __shared__ __align__(16) float Bs[16][136];
  const int tid = threadIdx.x;
  const int row0 = blockIdx.y << 6;
  const int col0 = blockIdx.x << 7;
  const int tx = tid & 15, ty = tid >> 4;
  const int akk = tid & 15, amb = tid >> 4;
  const int bn = tid & 127, bkb = tid >> 7;
  float acc[4][8];
#pragma unroll
  for (int i = 0; i < 4; ++i)
#pragma unroll
    for (int j = 0; j < 8; ++j) acc[i][j] = 0.f;

  for (int k0 = 0; k0 < K; k0 += 16) {
#pragma unroll
    for (int j = 0; j < 4; ++j) {
      int m = amb + (j << 4);
      As[akk][m] = (k0 + akk < K) ? A[(size_t)(row0 + m) * K + k0 + akk] : 0.f;
    }
#pragma unroll
    for (int j = 0; j < 8; ++j) {
      int kk = (bkb << 3) + j;
      int c = col0 + bn;
      Bs[kk][bn] = (k0 + kk < K && c < N) ? B[(size_t)(k0 + kk) * N + c] : 0.f;
    }
    __syncthreads();
#pragma unroll
    for (int kk = 0; kk < 16; ++kk) {
      f32x4 a = *(const f32x4*)&As[kk][ty << 2];
      f32x4 b0 = *(const f32x4*)&Bs[kk][tx << 3];
      f32x4 b1 = *(const f32x4*)&Bs[kk][(tx << 3) + 4];
#pragma unroll
      for (int i = 0; i < 4; ++i) {
#pragma unroll
        for (int j = 0; j < 4; ++j) {
          acc[i][j]     += a[i] * b0[j];
          acc[i][j + 4] += a[i] * b1[j];
        }
      }
    }
    __syncthreads();
  }
#pragma unroll
  for (int i = 0; i < 4; ++i) {
    int r = row0 + (ty << 2) + i;
#pragma unroll
    for (int j = 0; j < 8; ++j) {
      int c = col0 + (tx << 3) + j;
      if (c < N) {
        float v = acc[i][j];
        if (BIAS) v += bias[c];
        if (RELU) v = v > 0.f ? v : 0.f;
        C[(size_t)r * N + c] = v;
      }
    }
  }
}

// ---------------- attention per-node dots: a_src[n,h], a_dst[n,h] ----------------
__global__ __launch_bounds__(64) void att_dots(const float* __restrict__ h,
    const float* __restrict__ asv, const float* __restrict__ adv,
    float* __restrict__ a_src, float* __restrict__ a_dst)
{
  int n = blockIdx.x, lane = threadIdx.x;
  __shared__ float ss[NH], sd[NH];
  if (lane < NH) { ss[lane] = 0.f; sd[lane] = 0.f; }
  __syncthreads();
  const float* hr = h + (size_t)n * HID;
  for (int i = lane; i < HID; i += 64) {
    float v = hr[i];
    int hd = i / FO;
    atomicAdd(&ss[hd], v * asv[i]);
    atomicAdd(&sd[hd], v * adv[i]);
  }
  __syncthreads();
  if (lane < NH) { a_src[n * NH + lane] = ss[lane]; a_dst[n * NH + lane] = sd[lane]; }
}

// ---------------- CSR build (edge_index delivered as int32: src=ei[e], dst=ei[E+e]) ----------------
__global__ void count_dst(const int* __restrict__ ei, int E, int N, int* __restrict__ cnt)
{
  int e = blockIdx.x * 256 + threadIdx.x;
  if (e >= E + N) return;
  int dst = (e < E) ? ei[E + e] : (e - E);
  atomicAdd(&cnt[dst], 1);
}

__global__ __launch_bounds__(1024) void scan_dinv(const int* __restrict__ cnt,
    int* __restrict__ offs, float* __restrict__ dinv, int N)
{
  __shared__ int part[1024];
  int tid = threadIdx.x;
  int chunk = (N + 1023) >> 10;
  int b0 = tid * chunk, b1 = min(b0 + chunk, N);
  int s = 0;
  for (int i = b0; i < b1; ++i) s += cnt[i];
  part[tid] = s;
  __syncthreads();
  for (int off = 1; off < 1024; off <<= 1) {
    int v = part[tid];
    int add = (tid >= off) ? part[tid - off] : 0;
    __syncthreads();
    part[tid] = v + add;
    __syncthreads();
  }
  int run = (tid > 0) ? part[tid - 1] : 0;
  for (int i = b0; i < b1; ++i) {
    int c = cnt[i];
    offs[i] = run;
    dinv[i] = c > 0 ? rsqrtf((float)c) : 0.f;
    run += c;
  }
  if (tid == 1023) offs[N] = run;
}

__global__ void fill_csr(const int* __restrict__ ei, int E, int N,
    const int* __restrict__ offs, int* __restrict__ fillpos, int* __restrict__ csr_src)
{
  int e = blockIdx.x * 256 + threadIdx.x;
  if (e >= E + N) return;
  int src, dst;
  if (e < E) { src = ei[e]; dst = ei[E + e]; }
  else { src = e - E; dst = e - E; }
  int p = offs[dst] + atomicAdd(&fillpos[dst], 1);
  csr_src[p] = src;
}

// ---------------- GAT gather: per-dst softmax + weighted sum ----------------
__global__ __launch_bounds__(64) void gat_gather(const float* __restrict__ h,
    const float* __restrict__ a_src, const float* __restrict__ a_dst,
    const int* __restrict__ offs, const int* __restrict__ csr_src,
    const float* __restrict__ gat_bias, float* __restrict__ x1)
{
  int n = blockIdx.x, lane = threadIdx.x;
  int o0 = offs[n], deg = offs[n + 1] - o0;
  __shared__ float ad[NH], m[NH], wbuf[NH], ssum[NH];
  __shared__ unsigned mu[NH];
  if (lane < NH) { ad[lane] = a_dst[n * NH + lane]; mu[lane] = 0u; }
  __syncthreads();
  // pass 1: per-head max of leaky-relu logits (ordered-uint atomicMax)
  for (int idx = lane; idx < deg * NH; idx += 64) {
    int e = idx / NH, hd = idx - e * NH;
    int s = csr_src[o0 + e];
    float l = a_src[s * NH + hd] + ad[hd];
    l = l > 0.f ? l : 0.2f * l;
    unsigned u = __float_as_uint(l);
    u = (u & 0x80000000u) ? ~u : (u | 0x80000000u);
    atomicMax(&mu[hd], u);
  }
  __syncthreads();
  if (lane < NH) {
    unsigned u = mu[lane];
    m[lane] = __uint_as_float((u & 0x80000000u) ? (u & 0x7fffffffu) : ~u);
  }
  __syncthreads();
  // precompute head index per feature slot
  int hidx[13];
#pragma unroll
  for (int i = 0; i < 13; ++i) { int f = lane + 64 * i; hidx[i] = (f < HID) ? (f / FO) : 0; }
  float acc[13];
#pragma unroll
  for (int i = 0; i < 13; ++i) acc[i] = 0.f;
  float ssr = 0.f;  // per-head running sum (lane<10 owns head=lane)
  for (int e = 0; e < deg; ++e) {
    int s = csr_src[o0 + e];
    if (lane < NH) {
      float l = a_src[s * NH + lane] + ad[lane];
      l = l > 0.f ? l : 0.2f * l;
      float w = __expf(l - m[lane]);
      wbuf[lane] = w;
      ssr += w;
    }
    __syncthreads();
    const float* hs = h + (size_t)s * HID;
#pragma unroll
    for (int i = 0; i < 13; ++i) {
      int f = lane + 64 * i;
      if (f < HID) acc[i] += wbuf[hidx[i]] * hs[f];
    }
    __syncthreads();
  }
  if (lane < NH) ssum[lane] = ssr;
  __syncthreads();
  float* xr = x1 + (size_t)n * HID;
#pragma unroll
  for (int i = 0; i < 13; ++i) {
    int f = lane + 64 * i;
    if (f < HID) {
      float v = acc[i] / (ssum[hidx[i]] + 1e-16f) + gat_bias[f];
      xr[f] = v > 0.f ? v : 0.f;
    }
  }
}

// ---------------- GCN gather fused with global max+mean pooling ----------------
__global__ __launch_bounds__(64) void gcn_gather_pool(const float* __restrict__ h2,
    const int* __restrict__ offs, const int* __restrict__ csr_src,
    const float* __restrict__ dinv, const float* __restrict__ gcn_bias,
    const int* __restrict__ batch, float* __restrict__ g, int* __restrict__ gcnt)
{
  int n = blockIdx.x, lane = threadIdx.x;
  int o0 = offs[n], deg = offs[n + 1] - o0;
  float dn = dinv[n];
  float acc[13];
#pragma unroll
  for (int i = 0; i < 13; ++i) acc[i] = 0.f;
  for (int e = 0; e < deg; ++e) {
    int s = csr_src[o0 + e];
    float c = dn * dinv[s];
    const float* hr = h2 + (size_t)s * HID;
#pragma unroll
    for (int i = 0; i < 13; ++i) {
      int f = lane + 64 * i;
      if (f < HID) acc[i] += c * hr[f];
    }
  }
  int b = batch[n];
  float* gb = g + (size_t)b * (2 * HID);
#pragma unroll
  for (int i = 0; i < 13; ++i) {
    int f = lane + 64 * i;
    if (f < HID) {
      float v = acc[i] + gcn_bias[f];
      v = v > 0.f ? v : 0.f;
      atomicMax((unsigned*)&gb[f], __float_as_uint(v));  // v>=0 -> uint order ok
      atomicAdd(&gb[HID + f], v);
    }
  }
  if (lane == 0) atomicAdd(&gcnt[b], 1);
}

__global__ void gmean_norm(float* __restrict__ g, const int* __restrict__ gcnt)
{
  int b = blockIdx.x, t = threadIdx.x;
  float inv = 1.f / fmaxf((float)gcnt[b], 1.f);
  for (int f = t; f < HID; f += 256) g[(size_t)b * (2 * HID) + HID + f] *= inv;
}

// ---------------- protein branch: A[b,v,o*8+k] = sum_{i: t=v} W[o,i,k] ----------------
__global__ __launch_bounds__(256) void build_A(const int* __restrict__ tgt,
    const float* __restrict__ W, float* __restrict__ Aout)
{
  int b = blockIdx.x, tid = threadIdx.x;
  __shared__ unsigned char tl[1000];
  __shared__ int vcnt[26], voff[27], vfill[26];
  __shared__ short vlist[1000];
  if (tid < 26) { vcnt[tid] = 0; vfill[tid] = 0; }
  __syncthreads();
  for (int i = tid; i < 1000; i += 256) {
    int v = tgt[b * 1000 + i];
    tl[i] = (unsigned char)v;
    atomicAdd(&vcnt[v], 1);
  }
  __syncthreads();
  if (tid == 0) { int r = 0; for (int v = 0; v < 26; ++v) { voff[v] = r; r += vcnt[v]; } voff[26] = r; }
  __syncthreads();
  for (int i = tid; i < 1000; i += 256) {
    int v = tl[i];
    int p = voff[v] + atomicAdd(&vfill[v], 1);
    vlist[p] = (short)i;
  }
  __syncthreads();
  int o = tid >> 3, k = tid & 7;
  const float* Wok = W + o * 8000 + k;
  float* Ao = Aout + (size_t)b * 6656;
  for (int v = 0; v < 26; ++v) {
    float a = 0.f;
    int s = voff[v], e = voff[v + 1];
    for (int j = s; j < e; ++j) a += Wok[(int)vlist[j] * 8];
    Ao[v * 256 + tid] = a;
  }
}

// conv[b,o,l] = convb[o] + sum_v sum_k A[b,v,o*8+k] * emb[v,l+k]
__global__ __launch_bounds__(256) void conv_xt(const float* __restrict__ Aall,
    const float* __restrict__ embed, const float* __restrict__ cbias,
    float* __restrict__ out)
{
  int b = blockIdx.x, tid = threadIdx.x;
  __shared__ __align__(16) float Al[6656];
  __shared__ __align__(16) float el[3360];
  const float* Ab = Aall + (size_t)b * 6656;
  for (int i = tid; i < 6656; i += 256) Al[i] = Ab[i];
  for (int i = tid; i < 3328; i += 256) el[i] = embed[i];
  if (tid < 32) el[3328 + tid] = 0.f;
  __syncthreads();
  for (int grp = tid; grp < 512; grp += 256) {
    int o = grp >> 4;
    int l0 = (grp & 15) << 3;
    float cb = cbias[o];
    float acc[8];
#pragma unroll
    for (int j = 0; j < 8; ++j) acc[j] = cb;
    for (int v = 0; v < 26; ++v) {
      const float* ap = &Al[v * 256 + (o << 3)];
      f32x4 a0 = *(const f32x4*)ap;
      f32x4 a1 = *(const f32x4*)(ap + 4);
      const float* ep = &el[v * 128 + l0];
      f32x4 e0 = *(const f32x4*)ep;
      f32x4 e1 = *(const f32x4*)(ep + 4);
      f32x4 e2 = *(const f32x4*)(ep + 8);
      f32x4 e3 = *(const f32x4*)(ep + 12);
      float a[8] = { a0[0], a0[1], a0[2], a0[3], a1[0], a1[1], a1[2], a1[3] };
      float e[16] = { e0[0], e0[1], e0[2], e0[3], e1[0], e1[1], e1[2], e1[3],
                      e2[0], e2[1], e2[2], e2[3], e3[0], e3[1], e3[2], e3[3] };
#pragma unroll
      for (int k = 0; k < 8; ++k)
#pragma unroll
        for (int j = 0; j < 8; ++j) acc[j] += a[k] * e[k + j];
    }
    int base = o * 121 + l0;
#pragma unroll
    for (int j = 0; j < 8; ++j)
      if (l0 + j < 121) out[(size_t)b * 3872 + base + j] = acc[j];
  }
}

// ---------------- joint head helpers ----------------
__global__ void concat_xc(const float* __restrict__ g2, const float* __restrict__ xt,
                          float* __restrict__ xc)
{
  int b = blockIdx.x, t = threadIdx.x;
  xc[(size_t)b * 256 + t] = (t < 128) ? g2[(size_t)b * 128 + t] : xt[(size_t)b * 128 + t - 128];
}

__global__ __launch_bounds__(256) void final_out(const float* __restrict__ z2,
    const float* __restrict__ W, const float* __restrict__ bias, float* __restrict__ out)
{
  int row = blockIdx.x * 4 + (threadIdx.x >> 6);
  int lane = threadIdx.x & 63;
  const float* zr = z2 + (size_t)row * 512;
  float s = 0.f;
  for (int i = lane; i < 512; i += 64) s += zr[i] * W[i];
#pragma unroll
  for (int off = 32; off > 0; off >>= 1) s += __shfl_down(s, off, 64);
  if (lane == 0) out[row] = s + bias[0];
}

// ---------------- launch ----------------
extern "C" void kernel_launch(void* const* d_in, const int* in_sizes, int n_in,
                              void* d_out, int out_size, void* d_ws, size_t ws_size,
                              hipStream_t stream)
{
  const float* x        = (const float*)d_in[0];
  const int*   ei       = (const int*)d_in[1];   // int32: src=ei[0..E), dst=ei[E..2E)
  const int*   batch    = (const int*)d_in[2];   // int32 [N]
  const int*   tgt      = (const int*)d_in[3];   // int32 [B*1000]
  const float* gat_W    = (const float*)d_in[4];
  const float* att_src  = (const float*)d_in[5];
  const float* att_dst  = (const float*)d_in[6];
  const float* gat_bias = (const float*)d_in[7];
  const float* gcn_W    = (const float*)d_in[8];
  const float* gcn_bias = (const float*)d_in[9];
  const float* fcg1_W   = (const float*)d_in[10];
  const float* fcg1_b   = (const float*)d_in[11];
  const float* fcg2_W   = (const float*)d_in[12];
  const float* fcg2_b   = (const float*)d_in[13];
  const float* embed    = (const float*)d_in[14];
  const float* convW    = (const float*)d_in[15];
  const float* convb    = (const float*)d_in[16];
  const float* fc1xt_W  = (const float*)d_in[17];
  const float* fc1xt_b  = (const float*)d_in[18];
  const float* fc1_W    = (const float*)d_in[19];
  const float* fc1_b    = (const float*)d_in[20];
  const float* fc2_W    = (const float*)d_in[21];
  const float* fc2_b    = (const float*)d_in[22];
  const float* out_W    = (const float*)d_in[23];
  const float* out_b    = (const float*)d_in[24];

  const int N = in_sizes[0] / FO;      // 40960
  const int E = in_sizes[1] / 2;       // 163840
  const int B = in_sizes[3] / 1000;    // 1024
  const int ET = E + N;

  char* ws = (char*)d_ws;
  size_t off = 0;
  auto alloc = [&](size_t bytes) -> char* {
    char* p = ws + off;
    off = (off + bytes + 255) & ~(size_t)255;
    return p;
  };
  float* buf0   = (float*)alloc((size_t)N * HID * 4);   // h, then h2, then protein
  float* buf1   = (float*)alloc((size_t)N * HID * 4);   // x1, then MLP scratch
  float* a_src  = (float*)alloc((size_t)N * NH * 4);
  float* a_dst  = (float*)alloc((size_t)N * NH * 4);
  int*   cnt    = (int*)alloc((size_t)N * 4);
  int*   offs   = (int*)alloc((size_t)(N + 1) * 4);
  int*   fillp  = (int*)alloc((size_t)N * 4);
  int*   csr    = (int*)alloc((size_t)ET * 4);
  float* dinv   = (float*)alloc((size_t)N * 4);
  float* g      = (float*)alloc((size_t)B * 2 * HID * 4);
  int*   gcnt   = (int*)alloc((size_t)B * 4);

  // aliases into buf0 (valid after gcn_gather_pool)
  float* Aprot    = buf0;
  float* convflat = buf0 + (size_t)6656 * B;
  // aliases into buf1 (valid after gemm h2)
  float* g1out = buf1;
  float* g2out = buf1 + 1600000;
  float* xtb   = buf1 + 1800000;
  float* xc    = buf1 + 2000000;
  float* z1    = buf1 + 2300000;
  float* z2    = buf1 + 3400000;

  hipMemsetAsync(cnt, 0, (size_t)N * 4, stream);
  hipMemsetAsync(fillp, 0, (size_t)N * 4, stream);
  hipMemsetAsync(g, 0, (size_t)B * 2 * HID * 4, stream);
  hipMemsetAsync(gcnt, 0, (size_t)B * 4, stream);

  // h = x @ gat_W
  gemm_f32<false, false><<<dim3((HID + 127) / 128, N / 64), 256, 0, stream>>>(
      x, gat_W, nullptr, buf0, N, HID, FO);
  att_dots<<<N, 64, 0, stream>>>(buf0, att_src, att_dst, a_src, a_dst);

  int egrid = (ET + 255) / 256;
  count_dst<<<egrid, 256, 0, stream>>>(ei, E, N, cnt);
  scan_dinv<<<1, 1024, 0, stream>>>(cnt, offs, dinv, N);
  fill_csr<<<egrid, 256, 0, stream>>>(ei, E, N, offs, fillp, csr);

  gat_gather<<<N, 64, 0, stream>>>(buf0, a_src, a_dst, offs, csr, gat_bias, buf1);

  // h2 = x1 @ gcn_W
  gemm_f32<false, false><<<dim3((HID + 127) / 128, N / 64), 256, 0, stream>>>(
      buf1, gcn_W, nullptr, buf0, N, HID, HID);

  gcn_gather_pool<<<N, 64, 0, stream>>>(buf0, offs, csr, dinv, gcn_bias, batch, g, gcnt);
  gmean_norm<<<B, 256, 0, stream>>>(g, gcnt);

  // protein branch (buf0 free now)
  build_A<<<B, 256, 0, stream>>>(tgt, convW, Aprot);
  conv_xt<<<B, 256, 0, stream>>>(Aprot, embed, convb, convflat);
  gemm_f32<false, true><<<dim3(1, B / 64), 256, 0, stream>>>(
      convflat, fc1xt_W, fc1xt_b, xtb, B, 128, 3872);

  // graph head
  gemm_f32<true, true><<<dim3((1500 + 127) / 128, B / 64), 256, 0, stream>>>(
      g, fcg1_W, fcg1_b, g1out, B, 1500, 2 * HID);
  gemm_f32<false, true><<<dim3(1, B / 64), 256, 0, stream>>>(
      g1out, fcg2_W, fcg2_b, g2out, B, 128, 1500);

  // joint head
  concat_xc<<<B, 256, 0, stream>>>(g2out, xtb, xc);
  gemm_f32<true, true><<<dim3(8, B / 64), 256, 0, stream>>>(
      xc, fc1_W, fc1_b, z1, B, 1024, 256);
  gemm_f32<true, true><<<dim3(4, B / 64), 256, 0, stream>>>(
      z1, fc2_W, fc2_b, z2, B, 512, 1024);
  final_out<<<B / 4, 256, 0, stream>>>(z2, out_W, out_b, (float*)d_out);
}

// Round 4
// 3068.090 us; speedup vs baseline: 1.5683x; 1.5683x over previous
//
#include <hip/hip_runtime.h>

typedef __attribute__((ext_vector_type(4))) float f32x4;
typedef __attribute__((ext_vector_type(8))) short bf16x8;
typedef unsigned short u16;

#define HID 780
#define NH 10
#define FO 78

__device__ inline u16 f2b(float f) {  // fp32 -> bf16 RNE
  unsigned u = __float_as_uint(f);
  unsigned r = (u + 0x7fff + ((u >> 16) & 1)) >> 16;
  return (u16)r;
}

// ---------------- bf16 MFMA GEMM: C[M,N] = A[M,KP] @ BT[N,KP]^T ----------------
// A row-major bf16 [M][KP], BT row-major bf16 [NP][KP] (B transposed, zero-padded),
// KP % 32 == 0, M % 128 == 0, NP >= ceil(N/128)*128. Tile 128x128, 4 waves.
__global__ __launch_bounds__(256) void gemm_mfma(const u16* __restrict__ A,
    const u16* __restrict__ BT, float* __restrict__ C, int M, int N, int KP)
{
  __shared__ u16 As[128 * 40];
  __shared__ u16 Bs[128 * 40];
  const int tid = threadIdx.x;
  const int row0 = blockIdx.y << 7, col0 = blockIdx.x << 7;
  const int l = tid & 63, wid = tid >> 6;
  const int wr = wid >> 1, wc = wid & 1;
  const int lr = l & 15, lk = l >> 4;
  f32x4 acc[4][4];
#pragma unroll
  for (int i = 0; i < 4; ++i)
#pragma unroll
    for (int j = 0; j < 4; ++j) acc[i][j] = (f32x4){0.f, 0.f, 0.f, 0.f};

  for (int k0 = 0; k0 < KP; k0 += 32) {
    __syncthreads();
#pragma unroll
    for (int i = 0; i < 2; ++i) {
      int c = tid + (i << 8);          // 0..511
      int row = c >> 2, off = c & 3;   // 128 rows x 4 chunks of 8 bf16
      *(uint4*)&As[row * 40 + off * 8] =
          *(const uint4*)(A + (size_t)(row0 + row) * KP + k0 + off * 8);
      *(uint4*)&Bs[row * 40 + off * 8] =
          *(const uint4*)(BT + (size_t)(col0 + row) * KP + k0 + off * 8);
    }
    __syncthreads();
    bf16x8 af[4], bfr[4];
#pragma unroll
    for (int fm = 0; fm < 4; ++fm)
      af[fm] = *(const bf16x8*)&As[(wr * 64 + fm * 16 + lr) * 40 + lk * 8];
#pragma unroll
    for (int fn = 0; fn < 4; ++fn)
      bfr[fn] = *(const bf16x8*)&Bs[(wc * 64 + fn * 16 + lr) * 40 + lk * 8];
#pragma unroll
    for (int fm = 0; fm < 4; ++fm)
#pragma unroll
      for (int fn = 0; fn < 4; ++fn)
        acc[fm][fn] = __builtin_amdgcn_mfma_f32_16x16x32_bf16(af[fm], bfr[fn], acc[fm][fn], 0, 0, 0);
  }
#pragma unroll
  for (int fm = 0; fm < 4; ++fm)
#pragma unroll
    for (int fn = 0; fn < 4; ++fn) {
      int col = col0 + wc * 64 + fn * 16 + lr;
      if (col < N) {
        f32x4 v = acc[fm][fn];
#pragma unroll
        for (int j = 0; j < 4; ++j)
          C[(size_t)(row0 + wr * 64 + fm * 16 + lk * 4 + j) * N + col] = v[j];
      }
    }
}

// ---------------- conversions ----------------
__global__ void conv_x_bf16(const float* __restrict__ x, u16* __restrict__ xb, int M)
{
  int idx = blockIdx.x * 256 + threadIdx.x;
  if (idx >= M * 96) return;
  int r = idx / 96, c = idx - r * 96;
  xb[idx] = (c < FO) ? f2b(x[(size_t)r * FO + c]) : (u16)0;
}

// WT[n][k] (NP x KP) = bf16(W[k][n]) zero-padded
__global__ void conv_wT_bf16(const float* __restrict__ W, u16* __restrict__ WT,
                             int K, int N, int KP, int NP)
{
  int idx = blockIdx.x * 256 + threadIdx.x;
  if (idx >= NP * KP) return;
  int n = idx / KP, k = idx - n * KP;
  WT[idx] = (n < N && k < K) ? f2b(W[(size_t)k * N + n]) : (u16)0;
}

// ---------------- GEMM fp32 (small matrices): C = act(A@B + bias) ----------------
template<bool RELU, bool BIAS>
__global__ __launch_bounds__(256) void gemm_f32(const float* __restrict__ A,
    const float* __restrict__ B, const float* __restrict__ bias,
    float* __restrict__ C, int M, int N, int K)
{
  __shared__ __align__(16) float As[16][68];
  __shared__ __align__(16) float Bs[16][136];
  const int tid = threadIdx.x;
  const int row0 = blockIdx.y << 6;
  const int col0 = blockIdx.x << 7;
  const int tx = tid & 15, ty = tid >> 4;
  const int akk = tid & 15, amb = tid >> 4;
  const int bn = tid & 127, bkb = tid >> 7;
  float acc[4][8];
#pragma unroll
  for (int i = 0; i < 4; ++i)
#pragma unroll
    for (int j = 0; j < 8; ++j) acc[i][j] = 0.f;

  for (int k0 = 0; k0 < K; k0 += 16) {
#pragma unroll
    for (int j = 0; j < 4; ++j) {
      int m = amb + (j << 4);
      As[akk][m] = (k0 + akk < K) ? A[(size_t)(row0 + m) * K + k0 + akk] : 0.f;
    }
#pragma unroll
    for (int j = 0; j < 8; ++j) {
      int kk = (bkb << 3) + j;
      int c = col0 + bn;
      Bs[kk][bn] = (k0 + kk < K && c < N) ? B[(size_t)(k0 + kk) * N + c] : 0.f;
    }
    __syncthreads();
#pragma unroll
    for (int kk = 0; kk < 16; ++kk) {
      f32x4 a = *(const f32x4*)&As[kk][ty << 2];
      f32x4 b0 = *(const f32x4*)&Bs[kk][tx << 3];
      f32x4 b1 = *(const f32x4*)&Bs[kk][(tx << 3) + 4];
#pragma unroll
      for (int i = 0; i < 4; ++i) {
#pragma unroll
        for (int j = 0; j < 4; ++j) {
          acc[i][j]     += a[i] * b0[j];
          acc[i][j + 4] += a[i] * b1[j];
        }
      }
    }
    __syncthreads();
  }
#pragma unroll
  for (int i = 0; i < 4; ++i) {
    int r = row0 + (ty << 2) + i;
#pragma unroll
    for (int j = 0; j < 8; ++j) {
      int c = col0 + (tx << 3) + j;
      if (c < N) {
        float v = acc[i][j];
        if (BIAS) v += bias[c];
        if (RELU) v = v > 0.f ? v : 0.f;
        C[(size_t)r * N + c] = v;
      }
    }
  }
}

// ---------------- attention per-node dots ----------------
__global__ __launch_bounds__(64) void att_dots(const float* __restrict__ h,
    const float* __restrict__ asv, const float* __restrict__ adv,
    float* __restrict__ a_src, float* __restrict__ a_dst)
{
  int n = blockIdx.x, lane = threadIdx.x;
  __shared__ float ss[NH], sd[NH];
  if (lane < NH) { ss[lane] = 0.f; sd[lane] = 0.f; }
  __syncthreads();
  const float* hr = h + (size_t)n * HID;
  for (int i = lane; i < HID; i += 64) {
    float v = hr[i];
    int hd = i / FO;
    atomicAdd(&ss[hd], v * asv[i]);
    atomicAdd(&sd[hd], v * adv[i]);
  }
  __syncthreads();
  if (lane < NH) { a_src[n * NH + lane] = ss[lane]; a_dst[n * NH + lane] = sd[lane]; }
}

// ---------------- CSR build ----------------
__global__ void count_dst(const int* __restrict__ ei, int E, int N, int* __restrict__ cnt)
{
  int e = blockIdx.x * 256 + threadIdx.x;
  if (e >= E + N) return;
  int dst = (e < E) ? ei[E + e] : (e - E);
  atomicAdd(&cnt[dst], 1);
}

__global__ __launch_bounds__(1024) void scan_dinv(const int* __restrict__ cnt,
    int* __restrict__ offs, float* __restrict__ dinv, int N)
{
  __shared__ int part[1024];
  int tid = threadIdx.x;
  int chunk = (N + 1023) >> 10;
  int b0 = tid * chunk, b1 = min(b0 + chunk, N);
  int s = 0;
  for (int i = b0; i < b1; ++i) s += cnt[i];
  part[tid] = s;
  __syncthreads();
  for (int off = 1; off < 1024; off <<= 1) {
    int v = part[tid];
    int add = (tid >= off) ? part[tid - off] : 0;
    __syncthreads();
    part[tid] = v + add;
    __syncthreads();
  }
  int run = (tid > 0) ? part[tid - 1] : 0;
  for (int i = b0; i < b1; ++i) {
    int c = cnt[i];
    offs[i] = run;
    dinv[i] = c > 0 ? rsqrtf((float)c) : 0.f;
    run += c;
  }
  if (tid == 1023) offs[N] = run;
}

__global__ void fill_csr(const int* __restrict__ ei, int E, int N,
    const int* __restrict__ offs, int* __restrict__ fillpos, int* __restrict__ csr_src)
{
  int e = blockIdx.x * 256 + threadIdx.x;
  if (e >= E + N) return;
  int src, dst;
  if (e < E) { src = ei[e]; dst = ei[E + e]; }
  else { src = e - E; dst = e - E; }
  int p = offs[dst] + atomicAdd(&fillpos[dst], 1);
  csr_src[p] = src;
}

// ---------------- GAT gather (chunked softmax), writes x1 as bf16 [N][800] ----------------
#define CH 48
__global__ __launch_bounds__(64) void gat_gather(const float* __restrict__ h,
    const float* __restrict__ a_src, const float* __restrict__ a_dst,
    const int* __restrict__ offs, const int* __restrict__ csr_src,
    const float* __restrict__ gat_bias, u16* __restrict__ x1b)
{
  int n = blockIdx.x, lane = threadIdx.x;
  int o0 = offs[n], deg = offs[n + 1] - o0;
  __shared__ float ad[NH], m[NH], ssum[NH];
  __shared__ float wbuf[CH][NH];
  __shared__ int slist[CH];
  __shared__ unsigned mu[NH];
  if (lane < NH) { ad[lane] = a_dst[n * NH + lane]; mu[lane] = 0u; ssum[lane] = 0.f; }
  __syncthreads();
  // pass 1: per-head max of leaky-relu logits
  for (int idx = lane; idx < deg * NH; idx += 64) {
    int e = idx / NH, hd = idx - e * NH;
    int s = csr_src[o0 + e];
    float l = a_src[s * NH + hd] + ad[hd];
    l = l > 0.f ? l : 0.2f * l;
    unsigned u = __float_as_uint(l);
    u = (u & 0x80000000u) ? ~u : (u | 0x80000000u);
    atomicMax(&mu[hd], u);
  }
  __syncthreads();
  if (lane < NH) {
    unsigned u = mu[lane];
    m[lane] = __uint_as_float((u & 0x80000000u) ? (u & 0x7fffffffu) : ~u);
  }
  int hidx[13];
#pragma unroll
  for (int i = 0; i < 13; ++i) { int f = lane + 64 * i; hidx[i] = (f < HID) ? (f / FO) : 0; }
  float acc[13];
#pragma unroll
  for (int i = 0; i < 13; ++i) acc[i] = 0.f;

  for (int e0 = 0; e0 < deg; e0 += CH) {
    int ce = min(CH, deg - e0);
    __syncthreads();  // protect wbuf/slist reuse + ensure m visible (first iter)
    for (int idx = lane; idx < ce * NH; idx += 64) {
      int e = idx / NH, hd = idx - e * NH;
      int s = csr_src[o0 + e0 + e];
      float l = a_src[s * NH + hd] + ad[hd];
      l = l > 0.f ? l : 0.2f * l;
      float w = __expf(l - m[hd]);
      wbuf[e][hd] = w;
      atomicAdd(&ssum[hd], w);
    }
    for (int idx = lane; idx < ce; idx += 64) slist[idx] = csr_src[o0 + e0 + idx];
    __syncthreads();
    for (int e = 0; e < ce; ++e) {
      const float* hs = h + (size_t)slist[e] * HID;
#pragma unroll
      for (int i = 0; i < 13; ++i) {
        int f = lane + 64 * i;
        if (f < HID) acc[i] += wbuf[e][hidx[i]] * hs[f];
      }
    }
  }
  __syncthreads();
#pragma unroll
  for (int i = 0; i < 13; ++i) {
    int f = lane + 64 * i;
    if (f < HID) {
      float v = acc[i] / (ssum[hidx[i]] + 1e-16f) + gat_bias[f];
      x1b[(size_t)n * 800 + f] = f2b(v > 0.f ? v : 0.f);
    }
  }
  if (lane < 20) x1b[(size_t)n * 800 + HID + lane] = 0;
}

// ---------------- GCN gather fused with per-graph pooling ----------------
// One block per graph (batch sorted => contiguous node range). 4 wave-groups
// stride over the graph's nodes; per-feature max/sum combined in LDS.
__global__ __launch_bounds__(256) void gcn_pool(const float* __restrict__ h2,
    const int* __restrict__ offs, const int* __restrict__ csr_src,
    const float* __restrict__ dinv, const float* __restrict__ gcn_bias,
    const int* __restrict__ batch, int N, float* __restrict__ g)
{
  int gi = blockIdx.x, tid = threadIdx.x;
  int grp = tid >> 6, lane = tid & 63;
  __shared__ int se[2];
  __shared__ float smx[HID];
  __shared__ float ssm[HID];
  for (int f = tid; f < HID; f += 256) { smx[f] = 0.f; ssm[f] = 0.f; }
  if (tid < 2) {
    int target = gi + tid;
    int lo = 0, hi = N;
    while (lo < hi) { int mid = (lo + hi) >> 1; if (batch[mid] < target) lo = mid + 1; else hi = mid; }
    se[tid] = lo;
  }
  __syncthreads();
  int s = se[0], e = se[1];
  float mx[13], sm[13];
#pragma unroll
  for (int i = 0; i < 13; ++i) { mx[i] = 0.f; sm[i] = 0.f; }
  for (int n = s + grp; n < e; n += 4) {
    int o0 = offs[n], deg = offs[n + 1] - o0;
    float dn = dinv[n];
    float acc[13];
#pragma unroll
    for (int i = 0; i < 13; ++i) acc[i] = 0.f;
    for (int ed = 0; ed < deg; ++ed) {
      int src = csr_src[o0 + ed];
      float c = dn * dinv[src];
      const float* hr = h2 + (size_t)src * HID;
#pragma unroll
      for (int i = 0; i < 13; ++i) {
        int f = lane + 64 * i;
        if (f < HID) acc[i] += c * hr[f];
      }
    }
#pragma unroll
    for (int i = 0; i < 13; ++i) {
      int f = lane + 64 * i;
      if (f < HID) {
        float v = acc[i] + gcn_bias[f];
        v = v > 0.f ? v : 0.f;   // relu => v >= 0
        mx[i] = fmaxf(mx[i], v);
        sm[i] += v;
      }
    }
  }
  // combine the 4 groups (values >= 0 so uint-ordered atomicMax is valid)
#pragma unroll
  for (int i = 0; i < 13; ++i) {
    int f = lane + 64 * i;
    if (f < HID) {
      atomicMax((unsigned*)&smx[f], __float_as_uint(mx[i]));
      atomicAdd(&ssm[f], sm[i]);
    }
  }
  __syncthreads();
  float inv = 1.f / fmaxf((float)(e - s), 1.f);
  for (int f = tid; f < HID; f += 256) {
    g[(size_t)gi * (2 * HID) + f] = smx[f];
    g[(size_t)gi * (2 * HID) + HID + f] = ssm[f] * inv;
  }
}

// ---------------- protein branch ----------------
__global__ __launch_bounds__(256) void build_A(const int* __restrict__ tgt,
    const float* __restrict__ W, float* __restrict__ Aout)
{
  int b = blockIdx.x, tid = threadIdx.x;
  __shared__ unsigned char tl[1000];
  __shared__ int vcnt[26], voff[27], vfill[26];
  __shared__ short vlist[1000];
  if (tid < 26) { vcnt[tid] = 0; vfill[tid] = 0; }
  __syncthreads();
  for (int i = tid; i < 1000; i += 256) {
    int v = tgt[b * 1000 + i];
    tl[i] = (unsigned char)v;
    atomicAdd(&vcnt[v], 1);
  }
  __syncthreads();
  if (tid == 0) { int r = 0; for (int v = 0; v < 26; ++v) { voff[v] = r; r += vcnt[v]; } voff[26] = r; }
  __syncthreads();
  for (int i = tid; i < 1000; i += 256) {
    int v = tl[i];
    int p = voff[v] + atomicAdd(&vfill[v], 1);
    vlist[p] = (short)i;
  }
  __syncthreads();
  int o = tid >> 3, k = tid & 7;
  const float* Wok = W + o * 8000 + k;
  float* Ao = Aout + (size_t)b * 6656;
  for (int v = 0; v < 26; ++v) {
    float a = 0.f;
    int s = voff[v], e = voff[v + 1];
    for (int j = s; j < e; ++j) a += Wok[(int)vlist[j] * 8];
    Ao[v * 256 + tid] = a;
  }
}

__global__ __launch_bounds__(256) void conv_xt(const float* __restrict__ Aall,
    const float* __restrict__ embed, const float* __restrict__ cbias,
    float* __restrict__ out)
{
  int b = blockIdx.x, tid = threadIdx.x;
  __shared__ __align__(16) float Al[6656];
  __shared__ __align__(16) float el[3360];
  const float* Ab = Aall + (size_t)b * 6656;
  for (int i = tid; i < 6656; i += 256) Al[i] = Ab[i];
  for (int i = tid; i < 3328; i += 256) el[i] = embed[i];
  if (tid < 32) el[3328 + tid] = 0.f;
  __syncthreads();
  for (int grp = tid; grp < 512; grp += 256) {
    int o = grp >> 4;
    int l0 = (grp & 15) << 3;
    float cb = cbias[o];
    float acc[8];
#pragma unroll
    for (int j = 0; j < 8; ++j) acc[j] = cb;
    for (int v = 0; v < 26; ++v) {
      const float* ap = &Al[v * 256 + (o << 3)];
      f32x4 a0 = *(const f32x4*)ap;
      f32x4 a1 = *(const f32x4*)(ap + 4);
      const float* ep = &el[v * 128 + l0];
      f32x4 e0 = *(const f32x4*)ep;
      f32x4 e1 = *(const f32x4*)(ep + 4);
      f32x4 e2 = *(const f32x4*)(ep + 8);
      f32x4 e3 = *(const f32x4*)(ep + 12);
      float a[8] = { a0[0], a0[1], a0[2], a0[3], a1[0], a1[1], a1[2], a1[3] };
      float e[16] = { e0[0], e0[1], e0[2], e0[3], e1[0], e1[1], e1[2], e1[3],
                      e2[0], e2[1], e2[2], e2[3], e3[0], e3[1], e3[2], e3[3] };
#pragma unroll
      for (int k = 0; k < 8; ++k)
#pragma unroll
        for (int j = 0; j < 8; ++j) acc[j] += a[k] * e[k + j];
    }
    int base = o * 121 + l0;
#pragma unroll
    for (int j = 0; j < 8; ++j)
      if (l0 + j < 121) out[(size_t)b * 3872 + base + j] = acc[j];
  }
}

// ---------------- joint head helpers ----------------
__global__ void concat_xc(const float* __restrict__ g2, const float* __restrict__ xt,
                          float* __restrict__ xc)
{
  int b = blockIdx.x, t = threadIdx.x;
  xc[(size_t)b * 256 + t] = (t < 128) ? g2[(size_t)b * 128 + t] : xt[(size_t)b * 128 + t - 128];
}

__global__ __launch_bounds__(256) void final_out(const float* __restrict__ z2,
    const float* __restrict__ W, const float* __restrict__ bias, float* __restrict__ out)
{
  int row = blockIdx.x * 4 + (threadIdx.x >> 6);
  int lane = threadIdx.x & 63;
  const float* zr = z2 + (size_t)row * 512;
  float s = 0.f;
  for (int i = lane; i < 512; i += 64) s += zr[i] * W[i];
#pragma unroll
  for (int off = 32; off > 0; off >>= 1) s += __shfl_down(s, off, 64);
  if (lane == 0) out[row] = s + bias[0];
}

// ---------------- launch ----------------
extern "C" void kernel_launch(void* const* d_in, const int* in_sizes, int n_in,
                              void* d_out, int out_size, void* d_ws, size_t ws_size,
                              hipStream_t stream)
{
  const float* x        = (const float*)d_in[0];
  const int*   ei       = (const int*)d_in[1];
  const int*   batch    = (const int*)d_in[2];
  const int*   tgt      = (const int*)d_in[3];
  const float* gat_W    = (const float*)d_in[4];
  const float* att_src  = (const float*)d_in[5];
  const float* att_dst  = (const float*)d_in[6];
  const float* gat_bias = (const float*)d_in[7];
  const float* gcn_W    = (const float*)d_in[8];
  const float* gcn_bias = (const float*)d_in[9];
  const float* fcg1_W   = (const float*)d_in[10];
  const float* fcg1_b   = (const float*)d_in[11];
  const float* fcg2_W   = (const float*)d_in[12];
  const float* fcg2_b   = (const float*)d_in[13];
  const float* embed    = (const float*)d_in[14];
  const float* convW    = (const float*)d_in[15];
  const float* convb    = (const float*)d_in[16];
  const float* fc1xt_W  = (const float*)d_in[17];
  const float* fc1xt_b  = (const float*)d_in[18];
  const float* fc1_W    = (const float*)d_in[19];
  const float* fc1_b    = (const float*)d_in[20];
  const float* fc2_W    = (const float*)d_in[21];
  const float* fc2_b    = (const float*)d_in[22];
  const float* out_W    = (const float*)d_in[23];
  const float* out_b    = (const float*)d_in[24];

  const int N = in_sizes[0] / FO;      // 40960
  const int E = in_sizes[1] / 2;       // 163840
  const int B = in_sizes[3] / 1000;    // 1024
  const int ET = E + N;

  char* ws = (char*)d_ws;
  size_t off = 0;
  auto alloc = [&](size_t bytes) -> char* {
    char* p = ws + off;
    off = (off + bytes + 255) & ~(size_t)255;
    return p;
  };
  // buf0: h (f32 [N][780]) -> h2 -> Aprot/convflat.  127.8 MB
  float* buf0  = (float*)alloc((size_t)N * HID * 4);
  // buf1: xb (bf16 [N][96]) -> x1b (bf16 [N][800]) -> MLP scratch.  65.6 MB
  float* buf1  = (float*)alloc((size_t)N * 800 * 2);
  u16*   wt1   = (u16*)alloc((size_t)896 * 96 * 2);
  u16*   wt2   = (u16*)alloc((size_t)896 * 800 * 2);
  float* a_src = (float*)alloc((size_t)N * NH * 4);
  float* a_dst = (float*)alloc((size_t)N * NH * 4);
  int*   cnt   = (int*)alloc((size_t)N * 4);
  int*   offs  = (int*)alloc((size_t)(N + 1) * 4);
  int*   fillp = (int*)alloc((size_t)N * 4);
  int*   csr   = (int*)alloc((size_t)ET * 4);
  float* dinv  = (float*)alloc((size_t)N * 4);
  float* g     = (float*)alloc((size_t)B * 2 * HID * 4);
  // total ~208 MB (fits known-good 256 MiB workspace)

  u16*   xb    = (u16*)buf1;                 // dead after gemm #1
  u16*   x1b   = (u16*)buf1;                 // written by gat_gather, read by gemm #2
  float* Aprot    = buf0;                    // after gcn_pool, buf0 free
  float* convflat = buf0 + (size_t)6656 * B;
  float* g1out = buf1;                       // after gemm #2, buf1 free
  float* g2out = buf1 + 1600000;
  float* xtb   = buf1 + 1800000;
  float* xc    = buf1 + 2000000;
  float* z1    = buf1 + 2300000;
  float* z2    = buf1 + 3400000;

  hipMemsetAsync(cnt, 0, (size_t)N * 4, stream);
  hipMemsetAsync(fillp, 0, (size_t)N * 4, stream);

  // conversions
  conv_x_bf16<<<(N * 96 + 255) / 256, 256, 0, stream>>>(x, xb, N);
  conv_wT_bf16<<<(896 * 96 + 255) / 256, 256, 0, stream>>>(gat_W, wt1, FO, HID, 96, 896);
  conv_wT_bf16<<<(896 * 800 + 255) / 256, 256, 0, stream>>>(gcn_W, wt2, HID, HID, 800, 896);

  // h = x @ gat_W  (MFMA)
  gemm_mfma<<<dim3(7, N / 128), 256, 0, stream>>>(xb, wt1, buf0, N, HID, 96);
  att_dots<<<N, 64, 0, stream>>>(buf0, att_src, att_dst, a_src, a_dst);

  int egrid = (ET + 255) / 256;
  count_dst<<<egrid, 256, 0, stream>>>(ei, E, N, cnt);
  scan_dinv<<<1, 1024, 0, stream>>>(cnt, offs, dinv, N);
  fill_csr<<<egrid, 256, 0, stream>>>(ei, E, N, offs, fillp, csr);

  gat_gather<<<N, 64, 0, stream>>>(buf0, a_src, a_dst, offs, csr, gat_bias, x1b);

  // h2 = x1 @ gcn_W  (MFMA)
  gemm_mfma<<<dim3(7, N / 128), 256, 0, stream>>>(x1b, wt2, buf0, N, HID, 800);

  // fused GCN gather + per-graph max/mean pool
  gcn_pool<<<B, 256, 0, stream>>>(buf0, offs, csr, dinv, gcn_bias, batch, N, g);

  // protein branch (buf0 free now)
  build_A<<<B, 256, 0, stream>>>(tgt, convW, Aprot);
  conv_xt<<<B, 256, 0, stream>>>(Aprot, embed, convb, convflat);
  gemm_f32<false, true><<<dim3(1, B / 64), 256, 0, stream>>>(
      convflat, fc1xt_W, fc1xt_b, xtb, B, 128, 3872);

  // graph head
  gemm_f32<true, true><<<dim3(12, B / 64), 256, 0, stream>>>(
      g, fcg1_W, fcg1_b, g1out, B, 1500, 2 * HID);
  gemm_f32<false, true><<<dim3(1, B / 64), 256, 0, stream>>>(
      g1out, fcg2_W, fcg2_b, g2out, B, 128, 1500);

  // joint head
  concat_xc<<<B, 256, 0, stream>>>(g2out, xtb, xc);
  gemm_f32<true, true><<<dim3(8, B / 64), 256, 0, stream>>>(
      xc, fc1_W, fc1_b, z1, B, 1024, 256);
  gemm_f32<true, true><<<dim3(4, B / 64), 256, 0, stream>>>(
      z1, fc2_W, fc2_b, z2, B, 512, 1024);
  final_out<<<B / 4, 256, 0, stream>>>(z2, out_W, out_b, (float*)d_out);
}

// Round 5
// 1714.777 us; speedup vs baseline: 2.8060x; 1.7892x over previous
//
#include <hip/hip_runtime.h>

typedef __attribute__((ext_vector_type(4))) float f32x4;
typedef __attribute__((ext_vector_type(8))) short bf16x8;
typedef unsigned short u16;

#define HID 780
#define NH 10
#define FO 78

__device__ inline u16 f2b(float f) {  // fp32 -> bf16 RNE
  unsigned u = __float_as_uint(f);
  unsigned r = (u + 0x7fff + ((u >> 16) & 1)) >> 16;
  return (u16)r;
}

// ---------------- bf16 MFMA GEMM: C[M,N] = A[M,KP] @ BT[N,KP]^T ----------------
__global__ __launch_bounds__(256) void gemm_mfma(const u16* __restrict__ A,
    const u16* __restrict__ BT, float* __restrict__ C, int M, int N, int KP)
{
  __shared__ u16 As[128 * 40];
  __shared__ u16 Bs[128 * 40];
  const int tid = threadIdx.x;
  const int row0 = blockIdx.y << 7, col0 = blockIdx.x << 7;
  const int l = tid & 63, wid = tid >> 6;
  const int wr = wid >> 1, wc = wid & 1;
  const int lr = l & 15, lk = l >> 4;
  f32x4 acc[4][4];
#pragma unroll
  for (int i = 0; i < 4; ++i)
#pragma unroll
    for (int j = 0; j < 4; ++j) acc[i][j] = (f32x4){0.f, 0.f, 0.f, 0.f};

  for (int k0 = 0; k0 < KP; k0 += 32) {
    __syncthreads();
#pragma unroll
    for (int i = 0; i < 2; ++i) {
      int c = tid + (i << 8);          // 0..511
      int row = c >> 2, off = c & 3;   // 128 rows x 4 chunks of 8 bf16
      *(uint4*)&As[row * 40 + off * 8] =
          *(const uint4*)(A + (size_t)(row0 + row) * KP + k0 + off * 8);
      *(uint4*)&Bs[row * 40 + off * 8] =
          *(const uint4*)(BT + (size_t)(col0 + row) * KP + k0 + off * 8);
    }
    __syncthreads();
    bf16x8 af[4], bfr[4];
#pragma unroll
    for (int fm = 0; fm < 4; ++fm)
      af[fm] = *(const bf16x8*)&As[(wr * 64 + fm * 16 + lr) * 40 + lk * 8];
#pragma unroll
    for (int fn = 0; fn < 4; ++fn)
      bfr[fn] = *(const bf16x8*)&Bs[(wc * 64 + fn * 16 + lr) * 40 + lk * 8];
#pragma unroll
    for (int fm = 0; fm < 4; ++fm)
#pragma unroll
      for (int fn = 0; fn < 4; ++fn)
        acc[fm][fn] = __builtin_amdgcn_mfma_f32_16x16x32_bf16(af[fm], bfr[fn], acc[fm][fn], 0, 0, 0);
  }
#pragma unroll
  for (int fm = 0; fm < 4; ++fm)
#pragma unroll
    for (int fn = 0; fn < 4; ++fn) {
      int col = col0 + wc * 64 + fn * 16 + lr;
      if (col < N) {
        f32x4 v = acc[fm][fn];
#pragma unroll
        for (int j = 0; j < 4; ++j)
          C[(size_t)(row0 + wr * 64 + fm * 16 + lk * 4 + j) * N + col] = v[j];
      }
    }
}

// ---------------- conversions ----------------
__global__ void conv_x_bf16(const float* __restrict__ x, u16* __restrict__ xb, int M)
{
  int idx = blockIdx.x * 256 + threadIdx.x;
  if (idx >= M * 96) return;
  int r = idx / 96, c = idx - r * 96;
  xb[idx] = (c < FO) ? f2b(x[(size_t)r * FO + c]) : (u16)0;
}

__global__ void conv_wT_bf16(const float* __restrict__ W, u16* __restrict__ WT,
                             int K, int N, int KP, int NP)
{
  int idx = blockIdx.x * 256 + threadIdx.x;
  if (idx >= NP * KP) return;
  int n = idx / KP, k = idx - n * KP;
  WT[idx] = (n < N && k < K) ? f2b(W[(size_t)k * N + n]) : (u16)0;
}

// ------- split-K fp32 GEMM: partial C[M,N] += A[M,K-slice] @ B[K-slice,N] -------
// tile 64(M) x 128(N); grid.z slices K by kchunk; ATOMIC: atomicAdd partials
// into pre-zeroed C (bias/relu applied by bias_act afterwards).
template<bool ATOMIC, bool RELU, bool BIAS>
__global__ __launch_bounds__(256) void gemm_f32s(const float* __restrict__ A,
    const float* __restrict__ B, const float* __restrict__ bias,
    float* __restrict__ C, int M, int N, int K, int ldc, int kchunk)
{
  __shared__ __align__(16) float As[16][68];
  __shared__ __align__(16) float Bs[16][136];
  const int tid = threadIdx.x;
  const int row0 = blockIdx.y << 6;
  const int col0 = blockIdx.x << 7;
  const int kbeg = blockIdx.z * kchunk;
  const int kend = min(K, kbeg + kchunk);
  const int tx = tid & 15, ty = tid >> 4;
  const int akk = tid & 15, amb = tid >> 4;
  const int bn = tid & 127, bkb = tid >> 7;
  float acc[4][8];
#pragma unroll
  for (int i = 0; i < 4; ++i)
#pragma unroll
    for (int j = 0; j < 8; ++j) acc[i][j] = 0.f;

  for (int k0 = kbeg; k0 < kend; k0 += 16) {
#pragma unroll
    for (int j = 0; j < 4; ++j) {
      int m = amb + (j << 4);
      As[akk][m] = (k0 + akk < kend) ? A[(size_t)(row0 + m) * K + k0 + akk] : 0.f;
    }
#pragma unroll
    for (int j = 0; j < 8; ++j) {
      int kk = (bkb << 3) + j;
      int c = col0 + bn;
      Bs[kk][bn] = (k0 + kk < kend && c < N) ? B[(size_t)(k0 + kk) * N + c] : 0.f;
    }
    __syncthreads();
#pragma unroll
    for (int kk = 0; kk < 16; ++kk) {
      f32x4 a = *(const f32x4*)&As[kk][ty << 2];
      f32x4 b0 = *(const f32x4*)&Bs[kk][tx << 2];
      f32x4 b1 = *(const f32x4*)&Bs[kk][64 + (tx << 2)];
#pragma unroll
      for (int i = 0; i < 4; ++i) {
#pragma unroll
        for (int j = 0; j < 4; ++j) {
          acc[i][j]     += a[i] * b0[j];
          acc[i][j + 4] += a[i] * b1[j];
        }
      }
    }
    __syncthreads();
  }
#pragma unroll
  for (int i = 0; i < 4; ++i) {
    int r = row0 + (ty << 2) + i;
#pragma unroll
    for (int j = 0; j < 4; ++j) {
      int c0 = col0 + (tx << 2) + j;
      int c1 = c0 + 64;
      if (ATOMIC) {
        if (c0 < N) atomicAdd(&C[(size_t)r * ldc + c0], acc[i][j]);
        if (c1 < N) atomicAdd(&C[(size_t)r * ldc + c1], acc[i][j + 4]);
      } else {
        if (c0 < N) {
          float v = acc[i][j];
          if (BIAS) v += bias[c0];
          if (RELU) v = v > 0.f ? v : 0.f;
          C[(size_t)r * ldc + c0] = v;
        }
        if (c1 < N) {
          float v = acc[i][j + 4];
          if (BIAS) v += bias[c1];
          if (RELU) v = v > 0.f ? v : 0.f;
          C[(size_t)r * ldc + c1] = v;
        }
      }
    }
  }
}

template<bool RELU>
__global__ void bias_act(float* __restrict__ C, const float* __restrict__ bias,
                         int M, int N, int ldc)
{
  int idx = blockIdx.x * 256 + threadIdx.x;
  if (idx >= M * N) return;
  int r = idx / N, c = idx - r * N;
  float v = C[(size_t)r * ldc + c] + bias[c];
  if (RELU) v = v > 0.f ? v : 0.f;
  C[(size_t)r * ldc + c] = v;
}

// ---------------- attention per-node dots ----------------
__global__ __launch_bounds__(64) void att_dots(const float* __restrict__ h,
    const float* __restrict__ asv, const float* __restrict__ adv,
    float* __restrict__ a_src, float* __restrict__ a_dst)
{
  int n = blockIdx.x, lane = threadIdx.x;
  __shared__ float ss[NH], sd[NH];
  if (lane < NH) { ss[lane] = 0.f; sd[lane] = 0.f; }
  __syncthreads();
  const float* hr = h + (size_t)n * HID;
  for (int i = lane; i < HID; i += 64) {
    float v = hr[i];
    int hd = i / FO;
    atomicAdd(&ss[hd], v * asv[i]);
    atomicAdd(&sd[hd], v * adv[i]);
  }
  __syncthreads();
  if (lane < NH) { a_src[n * NH + lane] = ss[lane]; a_dst[n * NH + lane] = sd[lane]; }
}

// ---------------- CSR build ----------------
__global__ void count_dst(const int* __restrict__ ei, int E, int N, int* __restrict__ cnt)
{
  int e = blockIdx.x * 256 + threadIdx.x;
  if (e >= E + N) return;
  int dst = (e < E) ? ei[E + e] : (e - E);
  atomicAdd(&cnt[dst], 1);
}

__global__ __launch_bounds__(1024) void scan_dinv(const int* __restrict__ cnt,
    int* __restrict__ offs, float* __restrict__ dinv, int N)
{
  __shared__ int part[1024];
  int tid = threadIdx.x;
  int chunk = (N + 1023) >> 10;
  int b0 = tid * chunk, b1 = min(b0 + chunk, N);
  int s = 0;
  for (int i = b0; i < b1; ++i) s += cnt[i];
  part[tid] = s;
  __syncthreads();
  for (int off = 1; off < 1024; off <<= 1) {
    int v = part[tid];
    int add = (tid >= off) ? part[tid - off] : 0;
    __syncthreads();
    part[tid] = v + add;
    __syncthreads();
  }
  int run = (tid > 0) ? part[tid - 1] : 0;
  for (int i = b0; i < b1; ++i) {
    int c = cnt[i];
    offs[i] = run;
    dinv[i] = c > 0 ? rsqrtf((float)c) : 0.f;
    run += c;
  }
  if (tid == 1023) offs[N] = run;
}

__global__ void fill_csr(const int* __restrict__ ei, int E, int N,
    const int* __restrict__ offs, int* __restrict__ fillpos, int* __restrict__ csr_src)
{
  int e = blockIdx.x * 256 + threadIdx.x;
  if (e >= E + N) return;
  int src, dst;
  if (e < E) { src = ei[e]; dst = ei[E + e]; }
  else { src = e - E; dst = e - E; }
  int p = offs[dst] + atomicAdd(&fillpos[dst], 1);
  csr_src[p] = src;
}

// ---------------- GAT gather (chunked softmax), writes x1 as bf16 [N][800] ----------------
#define CH 48
__global__ __launch_bounds__(64) void gat_gather(const float* __restrict__ h,
    const float* __restrict__ a_src, const float* __restrict__ a_dst,
    const int* __restrict__ offs, const int* __restrict__ csr_src,
    const float* __restrict__ gat_bias, u16* __restrict__ x1b)
{
  int n = blockIdx.x, lane = threadIdx.x;
  int o0 = offs[n], deg = offs[n + 1] - o0;
  __shared__ float ad[NH], m[NH], ssum[NH];
  __shared__ float wbuf[CH][NH];
  __shared__ int slist[CH];
  __shared__ unsigned mu[NH];
  if (lane < NH) { ad[lane] = a_dst[n * NH + lane]; mu[lane] = 0u; ssum[lane] = 0.f; }
  __syncthreads();
  for (int idx = lane; idx < deg * NH; idx += 64) {
    int e = idx / NH, hd = idx - e * NH;
    int s = csr_src[o0 + e];
    float l = a_src[s * NH + hd] + ad[hd];
    l = l > 0.f ? l : 0.2f * l;
    unsigned u = __float_as_uint(l);
    u = (u & 0x80000000u) ? ~u : (u | 0x80000000u);
    atomicMax(&mu[hd], u);
  }
  __syncthreads();
  if (lane < NH) {
    unsigned u = mu[lane];
    m[lane] = __uint_as_float((u & 0x80000000u) ? (u & 0x7fffffffu) : ~u);
  }
  int hidx[13];
#pragma unroll
  for (int i = 0; i < 13; ++i) { int f = lane + 64 * i; hidx[i] = (f < HID) ? (f / FO) : 0; }
  float acc[13];
#pragma unroll
  for (int i = 0; i < 13; ++i) acc[i] = 0.f;

  for (int e0 = 0; e0 < deg; e0 += CH) {
    int ce = min(CH, deg - e0);
    __syncthreads();
    for (int idx = lane; idx < ce * NH; idx += 64) {
      int e = idx / NH, hd = idx - e * NH;
      int s = csr_src[o0 + e0 + e];
      float l = a_src[s * NH + hd] + ad[hd];
      l = l > 0.f ? l : 0.2f * l;
      float w = __expf(l - m[hd]);
      wbuf[e][hd] = w;
      atomicAdd(&ssum[hd], w);
    }
    for (int idx = lane; idx < ce; idx += 64) slist[idx] = csr_src[o0 + e0 + idx];
    __syncthreads();
    for (int e = 0; e < ce; ++e) {
      const float* hs = h + (size_t)slist[e] * HID;
#pragma unroll
      for (int i = 0; i < 13; ++i) {
        int f = lane + 64 * i;
        if (f < HID) acc[i] += wbuf[e][hidx[i]] * hs[f];
      }
    }
  }
  __syncthreads();
#pragma unroll
  for (int i = 0; i < 13; ++i) {
    int f = lane + 64 * i;
    if (f < HID) {
      float v = acc[i] / (ssum[hidx[i]] + 1e-16f) + gat_bias[f];
      x1b[(size_t)n * 800 + f] = f2b(v > 0.f ? v : 0.f);
    }
  }
  if (lane < 20) x1b[(size_t)n * 800 + HID + lane] = 0;
}

// ---------------- GCN gather fused with per-graph pooling ----------------
__global__ __launch_bounds__(256) void gcn_pool(const float* __restrict__ h2,
    const int* __restrict__ offs, const int* __restrict__ csr_src,
    const float* __restrict__ dinv, const float* __restrict__ gcn_bias,
    const int* __restrict__ batch, int N, float* __restrict__ g)
{
  int gi = blockIdx.x, tid = threadIdx.x;
  int grp = tid >> 6, lane = tid & 63;
  __shared__ int se[2];
  __shared__ float smx[HID];
  __shared__ float ssm[HID];
  for (int f = tid; f < HID; f += 256) { smx[f] = 0.f; ssm[f] = 0.f; }
  if (tid < 2) {
    int target = gi + tid;
    int lo = 0, hi = N;
    while (lo < hi) { int mid = (lo + hi) >> 1; if (batch[mid] < target) lo = mid + 1; else hi = mid; }
    se[tid] = lo;
  }
  __syncthreads();
  int s = se[0], e = se[1];
  float mx[13], sm[13];
#pragma unroll
  for (int i = 0; i < 13; ++i) { mx[i] = 0.f; sm[i] = 0.f; }
  for (int n = s + grp; n < e; n += 4) {
    int o0 = offs[n], deg = offs[n + 1] - o0;
    float dn = dinv[n];
    float acc[13];
#pragma unroll
    for (int i = 0; i < 13; ++i) acc[i] = 0.f;
    for (int ed = 0; ed < deg; ++ed) {
      int src = csr_src[o0 + ed];
      float c = dn * dinv[src];
      const float* hr = h2 + (size_t)src * HID;
#pragma unroll
      for (int i = 0; i < 13; ++i) {
        int f = lane + 64 * i;
        if (f < HID) acc[i] += c * hr[f];
      }
    }
#pragma unroll
    for (int i = 0; i < 13; ++i) {
      int f = lane + 64 * i;
      if (f < HID) {
        float v = acc[i] + gcn_bias[f];
        v = v > 0.f ? v : 0.f;
        mx[i] = fmaxf(mx[i], v);
        sm[i] += v;
      }
    }
  }
#pragma unroll
  for (int i = 0; i < 13; ++i) {
    int f = lane + 64 * i;
    if (f < HID) {
      atomicMax((unsigned*)&smx[f], __float_as_uint(mx[i]));
      atomicAdd(&ssm[f], sm[i]);
    }
  }
  __syncthreads();
  float inv = 1.f / fmaxf((float)(e - s), 1.f);
  for (int f = tid; f < HID; f += 256) {
    g[(size_t)gi * (2 * HID) + f] = smx[f];
    g[(size_t)gi * (2 * HID) + HID + f] = ssm[f] * inv;
  }
}

// ---------------- protein branch ----------------
__global__ __launch_bounds__(256) void build_A(const int* __restrict__ tgt,
    const float* __restrict__ W, float* __restrict__ Aout)
{
  int b = blockIdx.x, tid = threadIdx.x;
  __shared__ unsigned char tl[1000];
  __shared__ int vcnt[26], voff[27], vfill[26];
  __shared__ short vlist[1000];
  if (tid < 26) { vcnt[tid] = 0; vfill[tid] = 0; }
  __syncthreads();
  for (int i = tid; i < 1000; i += 256) {
    int v = tgt[b * 1000 + i];
    tl[i] = (unsigned char)v;
    atomicAdd(&vcnt[v], 1);
  }
  __syncthreads();
  if (tid == 0) { int r = 0; for (int v = 0; v < 26; ++v) { voff[v] = r; r += vcnt[v]; } voff[26] = r; }
  __syncthreads();
  for (int i = tid; i < 1000; i += 256) {
    int v = tl[i];
    int p = voff[v] + atomicAdd(&vfill[v], 1);
    vlist[p] = (short)i;
  }
  __syncthreads();
  int o = tid >> 3, k = tid & 7;
  const float* Wok = W + o * 8000 + k;
  float* Ao = Aout + (size_t)b * 6656;
  for (int v = 0; v < 26; ++v) {
    float a = 0.f;
    int s = voff[v], e = voff[v + 1];
    for (int j = s; j < e; ++j) a += Wok[(int)vlist[j] * 8];
    Ao[v * 256 + tid] = a;
  }
}

__global__ __launch_bounds__(256) void conv_xt(const float* __restrict__ Aall,
    const float* __restrict__ embed, const float* __restrict__ cbias,
    float* __restrict__ out)
{
  int b = blockIdx.x, tid = threadIdx.x;
  __shared__ __align__(16) float Al[6656];
  __shared__ __align__(16) float el[3360];
  const float* Ab = Aall + (size_t)b * 6656;
  for (int i = tid; i < 6656; i += 256) Al[i] = Ab[i];
  for (int i = tid; i < 3328; i += 256) el[i] = embed[i];
  if (tid < 32) el[3328 + tid] = 0.f;
  __syncthreads();
  for (int grp = tid; grp < 512; grp += 256) {
    int o = grp >> 4;
    int l0 = (grp & 15) << 3;
    float cb = cbias[o];
    float acc[8];
#pragma unroll
    for (int j = 0; j < 8; ++j) acc[j] = cb;
    for (int v = 0; v < 26; ++v) {
      const float* ap = &Al[v * 256 + (o << 3)];
      f32x4 a0 = *(const f32x4*)ap;
      f32x4 a1 = *(const f32x4*)(ap + 4);
      const float* ep = &el[v * 128 + l0];
      f32x4 e0 = *(const f32x4*)ep;
      f32x4 e1 = *(const f32x4*)(ep + 4);
      f32x4 e2 = *(const f32x4*)(ep + 8);
      f32x4 e3 = *(const f32x4*)(ep + 12);
      float a[8] = { a0[0], a0[1], a0[2], a0[3], a1[0], a1[1], a1[2], a1[3] };
      float e[16] = { e0[0], e0[1], e0[2], e0[3], e1[0], e1[1], e1[2], e1[3],
                      e2[0], e2[1], e2[2], e2[3], e3[0], e3[1], e3[2], e3[3] };
#pragma unroll
      for (int k = 0; k < 8; ++k)
#pragma unroll
        for (int j = 0; j < 8; ++j) acc[j] += a[k] * e[k + j];
    }
    int base = o * 121 + l0;
#pragma unroll
    for (int j = 0; j < 8; ++j)
      if (l0 + j < 121) out[(size_t)b * 3872 + base + j] = acc[j];
  }
}

// ---------------- final row-dot ----------------
__global__ __launch_bounds__(256) void final_out(const float* __restrict__ z2,
    const float* __restrict__ W, const float* __restrict__ bias, float* __restrict__ out)
{
  int row = blockIdx.x * 4 + (threadIdx.x >> 6);
  int lane = threadIdx.x & 63;
  const float* zr = z2 + (size_t)row * 512;
  float s = 0.f;
  for (int i = lane; i < 512; i += 64) s += zr[i] * W[i];
#pragma unroll
  for (int off = 32; off > 0; off >>= 1) s += __shfl_down(s, off, 64);
  if (lane == 0) out[row] = s + bias[0];
}

// ---------------- launch ----------------
extern "C" void kernel_launch(void* const* d_in, const int* in_sizes, int n_in,
                              void* d_out, int out_size, void* d_ws, size_t ws_size,
                              hipStream_t stream)
{
  const float* x        = (const float*)d_in[0];
  const int*   ei       = (const int*)d_in[1];
  const int*   batch    = (const int*)d_in[2];
  const int*   tgt      = (const int*)d_in[3];
  const float* gat_W    = (const float*)d_in[4];
  const float* att_src  = (const float*)d_in[5];
  const float* att_dst  = (const float*)d_in[6];
  const float* gat_bias = (const float*)d_in[7];
  const float* gcn_W    = (const float*)d_in[8];
  const float* gcn_bias = (const float*)d_in[9];
  const float* fcg1_W   = (const float*)d_in[10];
  const float* fcg1_b   = (const float*)d_in[11];
  const float* fcg2_W   = (const float*)d_in[12];
  const float* fcg2_b   = (const float*)d_in[13];
  const float* embed    = (const float*)d_in[14];
  const float* convW    = (const float*)d_in[15];
  const float* convb    = (const float*)d_in[16];
  const float* fc1xt_W  = (const float*)d_in[17];
  const float* fc1xt_b  = (const float*)d_in[18];
  const float* fc1_W    = (const float*)d_in[19];
  const float* fc1_b    = (const float*)d_in[20];
  const float* fc2_W    = (const float*)d_in[21];
  const float* fc2_b    = (const float*)d_in[22];
  const float* out_W    = (const float*)d_in[23];
  const float* out_b    = (const float*)d_in[24];

  const int N = in_sizes[0] / FO;      // 40960
  const int E = in_sizes[1] / 2;       // 163840
  const int B = in_sizes[3] / 1000;    // 1024
  const int ET = E + N;

  char* ws = (char*)d_ws;
  size_t off = 0;
  auto alloc = [&](size_t bytes) -> char* {
    char* p = ws + off;
    off = (off + bytes + 255) & ~(size_t)255;
    return p;
  };
  float* buf0  = (float*)alloc((size_t)N * HID * 4);   // h -> h2 -> Aprot/convflat
  float* buf1  = (float*)alloc((size_t)N * 800 * 2);   // xb -> x1b -> MLP scratch
  u16*   wt1   = (u16*)alloc((size_t)896 * 96 * 2);
  u16*   wt2   = (u16*)alloc((size_t)896 * 800 * 2);
  float* a_src = (float*)alloc((size_t)N * NH * 4);
  float* a_dst = (float*)alloc((size_t)N * NH * 4);
  int*   cnt   = (int*)alloc((size_t)N * 4);
  int*   offs  = (int*)alloc((size_t)(N + 1) * 4);
  int*   fillp = (int*)alloc((size_t)N * 4);
  int*   csr   = (int*)alloc((size_t)ET * 4);
  float* dinv  = (float*)alloc((size_t)N * 4);
  float* g     = (float*)alloc((size_t)B * 2 * HID * 4);

  u16*   xb    = (u16*)buf1;                 // dead after gemm #1
  u16*   x1b   = (u16*)buf1;                 // gat_gather -> gemm #2
  float* Aprot    = buf0;                    // after gcn_pool
  float* convflat = buf0 + (size_t)6656 * B;
  // head scratch in buf1 (alive only after gemm #2 consumed x1b)
  float* g1out = buf1;                        // 1024x1500
  float* xc    = buf1 + 1600000;              // 1024x256 (g2 | xt)
  float* z1    = buf1 + 1900000;              // 1024x1024
  float* z2    = buf1 + 3000000;              // 1024x512

  hipMemsetAsync(cnt, 0, (size_t)N * 4, stream);
  hipMemsetAsync(fillp, 0, (size_t)N * 4, stream);

  // conversions
  conv_x_bf16<<<(N * 96 + 255) / 256, 256, 0, stream>>>(x, xb, N);
  conv_wT_bf16<<<(896 * 96 + 255) / 256, 256, 0, stream>>>(gat_W, wt1, FO, HID, 96, 896);
  conv_wT_bf16<<<(896 * 800 + 255) / 256, 256, 0, stream>>>(gcn_W, wt2, HID, HID, 800, 896);

  // h = x @ gat_W  (MFMA)
  gemm_mfma<<<dim3(7, N / 128), 256, 0, stream>>>(xb, wt1, buf0, N, HID, 96);
  att_dots<<<N, 64, 0, stream>>>(buf0, att_src, att_dst, a_src, a_dst);

  int egrid = (ET + 255) / 256;
  count_dst<<<egrid, 256, 0, stream>>>(ei, E, N, cnt);
  scan_dinv<<<1, 1024, 0, stream>>>(cnt, offs, dinv, N);
  fill_csr<<<egrid, 256, 0, stream>>>(ei, E, N, offs, fillp, csr);

  gat_gather<<<N, 64, 0, stream>>>(buf0, a_src, a_dst, offs, csr, gat_bias, x1b);

  // h2 = x1 @ gcn_W  (MFMA)
  gemm_mfma<<<dim3(7, N / 128), 256, 0, stream>>>(x1b, wt2, buf0, N, HID, 800);

  // fused GCN gather + per-graph max/mean pool
  gcn_pool<<<B, 256, 0, stream>>>(buf0, offs, csr, dinv, gcn_bias, batch, N, g);

  // protein branch (buf0 free now)
  build_A<<<B, 256, 0, stream>>>(tgt, convW, Aprot);
  conv_xt<<<B, 256, 0, stream>>>(Aprot, embed, convb, convflat);

  // zero split-K accumulation targets (buf1 free after gemm #2)
  hipMemsetAsync(g1out, 0, (size_t)1024 * 1500 * 4, stream);
  hipMemsetAsync(xc, 0, (size_t)1024 * 256 * 4, stream);
  hipMemsetAsync(z1, 0, (size_t)1024 * 1024 * 4, stream);
  hipMemsetAsync(z2, 0, (size_t)1024 * 512 * 4, stream);

  // xt = convflat @ fc1xt_W + b  -> xc[:,128:]   (split-K 16 -> 256 blocks)
  gemm_f32s<true, false, false><<<dim3(1, B / 64, 16), 256, 0, stream>>>(
      convflat, fc1xt_W, nullptr, xc + 128, B, 128, 3872, 256, 256);
  bias_act<false><<<(B * 128 + 255) / 256, 256, 0, stream>>>(xc + 128, fc1xt_b, B, 128, 256);

  // g1 = relu(g @ fcg1_W + b)   (split-K 2 -> 384 blocks)
  gemm_f32s<true, false, false><<<dim3(12, B / 64, 2), 256, 0, stream>>>(
      g, fcg1_W, nullptr, g1out, B, 1500, 2 * HID, 1500, 784);
  bias_act<true><<<(B * 1500 + 255) / 256, 256, 0, stream>>>(g1out, fcg1_b, B, 1500, 1500);

  // g2 = g1 @ fcg2_W + b  -> xc[:,0:128]   (split-K 12 -> 192 blocks)
  gemm_f32s<true, false, false><<<dim3(1, B / 64, 12), 256, 0, stream>>>(
      g1out, fcg2_W, nullptr, xc, B, 128, 1500, 256, 128);
  bias_act<false><<<(B * 128 + 255) / 256, 256, 0, stream>>>(xc, fcg2_b, B, 128, 256);

  // z1 = relu(xc @ fc1_W + b)   (split-K 2 -> 256 blocks)
  gemm_f32s<true, false, false><<<dim3(8, B / 64, 2), 256, 0, stream>>>(
      xc, fc1_W, nullptr, z1, B, 1024, 256, 1024, 128);
  bias_act<true><<<(B * 1024 + 255) / 256, 256, 0, stream>>>(z1, fc1_b, B, 1024, 1024);

  // z2 = relu(z1 @ fc2_W + b)   (split-K 4 -> 256 blocks)
  gemm_f32s<true, false, false><<<dim3(4, B / 64, 4), 256, 0, stream>>>(
      z1, fc2_W, nullptr, z2, B, 512, 1024, 512, 256);
  bias_act<true><<<(B * 512 + 255) / 256, 256, 0, stream>>>(z2, fc2_b, B, 512, 512);

  final_out<<<B / 4, 256, 0, stream>>>(z2, out_W, out_b, (float*)d_out);
}

// Round 6
// 1290.589 us; speedup vs baseline: 3.7282x; 1.3287x over previous
//
#include <hip/hip_runtime.h>

typedef __attribute__((ext_vector_type(4))) float f32x4;
typedef __attribute__((ext_vector_type(8))) short bf16x8;
typedef unsigned short u16;

#define HID 780
#define NH 10
#define FO 78

__device__ inline u16 f2b(float f) {  // fp32 -> bf16 RNE
  unsigned u = __float_as_uint(f);
  unsigned r = (u + 0x7fff + ((u >> 16) & 1)) >> 16;
  return (u16)r;
}

// ---------------- bf16 MFMA GEMM: C[M,Ncols] = A[M,KP] @ BT[*,KP]^T ----------------
// Columns [Ncols, Ncols+20) are routed to compact att_out[M,20] (if non-null).
__global__ __launch_bounds__(256) void gemm_mfma(const u16* __restrict__ A,
    const u16* __restrict__ BT, float* __restrict__ C, float* __restrict__ att_out,
    int M, int Ncols, int KP)
{
  __shared__ u16 As[128 * 40];
  __shared__ u16 Bs[128 * 40];
  const int tid = threadIdx.x;
  const int row0 = blockIdx.y << 7, col0 = blockIdx.x << 7;
  const int l = tid & 63, wid = tid >> 6;
  const int wr = wid >> 1, wc = wid & 1;
  const int lr = l & 15, lk = l >> 4;
  f32x4 acc[4][4];
#pragma unroll
  for (int i = 0; i < 4; ++i)
#pragma unroll
    for (int j = 0; j < 4; ++j) acc[i][j] = (f32x4){0.f, 0.f, 0.f, 0.f};

  for (int k0 = 0; k0 < KP; k0 += 32) {
    __syncthreads();
#pragma unroll
    for (int i = 0; i < 2; ++i) {
      int c = tid + (i << 8);          // 0..511
      int row = c >> 2, off = c & 3;   // 128 rows x 4 chunks of 8 bf16
      *(uint4*)&As[row * 40 + off * 8] =
          *(const uint4*)(A + (size_t)(row0 + row) * KP + k0 + off * 8);
      *(uint4*)&Bs[row * 40 + off * 8] =
          *(const uint4*)(BT + (size_t)(col0 + row) * KP + k0 + off * 8);
    }
    __syncthreads();
    bf16x8 af[4], bfr[4];
#pragma unroll
    for (int fm = 0; fm < 4; ++fm)
      af[fm] = *(const bf16x8*)&As[(wr * 64 + fm * 16 + lr) * 40 + lk * 8];
#pragma unroll
    for (int fn = 0; fn < 4; ++fn)
      bfr[fn] = *(const bf16x8*)&Bs[(wc * 64 + fn * 16 + lr) * 40 + lk * 8];
#pragma unroll
    for (int fm = 0; fm < 4; ++fm)
#pragma unroll
      for (int fn = 0; fn < 4; ++fn)
        acc[fm][fn] = __builtin_amdgcn_mfma_f32_16x16x32_bf16(af[fm], bfr[fn], acc[fm][fn], 0, 0, 0);
  }
#pragma unroll
  for (int fm = 0; fm < 4; ++fm)
#pragma unroll
    for (int fn = 0; fn < 4; ++fn) {
      int col = col0 + wc * 64 + fn * 16 + lr;
      f32x4 v = acc[fm][fn];
      int rbase = row0 + wr * 64 + fm * 16 + lk * 4;
      if (col < Ncols) {
#pragma unroll
        for (int j = 0; j < 4; ++j)
          C[(size_t)(rbase + j) * Ncols + col] = v[j];
      } else if (att_out != nullptr && col < Ncols + 20) {
        int c = col - Ncols;
#pragma unroll
        for (int j = 0; j < 4; ++j)
          att_out[(size_t)(rbase + j) * 20 + c] = v[j];
      }
    }
}

// ---------------- conversions ----------------
__global__ void conv_x_bf16(const float* __restrict__ x, u16* __restrict__ xb, int M)
{
  int idx = blockIdx.x * 256 + threadIdx.x;
  if (idx >= M * 96) return;
  int r = idx / 96, c = idx - r * 96;
  xb[idx] = (c < FO) ? f2b(x[(size_t)r * FO + c]) : (u16)0;
}

__global__ void conv_wT_bf16(const float* __restrict__ W, u16* __restrict__ WT,
                             int K, int N, int KP, int NP)
{
  int idx = blockIdx.x * 256 + threadIdx.x;
  if (idx >= NP * KP) return;
  int n = idx / KP, k = idx - n * KP;
  WT[idx] = (n < N && k < K) ? f2b(W[(size_t)k * N + n]) : (u16)0;
}

// fold attention vectors into wt1 rows 780..799:
// wt1[780+j][k] = bf16( sum_f gat_W[k, h*78+f] * av[h*78+f] ), h=j%10, av=src(j<10)/dst
__global__ void fold_att(const float* __restrict__ gat_W,
    const float* __restrict__ asv, const float* __restrict__ adv,
    u16* __restrict__ wt1)
{
  int j = blockIdx.x;            // 0..19
  int k = threadIdx.x;           // 0..95
  if (k >= 96) return;
  float s = 0.f;
  if (k < FO) {
    int h = (j < 10) ? j : j - 10;
    const float* av = ((j < 10) ? asv : adv) + h * FO;
    const float* wr = gat_W + (size_t)k * HID + h * FO;
    for (int f = 0; f < FO; ++f) s += wr[f] * av[f];
  }
  wt1[(size_t)(HID + j) * 96 + k] = f2b(s);
}

// ------- split-K fp32 GEMM -------
template<bool ATOMIC, bool RELU, bool BIAS>
__global__ __launch_bounds__(256) void gemm_f32s(const float* __restrict__ A,
    const float* __restrict__ B, const float* __restrict__ bias,
    float* __restrict__ C, int M, int N, int K, int ldc, int kchunk)
{
  __shared__ __align__(16) float As[16][68];
  __shared__ __align__(16) float Bs[16][136];
  const int tid = threadIdx.x;
  const int row0 = blockIdx.y << 6;
  const int col0 = blockIdx.x << 7;
  const int kbeg = blockIdx.z * kchunk;
  const int kend = min(K, kbeg + kchunk);
  const int tx = tid & 15, ty = tid >> 4;
  const int akk = tid & 15, amb = tid >> 4;
  const int bn = tid & 127, bkb = tid >> 7;
  float acc[4][8];
#pragma unroll
  for (int i = 0; i < 4; ++i)
#pragma unroll
    for (int j = 0; j < 8; ++j) acc[i][j] = 0.f;

  for (int k0 = kbeg; k0 < kend; k0 += 16) {
#pragma unroll
    for (int j = 0; j < 4; ++j) {
      int m = amb + (j << 4);
      As[akk][m] = (k0 + akk < kend) ? A[(size_t)(row0 + m) * K + k0 + akk] : 0.f;
    }
#pragma unroll
    for (int j = 0; j < 8; ++j) {
      int kk = (bkb << 3) + j;
      int c = col0 + bn;
      Bs[kk][bn] = (k0 + kk < kend && c < N) ? B[(size_t)(k0 + kk) * N + c] : 0.f;
    }
    __syncthreads();
#pragma unroll
    for (int kk = 0; kk < 16; ++kk) {
      f32x4 a = *(const f32x4*)&As[kk][ty << 2];
      f32x4 b0 = *(const f32x4*)&Bs[kk][tx << 2];
      f32x4 b1 = *(const f32x4*)&Bs[kk][64 + (tx << 2)];
#pragma unroll
      for (int i = 0; i < 4; ++i) {
#pragma unroll
        for (int j = 0; j < 4; ++j) {
          acc[i][j]     += a[i] * b0[j];
          acc[i][j + 4] += a[i] * b1[j];
        }
      }
    }
    __syncthreads();
  }
#pragma unroll
  for (int i = 0; i < 4; ++i) {
    int r = row0 + (ty << 2) + i;
#pragma unroll
    for (int j = 0; j < 4; ++j) {
      int c0 = col0 + (tx << 2) + j;
      int c1 = c0 + 64;
      if (ATOMIC) {
        if (c0 < N) atomicAdd(&C[(size_t)r * ldc + c0], acc[i][j]);
        if (c1 < N) atomicAdd(&C[(size_t)r * ldc + c1], acc[i][j + 4]);
      } else {
        if (c0 < N) {
          float v = acc[i][j];
          if (BIAS) v += bias[c0];
          if (RELU) v = v > 0.f ? v : 0.f;
          C[(size_t)r * ldc + c0] = v;
        }
        if (c1 < N) {
          float v = acc[i][j + 4];
          if (BIAS) v += bias[c1];
          if (RELU) v = v > 0.f ? v : 0.f;
          C[(size_t)r * ldc + c1] = v;
        }
      }
    }
  }
}

template<bool RELU>
__global__ void bias_act(float* __restrict__ C, const float* __restrict__ bias,
                         int M, int N, int ldc)
{
  int idx = blockIdx.x * 256 + threadIdx.x;
  if (idx >= M * N) return;
  int r = idx / N, c = idx - r * N;
  float v = C[(size_t)r * ldc + c] + bias[c];
  if (RELU) v = v > 0.f ? v : 0.f;
  C[(size_t)r * ldc + c] = v;
}

// ---------------- CSR build ----------------
__global__ void count_dst(const int* __restrict__ ei, int E, int N, int* __restrict__ cnt)
{
  int e = blockIdx.x * 256 + threadIdx.x;
  if (e >= E + N) return;
  int dst = (e < E) ? ei[E + e] : (e - E);
  atomicAdd(&cnt[dst], 1);
}

__global__ __launch_bounds__(1024) void scan_dinv(const int* __restrict__ cnt,
    int* __restrict__ offs, float* __restrict__ dinv, int N)
{
  __shared__ int part[1024];
  int tid = threadIdx.x;
  int chunk = (N + 1023) >> 10;
  int b0 = tid * chunk, b1 = min(b0 + chunk, N);
  int s = 0;
  for (int i = b0; i < b1; ++i) s += cnt[i];
  part[tid] = s;
  __syncthreads();
  for (int off = 1; off < 1024; off <<= 1) {
    int v = part[tid];
    int add = (tid >= off) ? part[tid - off] : 0;
    __syncthreads();
    part[tid] = v + add;
    __syncthreads();
  }
  int run = (tid > 0) ? part[tid - 1] : 0;
  for (int i = b0; i < b1; ++i) {
    int c = cnt[i];
    offs[i] = run;
    dinv[i] = c > 0 ? rsqrtf((float)c) : 0.f;
    run += c;
  }
  if (tid == 1023) offs[N] = run;
}

__global__ void fill_csr(const int* __restrict__ ei, int E, int N,
    const int* __restrict__ offs, int* __restrict__ fillpos, int* __restrict__ csr_src)
{
  int e = blockIdx.x * 256 + threadIdx.x;
  if (e >= E + N) return;
  int src, dst;
  if (e < E) { src = ei[e]; dst = ei[E + e]; }
  else { src = e - E; dst = e - E; }
  int p = offs[dst] + atomicAdd(&fillpos[dst], 1);
  csr_src[p] = src;
}

// ---------------- GAT gather (chunked softmax), writes x1 as bf16 [N][800] ----------------
// att[n*20 + 0..9] = a_src, att[n*20 + 10..19] = a_dst
#define CH 48
__global__ __launch_bounds__(64) void gat_gather(const float* __restrict__ h,
    const float* __restrict__ att,
    const int* __restrict__ offs, const int* __restrict__ csr_src,
    const float* __restrict__ gat_bias, u16* __restrict__ x1b)
{
  int n = blockIdx.x, lane = threadIdx.x;
  int o0 = offs[n], deg = offs[n + 1] - o0;
  __shared__ float ad[NH], m[NH], ssum[NH];
  __shared__ float wbuf[CH][NH];
  __shared__ int slist[CH];
  __shared__ unsigned mu[NH];
  if (lane < NH) { ad[lane] = att[n * 20 + 10 + lane]; mu[lane] = 0u; ssum[lane] = 0.f; }
  __syncthreads();
  for (int idx = lane; idx < deg * NH; idx += 64) {
    int e = idx / NH, hd = idx - e * NH;
    int s = csr_src[o0 + e];
    float l = att[s * 20 + hd] + ad[hd];
    l = l > 0.f ? l : 0.2f * l;
    unsigned u = __float_as_uint(l);
    u = (u & 0x80000000u) ? ~u : (u | 0x80000000u);
    atomicMax(&mu[hd], u);
  }
  __syncthreads();
  if (lane < NH) {
    unsigned u = mu[lane];
    m[lane] = __uint_as_float((u & 0x80000000u) ? (u & 0x7fffffffu) : ~u);
  }
  int hidx[13];
#pragma unroll
  for (int i = 0; i < 13; ++i) { int f = lane + 64 * i; hidx[i] = (f < HID) ? (f / FO) : 0; }
  float acc[13];
#pragma unroll
  for (int i = 0; i < 13; ++i) acc[i] = 0.f;

  for (int e0 = 0; e0 < deg; e0 += CH) {
    int ce = min(CH, deg - e0);
    __syncthreads();
    for (int idx = lane; idx < ce * NH; idx += 64) {
      int e = idx / NH, hd = idx - e * NH;
      int s = csr_src[o0 + e0 + e];
      float l = att[s * 20 + hd] + ad[hd];
      l = l > 0.f ? l : 0.2f * l;
      float w = __expf(l - m[hd]);
      wbuf[e][hd] = w;
      atomicAdd(&ssum[hd], w);
    }
    for (int idx = lane; idx < ce; idx += 64) slist[idx] = csr_src[o0 + e0 + idx];
    __syncthreads();
    for (int e = 0; e < ce; ++e) {
      const float* hs = h + (size_t)slist[e] * HID;
#pragma unroll
      for (int i = 0; i < 13; ++i) {
        int f = lane + 64 * i;
        if (f < HID) acc[i] += wbuf[e][hidx[i]] * hs[f];
      }
    }
  }
  __syncthreads();
#pragma unroll
  for (int i = 0; i < 13; ++i) {
    int f = lane + 64 * i;
    if (f < HID) {
      float v = acc[i] / (ssum[hidx[i]] + 1e-16f) + gat_bias[f];
      x1b[(size_t)n * 800 + f] = f2b(v > 0.f ? v : 0.f);
    }
  }
  if (lane < 20) x1b[(size_t)n * 800 + HID + lane] = 0;
}

// ---------------- GCN gather fused with per-graph pooling ----------------
__global__ __launch_bounds__(256) void gcn_pool(const float* __restrict__ h2,
    const int* __restrict__ offs, const int* __restrict__ csr_src,
    const float* __restrict__ dinv, const float* __restrict__ gcn_bias,
    const int* __restrict__ batch, int N, float* __restrict__ g)
{
  int gi = blockIdx.x, tid = threadIdx.x;
  int grp = tid >> 6, lane = tid & 63;
  __shared__ int se[2];
  __shared__ float smx[HID];
  __shared__ float ssm[HID];
  for (int f = tid; f < HID; f += 256) { smx[f] = 0.f; ssm[f] = 0.f; }
  if (tid < 2) {
    int target = gi + tid;
    int lo = 0, hi = N;
    while (lo < hi) { int mid = (lo + hi) >> 1; if (batch[mid] < target) lo = mid + 1; else hi = mid; }
    se[tid] = lo;
  }
  __syncthreads();
  int s = se[0], e = se[1];
  float mx[13], sm[13];
#pragma unroll
  for (int i = 0; i < 13; ++i) { mx[i] = 0.f; sm[i] = 0.f; }
  for (int n = s + grp; n < e; n += 4) {
    int o0 = offs[n], deg = offs[n + 1] - o0;
    float dn = dinv[n];
    float acc[13];
#pragma unroll
    for (int i = 0; i < 13; ++i) acc[i] = 0.f;
    for (int ed = 0; ed < deg; ++ed) {
      int src = csr_src[o0 + ed];
      float c = dn * dinv[src];
      const float* hr = h2 + (size_t)src * HID;
#pragma unroll
      for (int i = 0; i < 13; ++i) {
        int f = lane + 64 * i;
        if (f < HID) acc[i] += c * hr[f];
      }
    }
#pragma unroll
    for (int i = 0; i < 13; ++i) {
      int f = lane + 64 * i;
      if (f < HID) {
        float v = acc[i] + gcn_bias[f];
        v = v > 0.f ? v : 0.f;
        mx[i] = fmaxf(mx[i], v);
        sm[i] += v;
      }
    }
  }
#pragma unroll
  for (int i = 0; i < 13; ++i) {
    int f = lane + 64 * i;
    if (f < HID) {
      atomicMax((unsigned*)&smx[f], __float_as_uint(mx[i]));
      atomicAdd(&ssm[f], sm[i]);
    }
  }
  __syncthreads();
  float inv = 1.f / fmaxf((float)(e - s), 1.f);
  for (int f = tid; f < HID; f += 256) {
    g[(size_t)gi * (2 * HID) + f] = smx[f];
    g[(size_t)gi * (2 * HID) + HID + f] = ssm[f] * inv;
  }
}

// ---------------- protein branch ----------------
__global__ __launch_bounds__(256) void build_A(const int* __restrict__ tgt,
    const float* __restrict__ W, float* __restrict__ Aout)
{
  int b = blockIdx.x, tid = threadIdx.x;
  __shared__ unsigned char tl[1000];
  __shared__ int vcnt[26], voff[27], vfill[26];
  __shared__ short vlist[1000];
  if (tid < 26) { vcnt[tid] = 0; vfill[tid] = 0; }
  __syncthreads();
  for (int i = tid; i < 1000; i += 256) {
    int v = tgt[b * 1000 + i];
    tl[i] = (unsigned char)v;
    atomicAdd(&vcnt[v], 1);
  }
  __syncthreads();
  if (tid == 0) { int r = 0; for (int v = 0; v < 26; ++v) { voff[v] = r; r += vcnt[v]; } voff[26] = r; }
  __syncthreads();
  for (int i = tid; i < 1000; i += 256) {
    int v = tl[i];
    int p = voff[v] + atomicAdd(&vfill[v], 1);
    vlist[p] = (short)i;
  }
  __syncthreads();
  int o = tid >> 3, k = tid & 7;
  const float* Wok = W + o * 8000 + k;
  float* Ao = Aout + (size_t)b * 6656;
  for (int v = 0; v < 26; ++v) {
    float a = 0.f;
    int s = voff[v], e = voff[v + 1];
    for (int j = s; j < e; ++j) a += Wok[(int)vlist[j] * 8];
    Ao[v * 256 + tid] = a;
  }
}

__global__ __launch_bounds__(256) void conv_xt(const float* __restrict__ Aall,
    const float* __restrict__ embed, const float* __restrict__ cbias,
    float* __restrict__ out)
{
  int b = blockIdx.x, tid = threadIdx.x;
  __shared__ __align__(16) float Al[6656];
  __shared__ __align__(16) float el[3360];
  const float* Ab = Aall + (size_t)b * 6656;
  for (int i = tid; i < 6656; i += 256) Al[i] = Ab[i];
  for (int i = tid; i < 3328; i += 256) el[i] = embed[i];
  if (tid < 32) el[3328 + tid] = 0.f;
  __syncthreads();
  for (int grp = tid; grp < 512; grp += 256) {
    int o = grp >> 4;
    int l0 = (grp & 15) << 3;
    float cb = cbias[o];
    float acc[8];
#pragma unroll
    for (int j = 0; j < 8; ++j) acc[j] = cb;
    for (int v = 0; v < 26; ++v) {
      const float* ap = &Al[v * 256 + (o << 3)];
      f32x4 a0 = *(const f32x4*)ap;
      f32x4 a1 = *(const f32x4*)(ap + 4);
      const float* ep = &el[v * 128 + l0];
      f32x4 e0 = *(const f32x4*)ep;
      f32x4 e1 = *(const f32x4*)(ep + 4);
      f32x4 e2 = *(const f32x4*)(ep + 8);
      f32x4 e3 = *(const f32x4*)(ep + 12);
      float a[8] = { a0[0], a0[1], a0[2], a0[3], a1[0], a1[1], a1[2], a1[3] };
      float e[16] = { e0[0], e0[1], e0[2], e0[3], e1[0], e1[1], e1[2], e1[3],
                      e2[0], e2[1], e2[2], e2[3], e3[0], e3[1], e3[2], e3[3] };
#pragma unroll
      for (int k = 0; k < 8; ++k)
#pragma unroll
        for (int j = 0; j < 8; ++j) acc[j] += a[k] * e[k + j];
    }
    int base = o * 121 + l0;
#pragma unroll
    for (int j = 0; j < 8; ++j)
      if (l0 + j < 121) out[(size_t)b * 3872 + base + j] = acc[j];
  }
}

// ---------------- final row-dot ----------------
__global__ __launch_bounds__(256) void final_out(const float* __restrict__ z2,
    const float* __restrict__ W, const float* __restrict__ bias, float* __restrict__ out)
{
  int row = blockIdx.x * 4 + (threadIdx.x >> 6);
  int lane = threadIdx.x & 63;
  const float* zr = z2 + (size_t)row * 512;
  float s = 0.f;
  for (int i = lane; i < 512; i += 64) s += zr[i] * W[i];
#pragma unroll
  for (int off = 32; off > 0; off >>= 1) s += __shfl_down(s, off, 64);
  if (lane == 0) out[row] = s + bias[0];
}

// ---------------- launch ----------------
extern "C" void kernel_launch(void* const* d_in, const int* in_sizes, int n_in,
                              void* d_out, int out_size, void* d_ws, size_t ws_size,
                              hipStream_t stream)
{
  const float* x        = (const float*)d_in[0];
  const int*   ei       = (const int*)d_in[1];
  const int*   batch    = (const int*)d_in[2];
  const int*   tgt      = (const int*)d_in[3];
  const float* gat_W    = (const float*)d_in[4];
  const float* att_src  = (const float*)d_in[5];
  const float* att_dst  = (const float*)d_in[6];
  const float* gat_bias = (const float*)d_in[7];
  const float* gcn_W    = (const float*)d_in[8];
  const float* gcn_bias = (const float*)d_in[9];
  const float* fcg1_W   = (const float*)d_in[10];
  const float* fcg1_b   = (const float*)d_in[11];
  const float* fcg2_W   = (const float*)d_in[12];
  const float* fcg2_b   = (const float*)d_in[13];
  const float* embed    = (const float*)d_in[14];
  const float* convW    = (const float*)d_in[15];
  const float* convb    = (const float*)d_in[16];
  const float* fc1xt_W  = (const float*)d_in[17];
  const float* fc1xt_b  = (const float*)d_in[18];
  const float* fc1_W    = (const float*)d_in[19];
  const float* fc1_b    = (const float*)d_in[20];
  const float* fc2_W    = (const float*)d_in[21];
  const float* fc2_b    = (const float*)d_in[22];
  const float* out_W    = (const float*)d_in[23];
  const float* out_b    = (const float*)d_in[24];

  const int N = in_sizes[0] / FO;      // 40960
  const int E = in_sizes[1] / 2;       // 163840
  const int B = in_sizes[3] / 1000;    // 1024
  const int ET = E + N;

  char* ws = (char*)d_ws;
  size_t off = 0;
  auto alloc = [&](size_t bytes) -> char* {
    char* p = ws + off;
    off = (off + bytes + 255) & ~(size_t)255;
    return p;
  };
  float* buf0  = (float*)alloc((size_t)N * HID * 4);   // h -> h2 -> Aprot/convflat
  float* buf1  = (float*)alloc((size_t)N * 800 * 2);   // xb -> x1b -> MLP scratch
  u16*   wt1   = (u16*)alloc((size_t)896 * 96 * 2);
  u16*   wt2   = (u16*)alloc((size_t)896 * 800 * 2);
  float* att   = (float*)alloc((size_t)N * 20 * 4);    // a_src|a_dst compact
  int*   cnt   = (int*)alloc((size_t)N * 4);
  int*   offs  = (int*)alloc((size_t)(N + 1) * 4);
  int*   fillp = (int*)alloc((size_t)N * 4);
  int*   csr   = (int*)alloc((size_t)ET * 4);
  float* dinv  = (float*)alloc((size_t)N * 4);
  float* g     = (float*)alloc((size_t)B * 2 * HID * 4);

  u16*   xb    = (u16*)buf1;                 // dead after gemm #1
  u16*   x1b   = (u16*)buf1;                 // gat_gather -> gemm #2
  float* Aprot    = buf0;                    // after gcn_pool
  float* convflat = buf0 + (size_t)6656 * B;
  float* g1out = buf1;                        // 1024x1500
  float* xc    = buf1 + 1600000;              // 1024x256 (g2 | xt)
  float* z1    = buf1 + 1900000;              // 1024x1024
  float* z2    = buf1 + 3000000;              // 1024x512

  hipMemsetAsync(cnt, 0, (size_t)N * 4, stream);
  hipMemsetAsync(fillp, 0, (size_t)N * 4, stream);

  // conversions + attention fold
  conv_x_bf16<<<(N * 96 + 255) / 256, 256, 0, stream>>>(x, xb, N);
  conv_wT_bf16<<<(896 * 96 + 255) / 256, 256, 0, stream>>>(gat_W, wt1, FO, HID, 96, 896);
  fold_att<<<20, 96, 0, stream>>>(gat_W, att_src, att_dst, wt1);
  conv_wT_bf16<<<(896 * 800 + 255) / 256, 256, 0, stream>>>(gcn_W, wt2, HID, HID, 800, 896);

  // h = x @ gat_W (cols 0..779 -> buf0), att dots (cols 780..799 -> att)
  gemm_mfma<<<dim3(7, N / 128), 256, 0, stream>>>(xb, wt1, buf0, att, N, HID, 96);

  int egrid = (ET + 255) / 256;
  count_dst<<<egrid, 256, 0, stream>>>(ei, E, N, cnt);
  scan_dinv<<<1, 1024, 0, stream>>>(cnt, offs, dinv, N);
  fill_csr<<<egrid, 256, 0, stream>>>(ei, E, N, offs, fillp, csr);

  gat_gather<<<N, 64, 0, stream>>>(buf0, att, offs, csr, gat_bias, x1b);

  // h2 = x1 @ gcn_W  (MFMA)
  gemm_mfma<<<dim3(7, N / 128), 256, 0, stream>>>(x1b, wt2, buf0, nullptr, N, HID, 800);

  // fused GCN gather + per-graph max/mean pool
  gcn_pool<<<B, 256, 0, stream>>>(buf0, offs, csr, dinv, gcn_bias, batch, N, g);

  // protein branch (buf0 free now)
  build_A<<<B, 256, 0, stream>>>(tgt, convW, Aprot);
  conv_xt<<<B, 256, 0, stream>>>(Aprot, embed, convb, convflat);

  // zero split-K accumulation targets (buf1 free after gemm #2)
  hipMemsetAsync(g1out, 0, (size_t)1024 * 1500 * 4, stream);
  hipMemsetAsync(xc, 0, (size_t)1024 * 256 * 4, stream);
  hipMemsetAsync(z1, 0, (size_t)1024 * 1024 * 4, stream);
  hipMemsetAsync(z2, 0, (size_t)1024 * 512 * 4, stream);

  // xt = convflat @ fc1xt_W + b  -> xc[:,128:]
  gemm_f32s<true, false, false><<<dim3(1, B / 64, 16), 256, 0, stream>>>(
      convflat, fc1xt_W, nullptr, xc + 128, B, 128, 3872, 256, 256);
  bias_act<false><<<(B * 128 + 255) / 256, 256, 0, stream>>>(xc + 128, fc1xt_b, B, 128, 256);

  // g1 = relu(g @ fcg1_W + b)
  gemm_f32s<true, false, false><<<dim3(12, B / 64, 2), 256, 0, stream>>>(
      g, fcg1_W, nullptr, g1out, B, 1500, 2 * HID, 1500, 784);
  bias_act<true><<<(B * 1500 + 255) / 256, 256, 0, stream>>>(g1out, fcg1_b, B, 1500, 1500);

  // g2 = g1 @ fcg2_W + b  -> xc[:,0:128]
  gemm_f32s<true, false, false><<<dim3(1, B / 64, 12), 256, 0, stream>>>(
      g1out, fcg2_W, nullptr, xc, B, 128, 1500, 256, 128);
  bias_act<false><<<(B * 128 + 255) / 256, 256, 0, stream>>>(xc, fcg2_b, B, 128, 256);

  // z1 = relu(xc @ fc1_W + b)
  gemm_f32s<true, false, false><<<dim3(8, B / 64, 2), 256, 0, stream>>>(
      xc, fc1_W, nullptr, z1, B, 1024, 256, 1024, 128);
  bias_act<true><<<(B * 1024 + 255) / 256, 256, 0, stream>>>(z1, fc1_b, B, 1024, 1024);

  // z2 = relu(z1 @ fc2_W + b)
  gemm_f32s<true, false, false><<<dim3(4, B / 64, 4), 256, 0, stream>>>(
      z1, fc2_W, nullptr, z2, B, 512, 1024, 512, 256);
  bias_act<true><<<(B * 512 + 255) / 256, 256, 0, stream>>>(z2, fc2_b, B, 512, 512);

  final_out<<<B / 4, 256, 0, stream>>>(z2, out_W, out_b, (float*)d_out);
}

// Round 7
// 1072.468 us; speedup vs baseline: 4.4865x; 1.2034x over previous
//
#include <hip/hip_runtime.h>

typedef __attribute__((ext_vector_type(4))) float f32x4;
typedef __attribute__((ext_vector_type(8))) short bf16x8;
typedef unsigned short u16;

#define HID 780
#define NH 10
#define FO 78

__device__ inline u16 f2b(float f) {  // fp32 -> bf16 RNE
  unsigned u = __float_as_uint(f);
  unsigned r = (u + 0x7fff + ((u >> 16) & 1)) >> 16;
  return (u16)r;
}
__device__ inline float b2f(u16 b) { return __uint_as_float(((unsigned)b) << 16); }

// ---------------- bf16 MFMA GEMM ----------------
// A row-major bf16 [M][KP], BT row-major bf16 [NP][KP], KP%32==0, M%128==0.
// CBF16: C is bf16 with fused bias/relu, ldc-padded (cols [Ncols,ldc) zeroed);
// else C is fp32 (ldc leading dim), cols [Ncols,Ncols+20) -> att_out[M,20].
template<bool CBF16, bool BIAS, bool RELU>
__global__ __launch_bounds__(256) void gemm_mfma(const u16* __restrict__ A,
    const u16* __restrict__ BT, void* __restrict__ Cp, float* __restrict__ att_out,
    const float* __restrict__ bias, int M, int Ncols, int KP, int ldc)
{
  __shared__ u16 As[128 * 40];
  __shared__ u16 Bs[128 * 40];
  const int tid = threadIdx.x;
  const int row0 = blockIdx.y << 7, col0 = blockIdx.x << 7;
  const int l = tid & 63, wid = tid >> 6;
  const int wr = wid >> 1, wc = wid & 1;
  const int lr = l & 15, lk = l >> 4;
  f32x4 acc[4][4];
#pragma unroll
  for (int i = 0; i < 4; ++i)
#pragma unroll
    for (int j = 0; j < 4; ++j) acc[i][j] = (f32x4){0.f, 0.f, 0.f, 0.f};

  for (int k0 = 0; k0 < KP; k0 += 32) {
    __syncthreads();
#pragma unroll
    for (int i = 0; i < 2; ++i) {
      int c = tid + (i << 8);          // 0..511
      int row = c >> 2, off = c & 3;   // 128 rows x 4 chunks of 8 bf16
      *(uint4*)&As[row * 40 + off * 8] =
          *(const uint4*)(A + (size_t)(row0 + row) * KP + k0 + off * 8);
      *(uint4*)&Bs[row * 40 + off * 8] =
          *(const uint4*)(BT + (size_t)(col0 + row) * KP + k0 + off * 8);
    }
    __syncthreads();
    bf16x8 af[4], bfr[4];
#pragma unroll
    for (int fm = 0; fm < 4; ++fm)
      af[fm] = *(const bf16x8*)&As[(wr * 64 + fm * 16 + lr) * 40 + lk * 8];
#pragma unroll
    for (int fn = 0; fn < 4; ++fn)
      bfr[fn] = *(const bf16x8*)&Bs[(wc * 64 + fn * 16 + lr) * 40 + lk * 8];
#pragma unroll
    for (int fm = 0; fm < 4; ++fm)
#pragma unroll
      for (int fn = 0; fn < 4; ++fn)
        acc[fm][fn] = __builtin_amdgcn_mfma_f32_16x16x32_bf16(af[fm], bfr[fn], acc[fm][fn], 0, 0, 0);
  }
#pragma unroll
  for (int fm = 0; fm < 4; ++fm)
#pragma unroll
    for (int fn = 0; fn < 4; ++fn) {
      int col = col0 + wc * 64 + fn * 16 + lr;
      f32x4 v = acc[fm][fn];
      int rbase = row0 + wr * 64 + fm * 16 + lk * 4;
      if (CBF16) {
        u16* C = (u16*)Cp;
        if (col < Ncols) {
          float bb = BIAS ? bias[col] : 0.f;
#pragma unroll
          for (int j = 0; j < 4; ++j) {
            float vv = v[j] + bb;
            if (RELU) vv = vv > 0.f ? vv : 0.f;
            C[(size_t)(rbase + j) * ldc + col] = f2b(vv);
          }
        } else if (col < ldc) {
#pragma unroll
          for (int j = 0; j < 4; ++j) C[(size_t)(rbase + j) * ldc + col] = 0;
        }
      } else {
        float* C = (float*)Cp;
        if (col < Ncols) {
#pragma unroll
          for (int j = 0; j < 4; ++j)
            C[(size_t)(rbase + j) * ldc + col] = v[j];
        } else if (att_out != nullptr && col < Ncols + 20) {
          int c = col - Ncols;
#pragma unroll
          for (int j = 0; j < 4; ++j)
            att_out[(size_t)(rbase + j) * 20 + c] = v[j];
        }
      }
    }
}

// ---------------- conversions ----------------
__global__ void conv_x_bf16(const float* __restrict__ x, u16* __restrict__ xb, int M)
{
  int idx = blockIdx.x * 256 + threadIdx.x;
  if (idx >= M * 96) return;
  int r = idx / 96, c = idx - r * 96;
  xb[idx] = (c < FO) ? f2b(x[(size_t)r * FO + c]) : (u16)0;
}

// WT[n][k] (NP x KP) = bf16(W[k][n]) zero-padded
__global__ void conv_wT_bf16(const float* __restrict__ W, u16* __restrict__ WT,
                             int K, int N, int KP, int NP)
{
  int idx = blockIdx.x * 256 + threadIdx.x;
  if (idx >= NP * KP) return;
  int n = idx / KP, k = idx - n * KP;
  WT[idx] = (n < N && k < K) ? f2b(W[(size_t)k * N + n]) : (u16)0;
}

// fold attention vectors into wt1 rows 780..799
__global__ void fold_att(const float* __restrict__ gat_W,
    const float* __restrict__ asv, const float* __restrict__ adv,
    u16* __restrict__ wt1)
{
  int j = blockIdx.x;            // 0..19
  int k = threadIdx.x;           // 0..95
  if (k >= 96) return;
  float s = 0.f;
  if (k < FO) {
    int h = (j < 10) ? j : j - 10;
    const float* av = ((j < 10) ? asv : adv) + h * FO;
    const float* wr = gat_W + (size_t)k * HID + h * FO;
    for (int f = 0; f < FO; ++f) s += wr[f] * av[f];
  }
  wt1[(size_t)(HID + j) * 96 + k] = f2b(s);
}

// ---------------- CSR build ----------------
__global__ void count_dst(const int* __restrict__ ei, int E, int N, int* __restrict__ cnt)
{
  int e = blockIdx.x * 256 + threadIdx.x;
  if (e >= E + N) return;
  int dst = (e < E) ? ei[E + e] : (e - E);
  atomicAdd(&cnt[dst], 1);
}

__global__ __launch_bounds__(1024) void scan_dinv(const int* __restrict__ cnt,
    int* __restrict__ offs, float* __restrict__ dinv, int N)
{
  __shared__ int part[1024];
  int tid = threadIdx.x;
  int chunk = (N + 1023) >> 10;
  int b0 = tid * chunk, b1 = min(b0 + chunk, N);
  int s = 0;
  for (int i = b0; i < b1; ++i) s += cnt[i];
  part[tid] = s;
  __syncthreads();
  for (int off = 1; off < 1024; off <<= 1) {
    int v = part[tid];
    int add = (tid >= off) ? part[tid - off] : 0;
    __syncthreads();
    part[tid] = v + add;
    __syncthreads();
  }
  int run = (tid > 0) ? part[tid - 1] : 0;
  for (int i = b0; i < b1; ++i) {
    int c = cnt[i];
    offs[i] = run;
    dinv[i] = c > 0 ? rsqrtf((float)c) : 0.f;
    run += c;
  }
  if (tid == 1023) offs[N] = run;
}

__global__ void fill_csr(const int* __restrict__ ei, int E, int N,
    const int* __restrict__ offs, int* __restrict__ fillpos, int* __restrict__ csr_src)
{
  int e = blockIdx.x * 256 + threadIdx.x;
  if (e >= E + N) return;
  int src, dst;
  if (e < E) { src = ei[e]; dst = ei[E + e]; }
  else { src = e - E; dst = e - E; }
  int p = offs[dst] + atomicAdd(&fillpos[dst], 1);
  csr_src[p] = src;
}

// ---------------- GAT gather (chunked softmax), writes x1 as bf16 [N][800] ----------------
#define CH 48
__global__ __launch_bounds__(64) void gat_gather(const float* __restrict__ h,
    const float* __restrict__ att,
    const int* __restrict__ offs, const int* __restrict__ csr_src,
    const float* __restrict__ gat_bias, u16* __restrict__ x1b)
{
  int n = blockIdx.x, lane = threadIdx.x;
  int o0 = offs[n], deg = offs[n + 1] - o0;
  __shared__ float ad[NH], m[NH], ssum[NH];
  __shared__ float wbuf[CH][NH];
  __shared__ int slist[CH];
  __shared__ unsigned mu[NH];
  if (lane < NH) { ad[lane] = att[n * 20 + 10 + lane]; mu[lane] = 0u; ssum[lane] = 0.f; }
  __syncthreads();
  for (int idx = lane; idx < deg * NH; idx += 64) {
    int e = idx / NH, hd = idx - e * NH;
    int s = csr_src[o0 + e];
    float l = att[s * 20 + hd] + ad[hd];
    l = l > 0.f ? l : 0.2f * l;
    unsigned u = __float_as_uint(l);
    u = (u & 0x80000000u) ? ~u : (u | 0x80000000u);
    atomicMax(&mu[hd], u);
  }
  __syncthreads();
  if (lane < NH) {
    unsigned u = mu[lane];
    m[lane] = __uint_as_float((u & 0x80000000u) ? (u & 0x7fffffffu) : ~u);
  }
  int hidx[13];
#pragma unroll
  for (int i = 0; i < 13; ++i) { int f = lane + 64 * i; hidx[i] = (f < HID) ? (f / FO) : 0; }
  float acc[13];
#pragma unroll
  for (int i = 0; i < 13; ++i) acc[i] = 0.f;

  for (int e0 = 0; e0 < deg; e0 += CH) {
    int ce = min(CH, deg - e0);
    __syncthreads();
    for (int idx = lane; idx < ce * NH; idx += 64) {
      int e = idx / NH, hd = idx - e * NH;
      int s = csr_src[o0 + e0 + e];
      float l = att[s * 20 + hd] + ad[hd];
      l = l > 0.f ? l : 0.2f * l;
      float w = __expf(l - m[hd]);
      wbuf[e][hd] = w;
      atomicAdd(&ssum[hd], w);
    }
    for (int idx = lane; idx < ce; idx += 64) slist[idx] = csr_src[o0 + e0 + idx];
    __syncthreads();
    for (int e = 0; e < ce; ++e) {
      const float* hs = h + (size_t)slist[e] * HID;
#pragma unroll
      for (int i = 0; i < 13; ++i) {
        int f = lane + 64 * i;
        if (f < HID) acc[i] += wbuf[e][hidx[i]] * hs[f];
      }
    }
  }
  __syncthreads();
#pragma unroll
  for (int i = 0; i < 13; ++i) {
    int f = lane + 64 * i;
    if (f < HID) {
      float v = acc[i] / (ssum[hidx[i]] + 1e-16f) + gat_bias[f];
      x1b[(size_t)n * 800 + f] = f2b(v > 0.f ? v : 0.f);
    }
  }
  if (lane < 20) x1b[(size_t)n * 800 + HID + lane] = 0;
}

// ---------------- GCN gather fused with per-graph pooling, bf16 out [B][1568] ----------------
__global__ __launch_bounds__(256) void gcn_pool(const float* __restrict__ h2,
    const int* __restrict__ offs, const int* __restrict__ csr_src,
    const float* __restrict__ dinv, const float* __restrict__ gcn_bias,
    const int* __restrict__ batch, int N, u16* __restrict__ gb)
{
  int gi = blockIdx.x, tid = threadIdx.x;
  int grp = tid >> 6, lane = tid & 63;
  __shared__ int se[2];
  __shared__ float smx[HID];
  __shared__ float ssm[HID];
  for (int f = tid; f < HID; f += 256) { smx[f] = 0.f; ssm[f] = 0.f; }
  if (tid < 2) {
    int target = gi + tid;
    int lo = 0, hi = N;
    while (lo < hi) { int mid = (lo + hi) >> 1; if (batch[mid] < target) lo = mid + 1; else hi = mid; }
    se[tid] = lo;
  }
  __syncthreads();
  int s = se[0], e = se[1];
  float mx[13], sm[13];
#pragma unroll
  for (int i = 0; i < 13; ++i) { mx[i] = 0.f; sm[i] = 0.f; }
  for (int n = s + grp; n < e; n += 4) {
    int o0 = offs[n], deg = offs[n + 1] - o0;
    float dn = dinv[n];
    float acc[13];
#pragma unroll
    for (int i = 0; i < 13; ++i) acc[i] = 0.f;
    for (int ed = 0; ed < deg; ++ed) {
      int src = csr_src[o0 + ed];
      float c = dn * dinv[src];
      const float* hr = h2 + (size_t)src * HID;
#pragma unroll
      for (int i = 0; i < 13; ++i) {
        int f = lane + 64 * i;
        if (f < HID) acc[i] += c * hr[f];
      }
    }
#pragma unroll
    for (int i = 0; i < 13; ++i) {
      int f = lane + 64 * i;
      if (f < HID) {
        float v = acc[i] + gcn_bias[f];
        v = v > 0.f ? v : 0.f;
        mx[i] = fmaxf(mx[i], v);
        sm[i] += v;
      }
    }
  }
#pragma unroll
  for (int i = 0; i < 13; ++i) {
    int f = lane + 64 * i;
    if (f < HID) {
      atomicMax((unsigned*)&smx[f], __float_as_uint(mx[i]));
      atomicAdd(&ssm[f], sm[i]);
    }
  }
  __syncthreads();
  float inv = 1.f / fmaxf((float)(e - s), 1.f);
  for (int f = tid; f < HID; f += 256) {
    gb[(size_t)gi * 1568 + f] = f2b(smx[f]);
    gb[(size_t)gi * 1568 + HID + f] = f2b(ssm[f] * inv);
  }
  if (tid < 8) gb[(size_t)gi * 1568 + 1560 + tid] = 0;
}

// ---------------- protein branch ----------------
__global__ __launch_bounds__(256) void build_A(const int* __restrict__ tgt,
    const float* __restrict__ W, float* __restrict__ Aout)
{
  int b = blockIdx.x, tid = threadIdx.x;
  __shared__ unsigned char tl[1000];
  __shared__ int vcnt[26], voff[27], vfill[26];
  __shared__ short vlist[1000];
  if (tid < 26) { vcnt[tid] = 0; vfill[tid] = 0; }
  __syncthreads();
  for (int i = tid; i < 1000; i += 256) {
    int v = tgt[b * 1000 + i];
    tl[i] = (unsigned char)v;
    atomicAdd(&vcnt[v], 1);
  }
  __syncthreads();
  if (tid == 0) { int r = 0; for (int v = 0; v < 26; ++v) { voff[v] = r; r += vcnt[v]; } voff[26] = r; }
  __syncthreads();
  for (int i = tid; i < 1000; i += 256) {
    int v = tl[i];
    int p = voff[v] + atomicAdd(&vfill[v], 1);
    vlist[p] = (short)i;
  }
  __syncthreads();
  int o = tid >> 3, k = tid & 7;
  const float* Wok = W + o * 8000 + k;
  float* Ao = Aout + (size_t)b * 6656;
  for (int v = 0; v < 26; ++v) {
    float a = 0.f;
    int s = voff[v], e = voff[v + 1];
    for (int j = s; j < e; ++j) a += Wok[(int)vlist[j] * 8];
    Ao[v * 256 + tid] = a;
  }
}

// conv output written as bf16 [B][3872]
__global__ __launch_bounds__(256) void conv_xt(const float* __restrict__ Aall,
    const float* __restrict__ embed, const float* __restrict__ cbias,
    u16* __restrict__ out)
{
  int b = blockIdx.x, tid = threadIdx.x;
  __shared__ __align__(16) float Al[6656];
  __shared__ __align__(16) float el[3360];
  const float* Ab = Aall + (size_t)b * 6656;
  for (int i = tid; i < 6656; i += 256) Al[i] = Ab[i];
  for (int i = tid; i < 3328; i += 256) el[i] = embed[i];
  if (tid < 32) el[3328 + tid] = 0.f;
  __syncthreads();
  for (int grp = tid; grp < 512; grp += 256) {
    int o = grp >> 4;
    int l0 = (grp & 15) << 3;
    float cb = cbias[o];
    float acc[8];
#pragma unroll
    for (int j = 0; j < 8; ++j) acc[j] = cb;
    for (int v = 0; v < 26; ++v) {
      const float* ap = &Al[v * 256 + (o << 3)];
      f32x4 a0 = *(const f32x4*)ap;
      f32x4 a1 = *(const f32x4*)(ap + 4);
      const float* ep = &el[v * 128 + l0];
      f32x4 e0 = *(const f32x4*)ep;
      f32x4 e1 = *(const f32x4*)(ep + 4);
      f32x4 e2 = *(const f32x4*)(ep + 8);
      f32x4 e3 = *(const f32x4*)(ep + 12);
      float a[8] = { a0[0], a0[1], a0[2], a0[3], a1[0], a1[1], a1[2], a1[3] };
      float e[16] = { e0[0], e0[1], e0[2], e0[3], e1[0], e1[1], e1[2], e1[3],
                      e2[0], e2[1], e2[2], e2[3], e3[0], e3[1], e3[2], e3[3] };
#pragma unroll
      for (int k = 0; k < 8; ++k)
#pragma unroll
        for (int j = 0; j < 8; ++j) acc[j] += a[k] * e[k + j];
    }
    int base = o * 121 + l0;
#pragma unroll
    for (int j = 0; j < 8; ++j)
      if (l0 + j < 121) out[(size_t)b * 3872 + base + j] = f2b(acc[j]);
  }
}

// ---------------- final row-dot (bf16 input) ----------------
__global__ __launch_bounds__(256) void final_out(const u16* __restrict__ z2,
    const float* __restrict__ W, const float* __restrict__ bias, float* __restrict__ out)
{
  int row = blockIdx.x * 4 + (threadIdx.x >> 6);
  int lane = threadIdx.x & 63;
  const u16* zr = z2 + (size_t)row * 512;
  float s = 0.f;
  for (int i = lane; i < 512; i += 64) s += b2f(zr[i]) * W[i];
#pragma unroll
  for (int off = 32; off > 0; off >>= 1) s += __shfl_down(s, off, 64);
  if (lane == 0) out[row] = s + bias[0];
}

// ---------------- launch ----------------
extern "C" void kernel_launch(void* const* d_in, const int* in_sizes, int n_in,
                              void* d_out, int out_size, void* d_ws, size_t ws_size,
                              hipStream_t stream)
{
  const float* x        = (const float*)d_in[0];
  const int*   ei       = (const int*)d_in[1];
  const int*   batch    = (const int*)d_in[2];
  const int*   tgt      = (const int*)d_in[3];
  const float* gat_W    = (const float*)d_in[4];
  const float* att_src  = (const float*)d_in[5];
  const float* att_dst  = (const float*)d_in[6];
  const float* gat_bias = (const float*)d_in[7];
  const float* gcn_W    = (const float*)d_in[8];
  const float* gcn_bias = (const float*)d_in[9];
  const float* fcg1_W   = (const float*)d_in[10];
  const float* fcg1_b   = (const float*)d_in[11];
  const float* fcg2_W   = (const float*)d_in[12];
  const float* fcg2_b   = (const float*)d_in[13];
  const float* embed    = (const float*)d_in[14];
  const float* convW    = (const float*)d_in[15];
  const float* convb    = (const float*)d_in[16];
  const float* fc1xt_W  = (const float*)d_in[17];
  const float* fc1xt_b  = (const float*)d_in[18];
  const float* fc1_W    = (const float*)d_in[19];
  const float* fc1_b    = (const float*)d_in[20];
  const float* fc2_W    = (const float*)d_in[21];
  const float* fc2_b    = (const float*)d_in[22];
  const float* out_W    = (const float*)d_in[23];
  const float* out_b    = (const float*)d_in[24];

  const int N = in_sizes[0] / FO;      // 40960
  const int E = in_sizes[1] / 2;       // 163840
  const int B = in_sizes[3] / 1000;    // 1024
  const int ET = E + N;

  char* ws = (char*)d_ws;
  size_t off = 0;
  auto alloc = [&](size_t bytes) -> char* {
    char* p = ws + off;
    off = (off + bytes + 255) & ~(size_t)255;
    return p;
  };
  float* buf0  = (float*)alloc((size_t)N * HID * 4);   // h -> h2 -> Aprot/convflat
  float* buf1  = (float*)alloc((size_t)N * 800 * 2);   // xb -> x1b -> head scratch
  u16*   wt1   = (u16*)alloc((size_t)896 * 96 * 2);
  u16*   wt2   = (u16*)alloc((size_t)896 * 800 * 2);
  u16*   wtg1  = (u16*)alloc((size_t)1536 * 1568 * 2);
  u16*   wtg2  = (u16*)alloc((size_t)128 * 1504 * 2);
  u16*   wtxt  = (u16*)alloc((size_t)128 * 3872 * 2);
  u16*   wtf1  = (u16*)alloc((size_t)1024 * 256 * 2);
  u16*   wtf2  = (u16*)alloc((size_t)512 * 1024 * 2);
  float* att   = (float*)alloc((size_t)N * 20 * 4);
  int*   cnt   = (int*)alloc((size_t)N * 4);
  int*   offs  = (int*)alloc((size_t)(N + 1) * 4);
  int*   fillp = (int*)alloc((size_t)N * 4);
  int*   csr   = (int*)alloc((size_t)ET * 4);
  float* dinv  = (float*)alloc((size_t)N * 4);
  u16*   gb    = (u16*)alloc((size_t)B * 1568 * 2);

  u16*   xb    = (u16*)buf1;                 // dead after gemm #1
  u16*   x1b   = (u16*)buf1;                 // gat_gather -> gemm #2
  float* Aprot       = buf0;                 // after gcn_pool
  u16*   convflat    = (u16*)(buf0 + (size_t)6656 * B);   // bf16 [B][3872]
  // head scratch in buf1 (after gemm #2 consumed x1b)
  u16* g1b = (u16*)buf1;                     // [1024][1504]
  u16* xcb = g1b + (size_t)1024 * 1504;      // [1024][256] (g2 | xt)
  u16* z1b = xcb + (size_t)1024 * 256;       // [1024][1024]
  u16* z2b = z1b + (size_t)1024 * 1024;      // [1024][512]

  hipMemsetAsync(cnt, 0, (size_t)N * 4, stream);
  hipMemsetAsync(fillp, 0, (size_t)N * 4, stream);

  // conversions + attention fold
  conv_x_bf16<<<(N * 96 + 255) / 256, 256, 0, stream>>>(x, xb, N);
  conv_wT_bf16<<<(896 * 96 + 255) / 256, 256, 0, stream>>>(gat_W, wt1, FO, HID, 96, 896);
  fold_att<<<20, 96, 0, stream>>>(gat_W, att_src, att_dst, wt1);
  conv_wT_bf16<<<(896 * 800 + 255) / 256, 256, 0, stream>>>(gcn_W, wt2, HID, HID, 800, 896);
  conv_wT_bf16<<<(1536 * 1568 + 255) / 256, 256, 0, stream>>>(fcg1_W, wtg1, 1560, 1500, 1568, 1536);
  conv_wT_bf16<<<(128 * 1504 + 255) / 256, 256, 0, stream>>>(fcg2_W, wtg2, 1500, 128, 1504, 128);
  conv_wT_bf16<<<(128 * 3872 + 255) / 256, 256, 0, stream>>>(fc1xt_W, wtxt, 3872, 128, 3872, 128);
  conv_wT_bf16<<<(1024 * 256 + 255) / 256, 256, 0, stream>>>(fc1_W, wtf1, 256, 1024, 256, 1024);
  conv_wT_bf16<<<(512 * 1024 + 255) / 256, 256, 0, stream>>>(fc2_W, wtf2, 1024, 512, 1024, 512);

  // h = x @ gat_W (cols 0..779 -> buf0 f32), att dots (cols 780..799 -> att)
  gemm_mfma<false, false, false><<<dim3(7, N / 128), 256, 0, stream>>>(
      xb, wt1, buf0, att, nullptr, N, HID, 96, HID);

  int egrid = (ET + 255) / 256;
  count_dst<<<egrid, 256, 0, stream>>>(ei, E, N, cnt);
  scan_dinv<<<1, 1024, 0, stream>>>(cnt, offs, dinv, N);
  fill_csr<<<egrid, 256, 0, stream>>>(ei, E, N, offs, fillp, csr);

  gat_gather<<<N, 64, 0, stream>>>(buf0, att, offs, csr, gat_bias, x1b);

  // h2 = x1 @ gcn_W
  gemm_mfma<false, false, false><<<dim3(7, N / 128), 256, 0, stream>>>(
      x1b, wt2, buf0, nullptr, nullptr, N, HID, 800, HID);

  // fused GCN gather + per-graph max/mean pool -> gb bf16 [B][1568]
  gcn_pool<<<B, 256, 0, stream>>>(buf0, offs, csr, dinv, gcn_bias, batch, N, gb);

  // protein branch (buf0 free now)
  build_A<<<B, 256, 0, stream>>>(tgt, convW, Aprot);
  conv_xt<<<B, 256, 0, stream>>>(Aprot, embed, convb, convflat);

  // head: all bf16 MFMA with fused bias/act (buf1 free after gemm #2)
  // xt = convflat @ fc1xt_W + b -> xcb[:,128:]
  gemm_mfma<true, true, false><<<dim3(1, B / 128), 256, 0, stream>>>(
      convflat, wtxt, xcb + 128, nullptr, fc1xt_b, B, 128, 3872, 256);
  // g1 = relu(g @ fcg1_W + b) -> g1b [1024][1504]
  gemm_mfma<true, true, true><<<dim3(12, B / 128), 256, 0, stream>>>(
      gb, wtg1, g1b, nullptr, fcg1_b, B, 1500, 1568, 1504);
  // g2 = g1 @ fcg2_W + b -> xcb[:,0:128]
  gemm_mfma<true, true, false><<<dim3(1, B / 128), 256, 0, stream>>>(
      g1b, wtg2, xcb, nullptr, fcg2_b, B, 128, 1504, 256);
  // z1 = relu(xc @ fc1_W + b)
  gemm_mfma<true, true, true><<<dim3(8, B / 128), 256, 0, stream>>>(
      xcb, wtf1, z1b, nullptr, fc1_b, B, 1024, 256, 1024);
  // z2 = relu(z1 @ fc2_W + b)
  gemm_mfma<true, true, true><<<dim3(4, B / 128), 256, 0, stream>>>(
      z1b, wtf2, z2b, nullptr, fc2_b, B, 512, 1024, 512);

  final_out<<<B / 4, 256, 0, stream>>>(z2b, out_W, out_b, (float*)d_out);
}

// Round 8
// 1023.226 us; speedup vs baseline: 4.7024x; 1.0481x over previous
//
#include <hip/hip_runtime.h>

typedef __attribute__((ext_vector_type(4))) float f32x4;
typedef __attribute__((ext_vector_type(8))) short bf16x8;
typedef unsigned short u16;

#define HID 780
#define NH 10
#define FO 78

__device__ inline u16 f2b(float f) {  // fp32 -> bf16 RNE
  unsigned u = __float_as_uint(f);
  unsigned r = (u + 0x7fff + ((u >> 16) & 1)) >> 16;
  return (u16)r;
}
__device__ inline float b2f(u16 b) { return __uint_as_float(((unsigned)b) << 16); }

// ---------------- bf16 MFMA GEMM, bf16 C out ----------------
// A row-major bf16 [M][KP], BT row-major bf16 [NP][KP], KP%32==0, M%128==0.
// C bf16 [M][ldc] with fused bias/relu; cols [Ncols, Ncols+20) -> att_out f32
// (if non-null), remaining cols [.., ldc) zeroed.
template<bool BIAS, bool RELU>
__global__ __launch_bounds__(256) void gemm_mfma(const u16* __restrict__ A,
    const u16* __restrict__ BT, u16* __restrict__ C, float* __restrict__ att_out,
    const float* __restrict__ bias, int M, int Ncols, int KP, int ldc)
{
  __shared__ u16 As[128 * 40];
  __shared__ u16 Bs[128 * 40];
  const int tid = threadIdx.x;
  const int row0 = blockIdx.y << 7, col0 = blockIdx.x << 7;
  const int l = tid & 63, wid = tid >> 6;
  const int wr = wid >> 1, wc = wid & 1;
  const int lr = l & 15, lk = l >> 4;
  f32x4 acc[4][4];
#pragma unroll
  for (int i = 0; i < 4; ++i)
#pragma unroll
    for (int j = 0; j < 4; ++j) acc[i][j] = (f32x4){0.f, 0.f, 0.f, 0.f};

  for (int k0 = 0; k0 < KP; k0 += 32) {
    __syncthreads();
#pragma unroll
    for (int i = 0; i < 2; ++i) {
      int c = tid + (i << 8);          // 0..511
      int row = c >> 2, off = c & 3;   // 128 rows x 4 chunks of 8 bf16
      *(uint4*)&As[row * 40 + off * 8] =
          *(const uint4*)(A + (size_t)(row0 + row) * KP + k0 + off * 8);
      *(uint4*)&Bs[row * 40 + off * 8] =
          *(const uint4*)(BT + (size_t)(col0 + row) * KP + k0 + off * 8);
    }
    __syncthreads();
    bf16x8 af[4], bfr[4];
#pragma unroll
    for (int fm = 0; fm < 4; ++fm)
      af[fm] = *(const bf16x8*)&As[(wr * 64 + fm * 16 + lr) * 40 + lk * 8];
#pragma unroll
    for (int fn = 0; fn < 4; ++fn)
      bfr[fn] = *(const bf16x8*)&Bs[(wc * 64 + fn * 16 + lr) * 40 + lk * 8];
#pragma unroll
    for (int fm = 0; fm < 4; ++fm)
#pragma unroll
      for (int fn = 0; fn < 4; ++fn)
        acc[fm][fn] = __builtin_amdgcn_mfma_f32_16x16x32_bf16(af[fm], bfr[fn], acc[fm][fn], 0, 0, 0);
  }
#pragma unroll
  for (int fm = 0; fm < 4; ++fm)
#pragma unroll
    for (int fn = 0; fn < 4; ++fn) {
      int col = col0 + wc * 64 + fn * 16 + lr;
      f32x4 v = acc[fm][fn];
      int rbase = row0 + wr * 64 + fm * 16 + lk * 4;
      if (col < Ncols) {
        float bb = BIAS ? bias[col] : 0.f;
#pragma unroll
        for (int j = 0; j < 4; ++j) {
          float vv = v[j] + bb;
          if (RELU) vv = vv > 0.f ? vv : 0.f;
          C[(size_t)(rbase + j) * ldc + col] = f2b(vv);
        }
      } else if (att_out != nullptr && col < Ncols + 20) {
        int c = col - Ncols;
#pragma unroll
        for (int j = 0; j < 4; ++j)
          att_out[(size_t)(rbase + j) * 20 + c] = v[j];
      } else if (col < ldc) {
#pragma unroll
        for (int j = 0; j < 4; ++j) C[(size_t)(rbase + j) * ldc + col] = 0;
      }
    }
}

// ---------------- conversions ----------------
__global__ void conv_x_bf16(const float* __restrict__ x, u16* __restrict__ xb, int M)
{
  int idx = blockIdx.x * 256 + threadIdx.x;
  if (idx >= M * 96) return;
  int r = idx / 96, c = idx - r * 96;
  xb[idx] = (c < FO) ? f2b(x[(size_t)r * FO + c]) : (u16)0;
}

// WT[n][k] (NP x KP) = bf16(W[k][n]) zero-padded
__global__ void conv_wT_bf16(const float* __restrict__ W, u16* __restrict__ WT,
                             int K, int N, int KP, int NP)
{
  int idx = blockIdx.x * 256 + threadIdx.x;
  if (idx >= NP * KP) return;
  int n = idx / KP, k = idx - n * KP;
  WT[idx] = (n < N && k < K) ? f2b(W[(size_t)k * N + n]) : (u16)0;
}

// fold attention vectors into wt1 rows 780..799
__global__ void fold_att(const float* __restrict__ gat_W,
    const float* __restrict__ asv, const float* __restrict__ adv,
    u16* __restrict__ wt1)
{
  int j = blockIdx.x;            // 0..19
  int k = threadIdx.x;           // 0..95
  if (k >= 96) return;
  float s = 0.f;
  if (k < FO) {
    int h = (j < 10) ? j : j - 10;
    const float* av = ((j < 10) ? asv : adv) + h * FO;
    const float* wr = gat_W + (size_t)k * HID + h * FO;
    for (int f = 0; f < FO; ++f) s += wr[f] * av[f];
  }
  wt1[(size_t)(HID + j) * 96 + k] = f2b(s);
}

// ---------------- CSR build ----------------
__global__ void count_dst(const int* __restrict__ ei, int E, int N, int* __restrict__ cnt)
{
  int e = blockIdx.x * 256 + threadIdx.x;
  if (e >= E + N) return;
  int dst = (e < E) ? ei[E + e] : (e - E);
  atomicAdd(&cnt[dst], 1);
}

__global__ __launch_bounds__(1024) void scan_dinv(const int* __restrict__ cnt,
    int* __restrict__ offs, float* __restrict__ dinv, int N)
{
  __shared__ int part[1024];
  int tid = threadIdx.x;
  int chunk = (N + 1023) >> 10;
  int b0 = tid * chunk, b1 = min(b0 + chunk, N);
  int s = 0;
  for (int i = b0; i < b1; ++i) s += cnt[i];
  part[tid] = s;
  __syncthreads();
  for (int off = 1; off < 1024; off <<= 1) {
    int v = part[tid];
    int add = (tid >= off) ? part[tid - off] : 0;
    __syncthreads();
    part[tid] = v + add;
    __syncthreads();
  }
  int run = (tid > 0) ? part[tid - 1] : 0;
  for (int i = b0; i < b1; ++i) {
    int c = cnt[i];
    offs[i] = run;
    dinv[i] = c > 0 ? rsqrtf((float)c) : 0.f;
    run += c;
  }
  if (tid == 1023) offs[N] = run;
}

__global__ void fill_csr(const int* __restrict__ ei, int E, int N,
    const int* __restrict__ offs, int* __restrict__ fillpos, int* __restrict__ csr_src)
{
  int e = blockIdx.x * 256 + threadIdx.x;
  if (e >= E + N) return;
  int src, dst;
  if (e < E) { src = ei[e]; dst = ei[E + e]; }
  else { src = e - E; dst = e - E; }
  int p = offs[dst] + atomicAdd(&fillpos[dst], 1);
  csr_src[p] = src;
}

// ---------------- GAT gather (chunked softmax), h bf16 [N][800] -> x1 bf16 [N][800] ----------------
#define CH 48
__global__ __launch_bounds__(64) void gat_gather(const u16* __restrict__ h,
    const float* __restrict__ att,
    const int* __restrict__ offs, const int* __restrict__ csr_src,
    const float* __restrict__ gat_bias, u16* __restrict__ x1b)
{
  int n = blockIdx.x, lane = threadIdx.x;
  int o0 = offs[n], deg = offs[n + 1] - o0;
  __shared__ float ad[NH], m[NH], ssum[NH];
  __shared__ float wbuf[CH][NH];
  __shared__ int slist[CH];
  __shared__ unsigned mu[NH];
  if (lane < NH) { ad[lane] = att[n * 20 + 10 + lane]; mu[lane] = 0u; ssum[lane] = 0.f; }
  __syncthreads();
  for (int idx = lane; idx < deg * NH; idx += 64) {
    int e = idx / NH, hd = idx - e * NH;
    int s = csr_src[o0 + e];
    float l = att[s * 20 + hd] + ad[hd];
    l = l > 0.f ? l : 0.2f * l;
    unsigned u = __float_as_uint(l);
    u = (u & 0x80000000u) ? ~u : (u | 0x80000000u);
    atomicMax(&mu[hd], u);
  }
  __syncthreads();
  if (lane < NH) {
    unsigned u = mu[lane];
    m[lane] = __uint_as_float((u & 0x80000000u) ? (u & 0x7fffffffu) : ~u);
  }
  int hidx[13];
#pragma unroll
  for (int i = 0; i < 13; ++i) { int f = lane + 64 * i; hidx[i] = (f < HID) ? (f / FO) : 0; }
  float acc[13];
#pragma unroll
  for (int i = 0; i < 13; ++i) acc[i] = 0.f;

  for (int e0 = 0; e0 < deg; e0 += CH) {
    int ce = min(CH, deg - e0);
    __syncthreads();
    for (int idx = lane; idx < ce * NH; idx += 64) {
      int e = idx / NH, hd = idx - e * NH;
      int s = csr_src[o0 + e0 + e];
      float l = att[s * 20 + hd] + ad[hd];
      l = l > 0.f ? l : 0.2f * l;
      float w = __expf(l - m[hd]);
      wbuf[e][hd] = w;
      atomicAdd(&ssum[hd], w);
    }
    for (int idx = lane; idx < ce; idx += 64) slist[idx] = csr_src[o0 + e0 + idx];
    __syncthreads();
    for (int e = 0; e < ce; ++e) {
      const u16* hs = h + (size_t)slist[e] * 800;
#pragma unroll
      for (int i = 0; i < 13; ++i) {
        int f = lane + 64 * i;
        if (f < HID) acc[i] += wbuf[e][hidx[i]] * b2f(hs[f]);
      }
    }
  }
  __syncthreads();
#pragma unroll
  for (int i = 0; i < 13; ++i) {
    int f = lane + 64 * i;
    if (f < HID) {
      float v = acc[i] / (ssum[hidx[i]] + 1e-16f) + gat_bias[f];
      x1b[(size_t)n * 800 + f] = f2b(v > 0.f ? v : 0.f);
    }
  }
  if (lane < 20) x1b[(size_t)n * 800 + HID + lane] = 0;
}

// ---------------- GCN gather + per-graph pooling, h2 bf16 [N][800] -> gb bf16 [B][1568] ----------------
__global__ __launch_bounds__(256) void gcn_pool(const u16* __restrict__ h2,
    const int* __restrict__ offs, const int* __restrict__ csr_src,
    const float* __restrict__ dinv, const float* __restrict__ gcn_bias,
    const int* __restrict__ batch, int N, u16* __restrict__ gb)
{
  int gi = blockIdx.x, tid = threadIdx.x;
  int grp = tid >> 6, lane = tid & 63;
  __shared__ int se[2];
  __shared__ float smx[HID];
  __shared__ float ssm[HID];
  for (int f = tid; f < HID; f += 256) { smx[f] = 0.f; ssm[f] = 0.f; }
  if (tid < 2) {
    int target = gi + tid;
    int lo = 0, hi = N;
    while (lo < hi) { int mid = (lo + hi) >> 1; if (batch[mid] < target) lo = mid + 1; else hi = mid; }
    se[tid] = lo;
  }
  __syncthreads();
  int s = se[0], e = se[1];
  float mx[13], sm[13];
#pragma unroll
  for (int i = 0; i < 13; ++i) { mx[i] = 0.f; sm[i] = 0.f; }
  for (int n = s + grp; n < e; n += 4) {
    int o0 = offs[n], deg = offs[n + 1] - o0;
    float dn = dinv[n];
    float acc[13];
#pragma unroll
    for (int i = 0; i < 13; ++i) acc[i] = 0.f;
    for (int ed = 0; ed < deg; ++ed) {
      int src = csr_src[o0 + ed];
      float c = dn * dinv[src];
      const u16* hr = h2 + (size_t)src * 800;
#pragma unroll
      for (int i = 0; i < 13; ++i) {
        int f = lane + 64 * i;
        if (f < HID) acc[i] += c * b2f(hr[f]);
      }
    }
#pragma unroll
    for (int i = 0; i < 13; ++i) {
      int f = lane + 64 * i;
      if (f < HID) {
        float v = acc[i] + gcn_bias[f];
        v = v > 0.f ? v : 0.f;
        mx[i] = fmaxf(mx[i], v);
        sm[i] += v;
      }
    }
  }
#pragma unroll
  for (int i = 0; i < 13; ++i) {
    int f = lane + 64 * i;
    if (f < HID) {
      atomicMax((unsigned*)&smx[f], __float_as_uint(mx[i]));
      atomicAdd(&ssm[f], sm[i]);
    }
  }
  __syncthreads();
  float inv = 1.f / fmaxf((float)(e - s), 1.f);
  for (int f = tid; f < HID; f += 256) {
    gb[(size_t)gi * 1568 + f] = f2b(smx[f]);
    gb[(size_t)gi * 1568 + HID + f] = f2b(ssm[f] * inv);
  }
  if (tid < 8) gb[(size_t)gi * 1568 + 1560 + tid] = 0;
}

// ---------------- protein branch ----------------
__global__ __launch_bounds__(256) void build_A(const int* __restrict__ tgt,
    const float* __restrict__ W, float* __restrict__ Aout)
{
  int b = blockIdx.x, tid = threadIdx.x;
  __shared__ unsigned char tl[1000];
  __shared__ int vcnt[26], voff[27], vfill[26];
  __shared__ short vlist[1000];
  if (tid < 26) { vcnt[tid] = 0; vfill[tid] = 0; }
  __syncthreads();
  for (int i = tid; i < 1000; i += 256) {
    int v = tgt[b * 1000 + i];
    tl[i] = (unsigned char)v;
    atomicAdd(&vcnt[v], 1);
  }
  __syncthreads();
  if (tid == 0) { int r = 0; for (int v = 0; v < 26; ++v) { voff[v] = r; r += vcnt[v]; } voff[26] = r; }
  __syncthreads();
  for (int i = tid; i < 1000; i += 256) {
    int v = tl[i];
    int p = voff[v] + atomicAdd(&vfill[v], 1);
    vlist[p] = (short)i;
  }
  __syncthreads();
  int o = tid >> 3, k = tid & 7;
  const float* Wok = W + o * 8000 + k;
  float* Ao = Aout + (size_t)b * 6656;
  for (int v = 0; v < 26; ++v) {
    float a = 0.f;
    int s = voff[v], e = voff[v + 1];
    for (int j = s; j < e; ++j) a += Wok[(int)vlist[j] * 8];
    Ao[v * 256 + tid] = a;
  }
}

// conv output written as bf16 [B][3872]
__global__ __launch_bounds__(256) void conv_xt(const float* __restrict__ Aall,
    const float* __restrict__ embed, const float* __restrict__ cbias,
    u16* __restrict__ out)
{
  int b = blockIdx.x, tid = threadIdx.x;
  __shared__ __align__(16) float Al[6656];
  __shared__ __align__(16) float el[3360];
  const float* Ab = Aall + (size_t)b * 6656;
  for (int i = tid; i < 6656; i += 256) Al[i] = Ab[i];
  for (int i = tid; i < 3328; i += 256) el[i] = embed[i];
  if (tid < 32) el[3328 + tid] = 0.f;
  __syncthreads();
  for (int grp = tid; grp < 512; grp += 256) {
    int o = grp >> 4;
    int l0 = (grp & 15) << 3;
    float cb = cbias[o];
    float acc[8];
#pragma unroll
    for (int j = 0; j < 8; ++j) acc[j] = cb;
    for (int v = 0; v < 26; ++v) {
      const float* ap = &Al[v * 256 + (o << 3)];
      f32x4 a0 = *(const f32x4*)ap;
      f32x4 a1 = *(const f32x4*)(ap + 4);
      const float* ep = &el[v * 128 + l0];
      f32x4 e0 = *(const f32x4*)ep;
      f32x4 e1 = *(const f32x4*)(ep + 4);
      f32x4 e2 = *(const f32x4*)(ep + 8);
      f32x4 e3 = *(const f32x4*)(ep + 12);
      float a[8] = { a0[0], a0[1], a0[2], a0[3], a1[0], a1[1], a1[2], a1[3] };
      float e[16] = { e0[0], e0[1], e0[2], e0[3], e1[0], e1[1], e1[2], e1[3],
                      e2[0], e2[1], e2[2], e2[3], e3[0], e3[1], e3[2], e3[3] };
#pragma unroll
      for (int k = 0; k < 8; ++k)
#pragma unroll
        for (int j = 0; j < 8; ++j) acc[j] += a[k] * e[k + j];
    }
    int base = o * 121 + l0;
#pragma unroll
    for (int j = 0; j < 8; ++j)
      if (l0 + j < 121) out[(size_t)b * 3872 + base + j] = f2b(acc[j]);
  }
}

// ---------------- final row-dot (bf16 input) ----------------
__global__ __launch_bounds__(256) void final_out(const u16* __restrict__ z2,
    const float* __restrict__ W, const float* __restrict__ bias, float* __restrict__ out)
{
  int row = blockIdx.x * 4 + (threadIdx.x >> 6);
  int lane = threadIdx.x & 63;
  const u16* zr = z2 + (size_t)row * 512;
  float s = 0.f;
  for (int i = lane; i < 512; i += 64) s += b2f(zr[i]) * W[i];
#pragma unroll
  for (int off = 32; off > 0; off >>= 1) s += __shfl_down(s, off, 64);
  if (lane == 0) out[row] = s + bias[0];
}

// ---------------- launch ----------------
extern "C" void kernel_launch(void* const* d_in, const int* in_sizes, int n_in,
                              void* d_out, int out_size, void* d_ws, size_t ws_size,
                              hipStream_t stream)
{
  const float* x        = (const float*)d_in[0];
  const int*   ei       = (const int*)d_in[1];
  const int*   batch    = (const int*)d_in[2];
  const int*   tgt      = (const int*)d_in[3];
  const float* gat_W    = (const float*)d_in[4];
  const float* att_src  = (const float*)d_in[5];
  const float* att_dst  = (const float*)d_in[6];
  const float* gat_bias = (const float*)d_in[7];
  const float* gcn_W    = (const float*)d_in[8];
  const float* gcn_bias = (const float*)d_in[9];
  const float* fcg1_W   = (const float*)d_in[10];
  const float* fcg1_b   = (const float*)d_in[11];
  const float* fcg2_W   = (const float*)d_in[12];
  const float* fcg2_b   = (const float*)d_in[13];
  const float* embed    = (const float*)d_in[14];
  const float* convW    = (const float*)d_in[15];
  const float* convb    = (const float*)d_in[16];
  const float* fc1xt_W  = (const float*)d_in[17];
  const float* fc1xt_b  = (const float*)d_in[18];
  const float* fc1_W    = (const float*)d_in[19];
  const float* fc1_b    = (const float*)d_in[20];
  const float* fc2_W    = (const float*)d_in[21];
  const float* fc2_b    = (const float*)d_in[22];
  const float* out_W    = (const float*)d_in[23];
  const float* out_b    = (const float*)d_in[24];

  const int N = in_sizes[0] / FO;      // 40960
  const int E = in_sizes[1] / 2;       // 163840
  const int B = in_sizes[3] / 1000;    // 1024
  const int ET = E + N;

  char* ws = (char*)d_ws;
  size_t off = 0;
  auto alloc = [&](size_t bytes) -> char* {
    char* p = ws + off;
    off = (off + bytes + 255) & ~(size_t)255;
    return p;
  };
  float* buf0  = (float*)alloc((size_t)N * HID * 4);   // h/h2 bf16 -> Aprot/convflat
  float* buf1  = (float*)alloc((size_t)N * 800 * 2);   // xb -> x1b -> head scratch
  u16*   wt1   = (u16*)alloc((size_t)896 * 96 * 2);
  u16*   wt2   = (u16*)alloc((size_t)896 * 800 * 2);
  u16*   wtg1  = (u16*)alloc((size_t)1536 * 1568 * 2);
  u16*   wtg2  = (u16*)alloc((size_t)128 * 1504 * 2);
  u16*   wtxt  = (u16*)alloc((size_t)128 * 3872 * 2);
  u16*   wtf1  = (u16*)alloc((size_t)1024 * 256 * 2);
  u16*   wtf2  = (u16*)alloc((size_t)512 * 1024 * 2);
  float* att   = (float*)alloc((size_t)N * 20 * 4);
  int*   cnt   = (int*)alloc((size_t)N * 4);
  int*   offs  = (int*)alloc((size_t)(N + 1) * 4);
  int*   fillp = (int*)alloc((size_t)N * 4);
  int*   csr   = (int*)alloc((size_t)ET * 4);
  float* dinv  = (float*)alloc((size_t)N * 4);
  u16*   gb    = (u16*)alloc((size_t)B * 1568 * 2);

  u16*   xb    = (u16*)buf1;                 // dead after gemm #1
  u16*   x1b   = (u16*)buf1;                 // gat_gather -> gemm #2
  u16*   hb    = (u16*)buf0;                 // h / h2 bf16 [N][800]
  float* Aprot       = buf0;                 // after gcn_pool
  u16*   convflat    = (u16*)(buf0 + (size_t)6656 * B);   // bf16 [B][3872]
  // head scratch in buf1 (after gemm #2 consumed x1b)
  u16* g1b = (u16*)buf1;                     // [1024][1504]
  u16* xcb = g1b + (size_t)1024 * 1504;      // [1024][256] (g2 | xt)
  u16* z1b = xcb + (size_t)1024 * 256;       // [1024][1024]
  u16* z2b = z1b + (size_t)1024 * 1024;      // [1024][512]

  hipMemsetAsync(cnt, 0, (size_t)N * 4, stream);
  hipMemsetAsync(fillp, 0, (size_t)N * 4, stream);

  // conversions + attention fold
  conv_x_bf16<<<(N * 96 + 255) / 256, 256, 0, stream>>>(x, xb, N);
  conv_wT_bf16<<<(896 * 96 + 255) / 256, 256, 0, stream>>>(gat_W, wt1, FO, HID, 96, 896);
  fold_att<<<20, 96, 0, stream>>>(gat_W, att_src, att_dst, wt1);
  conv_wT_bf16<<<(896 * 800 + 255) / 256, 256, 0, stream>>>(gcn_W, wt2, HID, HID, 800, 896);
  conv_wT_bf16<<<(1536 * 1568 + 255) / 256, 256, 0, stream>>>(fcg1_W, wtg1, 1560, 1500, 1568, 1536);
  conv_wT_bf16<<<(128 * 1504 + 255) / 256, 256, 0, stream>>>(fcg2_W, wtg2, 1500, 128, 1504, 128);
  conv_wT_bf16<<<(128 * 3872 + 255) / 256, 256, 0, stream>>>(fc1xt_W, wtxt, 3872, 128, 3872, 128);
  conv_wT_bf16<<<(1024 * 256 + 255) / 256, 256, 0, stream>>>(fc1_W, wtf1, 256, 1024, 256, 1024);
  conv_wT_bf16<<<(512 * 1024 + 255) / 256, 256, 0, stream>>>(fc2_W, wtf2, 1024, 512, 1024, 512);

  // h = x @ gat_W -> hb bf16 [N][800]; att dots (cols 780..799) -> att f32
  gemm_mfma<false, false><<<dim3(7, N / 128), 256, 0, stream>>>(
      xb, wt1, hb, att, nullptr, N, HID, 96, 800);

  int egrid = (ET + 255) / 256;
  count_dst<<<egrid, 256, 0, stream>>>(ei, E, N, cnt);
  scan_dinv<<<1, 1024, 0, stream>>>(cnt, offs, dinv, N);
  fill_csr<<<egrid, 256, 0, stream>>>(ei, E, N, offs, fillp, csr);

  gat_gather<<<N, 64, 0, stream>>>(hb, att, offs, csr, gat_bias, x1b);

  // h2 = x1 @ gcn_W -> hb bf16 [N][800]
  gemm_mfma<false, false><<<dim3(7, N / 128), 256, 0, stream>>>(
      x1b, wt2, hb, nullptr, nullptr, N, HID, 800, 800);

  // fused GCN gather + per-graph max/mean pool -> gb bf16 [B][1568]
  gcn_pool<<<B, 256, 0, stream>>>(hb, offs, csr, dinv, gcn_bias, batch, N, gb);

  // protein branch (buf0 free now)
  build_A<<<B, 256, 0, stream>>>(tgt, convW, Aprot);
  conv_xt<<<B, 256, 0, stream>>>(Aprot, embed, convb, convflat);

  // head: all bf16 MFMA with fused bias/act (buf1 free after gemm #2)
  gemm_mfma<true, false><<<dim3(1, B / 128), 256, 0, stream>>>(
      convflat, wtxt, xcb + 128, nullptr, fc1xt_b, B, 128, 3872, 256);
  gemm_mfma<true, true><<<dim3(12, B / 128), 256, 0, stream>>>(
      gb, wtg1, g1b, nullptr, fcg1_b, B, 1500, 1568, 1504);
  gemm_mfma<true, false><<<dim3(1, B / 128), 256, 0, stream>>>(
      g1b, wtg2, xcb, nullptr, fcg2_b, B, 128, 1504, 256);
  gemm_mfma<true, true><<<dim3(8, B / 128), 256, 0, stream>>>(
      xcb, wtf1, z1b, nullptr, fc1_b, B, 1024, 256, 1024);
  gemm_mfma<true, true><<<dim3(4, B / 128), 256, 0, stream>>>(
      z1b, wtf2, z2b, nullptr, fc2_b, B, 512, 1024, 512);

  final_out<<<B / 4, 256, 0, stream>>>(z2b, out_W, out_b, (float*)d_out);
}

// Round 9
// 909.601 us; speedup vs baseline: 5.2898x; 1.1249x over previous
//
#include <hip/hip_runtime.h>

typedef __attribute__((ext_vector_type(4))) float f32x4;
typedef __attribute__((ext_vector_type(8))) short bf16x8;
typedef __attribute__((ext_vector_type(8))) unsigned short u16x8;
typedef unsigned short u16;

#define HID 780
#define NH 10
#define FO 78

__device__ inline u16 f2b(float f) {  // fp32 -> bf16 RNE
  unsigned u = __float_as_uint(f);
  unsigned r = (u + 0x7fff + ((u >> 16) & 1)) >> 16;
  return (u16)r;
}
__device__ inline float b2f(u16 b) { return __uint_as_float(((unsigned)b) << 16); }

// ---------------- bf16 MFMA GEMM, bf16 C out ----------------
// A row-major bf16 [M][KP], BT row-major bf16 [NP][KP], KP%32==0, M%128==0.
// C bf16 [M][ldc] fused bias/relu; cols [Ncols,Ncols+20) -> att_out f32 (if set);
// all cols in [Ncols, ldc) of C are zeroed.
template<bool BIAS, bool RELU>
__global__ __launch_bounds__(256) void gemm_mfma(const u16* __restrict__ A,
    const u16* __restrict__ BT, u16* __restrict__ C, float* __restrict__ att_out,
    const float* __restrict__ bias, int M, int Ncols, int KP, int ldc)
{
  __shared__ u16 As[128 * 40];
  __shared__ u16 Bs[128 * 40];
  const int tid = threadIdx.x;
  const int row0 = blockIdx.y << 7, col0 = blockIdx.x << 7;
  const int l = tid & 63, wid = tid >> 6;
  const int wr = wid >> 1, wc = wid & 1;
  const int lr = l & 15, lk = l >> 4;
  f32x4 acc[4][4];
#pragma unroll
  for (int i = 0; i < 4; ++i)
#pragma unroll
    for (int j = 0; j < 4; ++j) acc[i][j] = (f32x4){0.f, 0.f, 0.f, 0.f};

  for (int k0 = 0; k0 < KP; k0 += 32) {
    __syncthreads();
#pragma unroll
    for (int i = 0; i < 2; ++i) {
      int c = tid + (i << 8);          // 0..511
      int row = c >> 2, off = c & 3;   // 128 rows x 4 chunks of 8 bf16
      *(uint4*)&As[row * 40 + off * 8] =
          *(const uint4*)(A + (size_t)(row0 + row) * KP + k0 + off * 8);
      *(uint4*)&Bs[row * 40 + off * 8] =
          *(const uint4*)(BT + (size_t)(col0 + row) * KP + k0 + off * 8);
    }
    __syncthreads();
    bf16x8 af[4], bfr[4];
#pragma unroll
    for (int fm = 0; fm < 4; ++fm)
      af[fm] = *(const bf16x8*)&As[(wr * 64 + fm * 16 + lr) * 40 + lk * 8];
#pragma unroll
    for (int fn = 0; fn < 4; ++fn)
      bfr[fn] = *(const bf16x8*)&Bs[(wc * 64 + fn * 16 + lr) * 40 + lk * 8];
#pragma unroll
    for (int fm = 0; fm < 4; ++fm)
#pragma unroll
      for (int fn = 0; fn < 4; ++fn)
        acc[fm][fn] = __builtin_amdgcn_mfma_f32_16x16x32_bf16(af[fm], bfr[fn], acc[fm][fn], 0, 0, 0);
  }
#pragma unroll
  for (int fm = 0; fm < 4; ++fm)
#pragma unroll
    for (int fn = 0; fn < 4; ++fn) {
      int col = col0 + wc * 64 + fn * 16 + lr;
      f32x4 v = acc[fm][fn];
      int rbase = row0 + wr * 64 + fm * 16 + lk * 4;
      if (col < Ncols) {
        float bb = BIAS ? bias[col] : 0.f;
#pragma unroll
        for (int j = 0; j < 4; ++j) {
          float vv = v[j] + bb;
          if (RELU) vv = vv > 0.f ? vv : 0.f;
          C[(size_t)(rbase + j) * ldc + col] = f2b(vv);
        }
      } else {
        if (att_out != nullptr && col < Ncols + 20) {
          int c = col - Ncols;
#pragma unroll
          for (int j = 0; j < 4; ++j)
            att_out[(size_t)(rbase + j) * 20 + c] = v[j];
        }
        if (col < ldc) {
#pragma unroll
          for (int j = 0; j < 4; ++j) C[(size_t)(rbase + j) * ldc + col] = 0;
        }
      }
    }
}

// ---------------- conversions ----------------
__global__ void conv_x_bf16(const float* __restrict__ x, u16* __restrict__ xb, int M)
{
  int idx = blockIdx.x * 256 + threadIdx.x;
  if (idx >= M * 96) return;
  int r = idx / 96, c = idx - r * 96;
  xb[idx] = (c < FO) ? f2b(x[(size_t)r * FO + c]) : (u16)0;
}

// WT[n][k] (NP x KP) = bf16(W[k][n]) zero-padded
__global__ void conv_wT_bf16(const float* __restrict__ W, u16* __restrict__ WT,
                             int K, int N, int KP, int NP)
{
  int idx = blockIdx.x * 256 + threadIdx.x;
  if (idx >= NP * KP) return;
  int n = idx / KP, k = idx - n * KP;
  WT[idx] = (n < N && k < K) ? f2b(W[(size_t)k * N + n]) : (u16)0;
}

// fold attention vectors into wt1 rows 780..799
__global__ void fold_att(const float* __restrict__ gat_W,
    const float* __restrict__ asv, const float* __restrict__ adv,
    u16* __restrict__ wt1)
{
  int j = blockIdx.x;            // 0..19
  int k = threadIdx.x;           // 0..95
  if (k >= 96) return;
  float s = 0.f;
  if (k < FO) {
    int h = (j < 10) ? j : j - 10;
    const float* av = ((j < 10) ? asv : adv) + h * FO;
    const float* wr = gat_W + (size_t)k * HID + h * FO;
    for (int f = 0; f < FO; ++f) s += wr[f] * av[f];
  }
  wt1[(size_t)(HID + j) * 96 + k] = f2b(s);
}

// ---------------- CSR build ----------------
__global__ void count_dst(const int* __restrict__ ei, int E, int N, int* __restrict__ cnt)
{
  int e = blockIdx.x * 256 + threadIdx.x;
  if (e >= E + N) return;
  int dst = (e < E) ? ei[E + e] : (e - E);
  atomicAdd(&cnt[dst], 1);
}

__global__ __launch_bounds__(1024) void scan_dinv(const int* __restrict__ cnt,
    int* __restrict__ offs, float* __restrict__ dinv, int N)
{
  __shared__ int part[1024];
  int tid = threadIdx.x;
  int chunk = (N + 1023) >> 10;
  int b0 = tid * chunk, b1 = min(b0 + chunk, N);
  int s = 0;
  for (int i = b0; i < b1; ++i) s += cnt[i];
  part[tid] = s;
  __syncthreads();
  for (int off = 1; off < 1024; off <<= 1) {
    int v = part[tid];
    int add = (tid >= off) ? part[tid - off] : 0;
    __syncthreads();
    part[tid] = v + add;
    __syncthreads();
  }
  int run = (tid > 0) ? part[tid - 1] : 0;
  for (int i = b0; i < b1; ++i) {
    int c = cnt[i];
    offs[i] = run;
    dinv[i] = c > 0 ? rsqrtf((float)c) : 0.f;
    run += c;
  }
  if (tid == 1023) offs[N] = run;
}

__global__ void fill_csr(const int* __restrict__ ei, int E, int N,
    const int* __restrict__ offs, int* __restrict__ fillpos, int* __restrict__ csr_src)
{
  int e = blockIdx.x * 256 + threadIdx.x;
  if (e >= E + N) return;
  int src, dst;
  if (e < E) { src = ei[e]; dst = ei[E + e]; }
  else { src = e - E; dst = e - E; }
  int p = offs[dst] + atomicAdd(&fillpos[dst], 1);
  csr_src[p] = src;
}

// ---------------- GAT gather: single-pass softmax (no max; logits O(1)), u16x8 gather ----------------
#define CH 48
__global__ __launch_bounds__(64) void gat_gather(const u16* __restrict__ h,
    const float* __restrict__ att,
    const int* __restrict__ offs, const int* __restrict__ csr_src,
    const float* __restrict__ gat_bias, u16* __restrict__ x1b)
{
  int n = blockIdx.x, lane = threadIdx.x;
  int o0 = offs[n], deg = offs[n + 1] - o0;
  __shared__ float ad[NH], ssum[NH];
  __shared__ float wbuf[CH][NH];
  __shared__ int slist[CH];
  if (lane < NH) { ad[lane] = att[n * 20 + 10 + lane]; ssum[lane] = 0.f; }
  // slots: s0 = lane (cols lane*8..+7, all <512), s1 = 64+lane (cols 512..799)
  const int s0 = lane, s1 = 64 + lane;
  const bool a1 = s1 < 100;
  int hA0 = min((s0 * 8) / FO, NH - 1), bb0 = FO * ((s0 * 8) / FO + 1) - s0 * 8;
  int hB0 = min((s0 * 8) / FO + 1, NH - 1);
  int hA1 = min((s1 * 8) / FO, NH - 1), bb1 = FO * ((s1 * 8) / FO + 1) - s1 * 8;
  int hB1 = min((s1 * 8) / FO + 1, NH - 1);
  float acc0[8], acc1[8];
#pragma unroll
  for (int j = 0; j < 8; ++j) { acc0[j] = 0.f; acc1[j] = 0.f; }
  __syncthreads();

  for (int e0 = 0; e0 < deg; e0 += CH) {
    int ce = min(CH, deg - e0);
    for (int idx = lane; idx < ce * NH; idx += 64) {
      int e = idx / NH, hd = idx - e * NH;
      int s = csr_src[o0 + e0 + e];
      float l = att[s * 20 + hd] + ad[hd];
      l = l > 0.f ? l : 0.2f * l;
      float w = __expf(l);           // no max-shift: logits are O(1) here
      wbuf[e][hd] = w;
      atomicAdd(&ssum[hd], w);
    }
    for (int idx = lane; idx < ce; idx += 64) slist[idx] = csr_src[o0 + e0 + idx];
    __syncthreads();
    for (int e = 0; e < ce; ++e) {
      const u16* hs = h + (size_t)slist[e] * 800;
      u16x8 v0 = *(const u16x8*)(hs + s0 * 8);
      float wA0 = wbuf[e][hA0], wB0 = wbuf[e][hB0];
#pragma unroll
      for (int j = 0; j < 8; ++j)
        acc0[j] += (j < bb0 ? wA0 : wB0) * b2f(v0[j]);
      if (a1) {
        u16x8 v1 = *(const u16x8*)(hs + s1 * 8);
        float wA1 = wbuf[e][hA1], wB1 = wbuf[e][hB1];
#pragma unroll
        for (int j = 0; j < 8; ++j)
          acc1[j] += (j < bb1 ? wA1 : wB1) * b2f(v1[j]);
      }
    }
    __syncthreads();
  }
  // write x1 (bf16, cols >= 780 zeroed)
  float iA0 = 1.f / (ssum[hA0] + 1e-16f), iB0 = 1.f / (ssum[hB0] + 1e-16f);
  u16x8 o0v;
#pragma unroll
  for (int j = 0; j < 8; ++j) {
    int f = s0 * 8 + j;
    float v = acc0[j] * (j < bb0 ? iA0 : iB0) + gat_bias[f];
    o0v[j] = f2b(v > 0.f ? v : 0.f);
  }
  *(u16x8*)(x1b + (size_t)n * 800 + s0 * 8) = o0v;
  if (a1) {
    float iA1 = 1.f / (ssum[hA1] + 1e-16f), iB1 = 1.f / (ssum[hB1] + 1e-16f);
    u16x8 o1v;
#pragma unroll
    for (int j = 0; j < 8; ++j) {
      int f = s1 * 8 + j;
      if (f < HID) {
        float v = acc1[j] * (j < bb1 ? iA1 : iB1) + gat_bias[f];
        o1v[j] = f2b(v > 0.f ? v : 0.f);
      } else o1v[j] = 0;
    }
    *(u16x8*)(x1b + (size_t)n * 800 + s1 * 8) = o1v;
  }
}

// ---------------- GCN gather + per-graph pooling, u16x8 gather ----------------
__global__ __launch_bounds__(256) void gcn_pool(const u16* __restrict__ h2,
    const int* __restrict__ offs, const int* __restrict__ csr_src,
    const float* __restrict__ dinv, const float* __restrict__ gcn_bias,
    const int* __restrict__ batch, int N, u16* __restrict__ gb)
{
  int gi = blockIdx.x, tid = threadIdx.x;
  int grp = tid >> 6, lane = tid & 63;
  __shared__ int se[2];
  __shared__ float smx[HID];
  __shared__ float ssm[HID];
  for (int f = tid; f < HID; f += 256) { smx[f] = 0.f; ssm[f] = 0.f; }
  if (tid < 2) {
    int target = gi + tid;
    int lo = 0, hi = N;
    while (lo < hi) { int mid = (lo + hi) >> 1; if (batch[mid] < target) lo = mid + 1; else hi = mid; }
    se[tid] = lo;
  }
  __syncthreads();
  int s = se[0], e = se[1];
  const int s0 = lane, s1 = 64 + lane;
  const bool a1 = s1 < 100;
  float bv0[8], bv1[8];
#pragma unroll
  for (int j = 0; j < 8; ++j) {
    int f0 = s0 * 8 + j, f1 = s1 * 8 + j;
    bv0[j] = gcn_bias[f0];
    bv1[j] = (a1 && f1 < HID) ? gcn_bias[f1] : 0.f;
  }
  float mx0[8], sm0[8], mx1[8], sm1[8];
#pragma unroll
  for (int j = 0; j < 8; ++j) { mx0[j] = 0.f; sm0[j] = 0.f; mx1[j] = 0.f; sm1[j] = 0.f; }

  for (int n = s + grp; n < e; n += 4) {
    int o0 = offs[n], deg = offs[n + 1] - o0;
    float dn = dinv[n];
    float acc0[8], acc1[8];
#pragma unroll
    for (int j = 0; j < 8; ++j) { acc0[j] = 0.f; acc1[j] = 0.f; }
    for (int ed = 0; ed < deg; ++ed) {
      int src = csr_src[o0 + ed];
      float c = dn * dinv[src];
      const u16* hr = h2 + (size_t)src * 800;
      u16x8 v0 = *(const u16x8*)(hr + s0 * 8);
#pragma unroll
      for (int j = 0; j < 8; ++j) acc0[j] += c * b2f(v0[j]);
      if (a1) {
        u16x8 v1 = *(const u16x8*)(hr + s1 * 8);
#pragma unroll
        for (int j = 0; j < 8; ++j) acc1[j] += c * b2f(v1[j]);
      }
    }
#pragma unroll
    for (int j = 0; j < 8; ++j) {
      float v = acc0[j] + bv0[j];
      v = v > 0.f ? v : 0.f;
      mx0[j] = fmaxf(mx0[j], v); sm0[j] += v;
      float w = acc1[j] + bv1[j];
      w = w > 0.f ? w : 0.f;
      mx1[j] = fmaxf(mx1[j], w); sm1[j] += w;
    }
  }
  // combine the 4 groups (values >= 0 -> uint-ordered atomicMax valid)
#pragma unroll
  for (int j = 0; j < 8; ++j) {
    int f0 = s0 * 8 + j;
    atomicMax((unsigned*)&smx[f0], __float_as_uint(mx0[j]));
    atomicAdd(&ssm[f0], sm0[j]);
    int f1 = s1 * 8 + j;
    if (a1 && f1 < HID) {
      atomicMax((unsigned*)&smx[f1], __float_as_uint(mx1[j]));
      atomicAdd(&ssm[f1], sm1[j]);
    }
  }
  __syncthreads();
  float inv = 1.f / fmaxf((float)(e - s), 1.f);
  for (int f = tid; f < HID; f += 256) {
    gb[(size_t)gi * 1568 + f] = f2b(smx[f]);
    gb[(size_t)gi * 1568 + HID + f] = f2b(ssm[f] * inv);
  }
  if (tid < 8) gb[(size_t)gi * 1568 + 1560 + tid] = 0;
}

// ---------------- protein branch ----------------
__global__ __launch_bounds__(256) void build_A(const int* __restrict__ tgt,
    const float* __restrict__ W, float* __restrict__ Aout)
{
  int b = blockIdx.x, tid = threadIdx.x;
  __shared__ unsigned char tl[1000];
  __shared__ int vcnt[26], voff[27], vfill[26];
  __shared__ short vlist[1000];
  if (tid < 26) { vcnt[tid] = 0; vfill[tid] = 0; }
  __syncthreads();
  for (int i = tid; i < 1000; i += 256) {
    int v = tgt[b * 1000 + i];
    tl[i] = (unsigned char)v;
    atomicAdd(&vcnt[v], 1);
  }
  __syncthreads();
  if (tid == 0) { int r = 0; for (int v = 0; v < 26; ++v) { voff[v] = r; r += vcnt[v]; } voff[26] = r; }
  __syncthreads();
  for (int i = tid; i < 1000; i += 256) {
    int v = tl[i];
    int p = voff[v] + atomicAdd(&vfill[v], 1);
    vlist[p] = (short)i;
  }
  __syncthreads();
  int o = tid >> 3, k = tid & 7;
  const float* Wok = W + o * 8000 + k;
  float* Ao = Aout + (size_t)b * 6656;
  for (int v = 0; v < 26; ++v) {
    float a = 0.f;
    int s = voff[v], e = voff[v + 1];
    for (int j = s; j < e; ++j) a += Wok[(int)vlist[j] * 8];
    Ao[v * 256 + tid] = a;
  }
}

// conv output written as bf16 [B][3872]
__global__ __launch_bounds__(256) void conv_xt(const float* __restrict__ Aall,
    const float* __restrict__ embed, const float* __restrict__ cbias,
    u16* __restrict__ out)
{
  int b = blockIdx.x, tid = threadIdx.x;
  __shared__ __align__(16) float Al[6656];
  __shared__ __align__(16) float el[3360];
  const float* Ab = Aall + (size_t)b * 6656;
  for (int i = tid; i < 6656; i += 256) Al[i] = Ab[i];
  for (int i = tid; i < 3328; i += 256) el[i] = embed[i];
  if (tid < 32) el[3328 + tid] = 0.f;
  __syncthreads();
  for (int grp = tid; grp < 512; grp += 256) {
    int o = grp >> 4;
    int l0 = (grp & 15) << 3;
    float cb = cbias[o];
    float acc[8];
#pragma unroll
    for (int j = 0; j < 8; ++j) acc[j] = cb;
    for (int v = 0; v < 26; ++v) {
      const float* ap = &Al[v * 256 + (o << 3)];
      f32x4 a0 = *(const f32x4*)ap;
      f32x4 a1 = *(const f32x4*)(ap + 4);
      const float* ep = &el[v * 128 + l0];
      f32x4 e0 = *(const f32x4*)ep;
      f32x4 e1 = *(const f32x4*)(ep + 4);
      f32x4 e2 = *(const f32x4*)(ep + 8);
      f32x4 e3 = *(const f32x4*)(ep + 12);
      float a[8] = { a0[0], a0[1], a0[2], a0[3], a1[0], a1[1], a1[2], a1[3] };
      float e[16] = { e0[0], e0[1], e0[2], e0[3], e1[0], e1[1], e1[2], e1[3],
                      e2[0], e2[1], e2[2], e2[3], e3[0], e3[1], e3[2], e3[3] };
#pragma unroll
      for (int k = 0; k < 8; ++k)
#pragma unroll
        for (int j = 0; j < 8; ++j) acc[j] += a[k] * e[k + j];
    }
    int base = o * 121 + l0;
#pragma unroll
    for (int j = 0; j < 8; ++j)
      if (l0 + j < 121) out[(size_t)b * 3872 + base + j] = f2b(acc[j]);
  }
}

// ---------------- final row-dot (bf16 input) ----------------
__global__ __launch_bounds__(256) void final_out(const u16* __restrict__ z2,
    const float* __restrict__ W, const float* __restrict__ bias, float* __restrict__ out)
{
  int row = blockIdx.x * 4 + (threadIdx.x >> 6);
  int lane = threadIdx.x & 63;
  const u16* zr = z2 + (size_t)row * 512;
  float s = 0.f;
  for (int i = lane; i < 512; i += 64) s += b2f(zr[i]) * W[i];
#pragma unroll
  for (int off = 32; off > 0; off >>= 1) s += __shfl_down(s, off, 64);
  if (lane == 0) out[row] = s + bias[0];
}

// ---------------- launch ----------------
extern "C" void kernel_launch(void* const* d_in, const int* in_sizes, int n_in,
                              void* d_out, int out_size, void* d_ws, size_t ws_size,
                              hipStream_t stream)
{
  const float* x        = (const float*)d_in[0];
  const int*   ei       = (const int*)d_in[1];
  const int*   batch    = (const int*)d_in[2];
  const int*   tgt      = (const int*)d_in[3];
  const float* gat_W    = (const float*)d_in[4];
  const float* att_src  = (const float*)d_in[5];
  const float* att_dst  = (const float*)d_in[6];
  const float* gat_bias = (const float*)d_in[7];
  const float* gcn_W    = (const float*)d_in[8];
  const float* gcn_bias = (const float*)d_in[9];
  const float* fcg1_W   = (const float*)d_in[10];
  const float* fcg1_b   = (const float*)d_in[11];
  const float* fcg2_W   = (const float*)d_in[12];
  const float* fcg2_b   = (const float*)d_in[13];
  const float* embed    = (const float*)d_in[14];
  const float* convW    = (const float*)d_in[15];
  const float* convb    = (const float*)d_in[16];
  const float* fc1xt_W  = (const float*)d_in[17];
  const float* fc1xt_b  = (const float*)d_in[18];
  const float* fc1_W    = (const float*)d_in[19];
  const float* fc1_b    = (const float*)d_in[20];
  const float* fc2_W    = (const float*)d_in[21];
  const float* fc2_b    = (const float*)d_in[22];
  const float* out_W    = (const float*)d_in[23];
  const float* out_b    = (const float*)d_in[24];

  const int N = in_sizes[0] / FO;      // 40960
  const int E = in_sizes[1] / 2;       // 163840
  const int B = in_sizes[3] / 1000;    // 1024
  const int ET = E + N;

  char* ws = (char*)d_ws;
  size_t off = 0;
  auto alloc = [&](size_t bytes) -> char* {
    char* p = ws + off;
    off = (off + bytes + 255) & ~(size_t)255;
    return p;
  };
  float* buf0  = (float*)alloc((size_t)N * HID * 4);   // h/h2 bf16 -> Aprot/convflat
  float* buf1  = (float*)alloc((size_t)N * 800 * 2);   // xb -> x1b -> head scratch
  u16*   wt1   = (u16*)alloc((size_t)896 * 96 * 2);
  u16*   wt2   = (u16*)alloc((size_t)896 * 800 * 2);
  u16*   wtg1  = (u16*)alloc((size_t)1536 * 1568 * 2);
  u16*   wtg2  = (u16*)alloc((size_t)128 * 1504 * 2);
  u16*   wtxt  = (u16*)alloc((size_t)128 * 3872 * 2);
  u16*   wtf1  = (u16*)alloc((size_t)1024 * 256 * 2);
  u16*   wtf2  = (u16*)alloc((size_t)512 * 1024 * 2);
  float* att   = (float*)alloc((size_t)N * 20 * 4);
  int*   cnt   = (int*)alloc((size_t)N * 4);
  int*   offs  = (int*)alloc((size_t)(N + 1) * 4);
  int*   fillp = (int*)alloc((size_t)N * 4);
  int*   csr   = (int*)alloc((size_t)ET * 4);
  float* dinv  = (float*)alloc((size_t)N * 4);
  u16*   gb    = (u16*)alloc((size_t)B * 1568 * 2);

  u16*   xb    = (u16*)buf1;                 // dead after gemm #1
  u16*   x1b   = (u16*)buf1;                 // gat_gather -> gemm #2
  u16*   hb    = (u16*)buf0;                 // h / h2 bf16 [N][800]
  float* Aprot       = buf0;                 // after gcn_pool
  u16*   convflat    = (u16*)(buf0 + (size_t)6656 * B);   // bf16 [B][3872]
  // head scratch in buf1 (after gemm #2 consumed x1b)
  u16* g1b = (u16*)buf1;                     // [1024][1504]
  u16* xcb = g1b + (size_t)1024 * 1504;      // [1024][256] (g2 | xt)
  u16* z1b = xcb + (size_t)1024 * 256;       // [1024][1024]
  u16* z2b = z1b + (size_t)1024 * 1024;      // [1024][512]

  hipMemsetAsync(cnt, 0, (size_t)N * 4, stream);
  hipMemsetAsync(fillp, 0, (size_t)N * 4, stream);

  // conversions + attention fold
  conv_x_bf16<<<(N * 96 + 255) / 256, 256, 0, stream>>>(x, xb, N);
  conv_wT_bf16<<<(896 * 96 + 255) / 256, 256, 0, stream>>>(gat_W, wt1, FO, HID, 96, 896);
  fold_att<<<20, 96, 0, stream>>>(gat_W, att_src, att_dst, wt1);
  conv_wT_bf16<<<(896 * 800 + 255) / 256, 256, 0, stream>>>(gcn_W, wt2, HID, HID, 800, 896);
  conv_wT_bf16<<<(1536 * 1568 + 255) / 256, 256, 0, stream>>>(fcg1_W, wtg1, 1560, 1500, 1568, 1536);
  conv_wT_bf16<<<(128 * 1504 + 255) / 256, 256, 0, stream>>>(fcg2_W, wtg2, 1500, 128, 1504, 128);
  conv_wT_bf16<<<(128 * 3872 + 255) / 256, 256, 0, stream>>>(fc1xt_W, wtxt, 3872, 128, 3872, 128);
  conv_wT_bf16<<<(1024 * 256 + 255) / 256, 256, 0, stream>>>(fc1_W, wtf1, 256, 1024, 256, 1024);
  conv_wT_bf16<<<(512 * 1024 + 255) / 256, 256, 0, stream>>>(fc2_W, wtf2, 1024, 512, 1024, 512);

  // h = x @ gat_W -> hb bf16 [N][800] (cols 780+ zeroed); att dots -> att f32
  gemm_mfma<false, false><<<dim3(7, N / 128), 256, 0, stream>>>(
      xb, wt1, hb, att, nullptr, N, HID, 96, 800);

  int egrid = (ET + 255) / 256;
  count_dst<<<egrid, 256, 0, stream>>>(ei, E, N, cnt);
  scan_dinv<<<1, 1024, 0, stream>>>(cnt, offs, dinv, N);
  fill_csr<<<egrid, 256, 0, stream>>>(ei, E, N, offs, fillp, csr);

  gat_gather<<<N, 64, 0, stream>>>(hb, att, offs, csr, gat_bias, x1b);

  // h2 = x1 @ gcn_W -> hb bf16 [N][800]
  gemm_mfma<false, false><<<dim3(7, N / 128), 256, 0, stream>>>(
      x1b, wt2, hb, nullptr, nullptr, N, HID, 800, 800);

  // fused GCN gather + per-graph max/mean pool -> gb bf16 [B][1568]
  gcn_pool<<<B, 256, 0, stream>>>(hb, offs, csr, dinv, gcn_bias, batch, N, gb);

  // protein branch (buf0 free now)
  build_A<<<B, 256, 0, stream>>>(tgt, convW, Aprot);
  conv_xt<<<B, 256, 0, stream>>>(Aprot, embed, convb, convflat);

  // head: all bf16 MFMA with fused bias/act (buf1 free after gemm #2)
  gemm_mfma<true, false><<<dim3(1, B / 128), 256, 0, stream>>>(
      convflat, wtxt, xcb + 128, nullptr, fc1xt_b, B, 128, 3872, 256);
  gemm_mfma<true, true><<<dim3(12, B / 128), 256, 0, stream>>>(
      gb, wtg1, g1b, nullptr, fcg1_b, B, 1500, 1568, 1504);
  gemm_mfma<true, false><<<dim3(1, B / 128), 256, 0, stream>>>(
      g1b, wtg2, xcb, nullptr, fcg2_b, B, 128, 1504, 256);
  gemm_mfma<true, true><<<dim3(8, B / 128), 256, 0, stream>>>(
      xcb, wtf1, z1b, nullptr, fc1_b, B, 1024, 256, 1024);
  gemm_mfma<true, true><<<dim3(4, B / 128), 256, 0, stream>>>(
      z1b, wtf2, z2b, nullptr, fc2_b, B, 512, 1024, 512);

  final_out<<<B / 4, 256, 0, stream>>>(z2b, out_W, out_b, (float*)d_out);
}

// Round 10
// 803.253 us; speedup vs baseline: 5.9902x; 1.1324x over previous
//
#include <hip/hip_runtime.h>

typedef __attribute__((ext_vector_type(4))) float f32x4;
typedef __attribute__((ext_vector_type(8))) short bf16x8;
typedef __attribute__((ext_vector_type(8))) unsigned short u16x8;
typedef unsigned short u16;

#define HID 780
#define NH 10
#define FO 78

__device__ inline u16 f2b(float f) {  // fp32 -> bf16 RNE
  unsigned u = __float_as_uint(f);
  unsigned r = (u + 0x7fff + ((u >> 16) & 1)) >> 16;
  return (u16)r;
}
__device__ inline float b2f(u16 b) { return __uint_as_float(((unsigned)b) << 16); }

// ---------------- bf16 MFMA GEMM, bf16 C out ----------------
template<bool BIAS, bool RELU>
__global__ __launch_bounds__(256) void gemm_mfma(const u16* __restrict__ A,
    const u16* __restrict__ BT, u16* __restrict__ C, float* __restrict__ att_out,
    const float* __restrict__ bias, int M, int Ncols, int KP, int ldc)
{
  __shared__ u16 As[128 * 40];
  __shared__ u16 Bs[128 * 40];
  const int tid = threadIdx.x;
  const int row0 = blockIdx.y << 7, col0 = blockIdx.x << 7;
  const int l = tid & 63, wid = tid >> 6;
  const int wr = wid >> 1, wc = wid & 1;
  const int lr = l & 15, lk = l >> 4;
  f32x4 acc[4][4];
#pragma unroll
  for (int i = 0; i < 4; ++i)
#pragma unroll
    for (int j = 0; j < 4; ++j) acc[i][j] = (f32x4){0.f, 0.f, 0.f, 0.f};

  for (int k0 = 0; k0 < KP; k0 += 32) {
    __syncthreads();
#pragma unroll
    for (int i = 0; i < 2; ++i) {
      int c = tid + (i << 8);
      int row = c >> 2, off = c & 3;
      *(uint4*)&As[row * 40 + off * 8] =
          *(const uint4*)(A + (size_t)(row0 + row) * KP + k0 + off * 8);
      *(uint4*)&Bs[row * 40 + off * 8] =
          *(const uint4*)(BT + (size_t)(col0 + row) * KP + k0 + off * 8);
    }
    __syncthreads();
    bf16x8 af[4], bfr[4];
#pragma unroll
    for (int fm = 0; fm < 4; ++fm)
      af[fm] = *(const bf16x8*)&As[(wr * 64 + fm * 16 + lr) * 40 + lk * 8];
#pragma unroll
    for (int fn = 0; fn < 4; ++fn)
      bfr[fn] = *(const bf16x8*)&Bs[(wc * 64 + fn * 16 + lr) * 40 + lk * 8];
#pragma unroll
    for (int fm = 0; fm < 4; ++fm)
#pragma unroll
      for (int fn = 0; fn < 4; ++fn)
        acc[fm][fn] = __builtin_amdgcn_mfma_f32_16x16x32_bf16(af[fm], bfr[fn], acc[fm][fn], 0, 0, 0);
  }
#pragma unroll
  for (int fm = 0; fm < 4; ++fm)
#pragma unroll
    for (int fn = 0; fn < 4; ++fn) {
      int col = col0 + wc * 64 + fn * 16 + lr;
      f32x4 v = acc[fm][fn];
      int rbase = row0 + wr * 64 + fm * 16 + lk * 4;
      if (col < Ncols) {
        float bb = BIAS ? bias[col] : 0.f;
#pragma unroll
        for (int j = 0; j < 4; ++j) {
          float vv = v[j] + bb;
          if (RELU) vv = vv > 0.f ? vv : 0.f;
          C[(size_t)(rbase + j) * ldc + col] = f2b(vv);
        }
      } else {
        if (att_out != nullptr && col < Ncols + 20) {
          int c = col - Ncols;
#pragma unroll
          for (int j = 0; j < 4; ++j)
            att_out[(size_t)(rbase + j) * 20 + c] = v[j];
        }
        if (col < ldc) {
#pragma unroll
          for (int j = 0; j < 4; ++j) C[(size_t)(rbase + j) * ldc + col] = 0;
        }
      }
    }
}

// ---------------- conversions ----------------
__global__ void conv_x_bf16(const float* __restrict__ x, u16* __restrict__ xb, int M)
{
  int idx = blockIdx.x * 256 + threadIdx.x;
  if (idx >= M * 96) return;
  int r = idx / 96, c = idx - r * 96;
  xb[idx] = (c < FO) ? f2b(x[(size_t)r * FO + c]) : (u16)0;
}

__global__ void conv_wT_bf16(const float* __restrict__ W, u16* __restrict__ WT,
                             int K, int N, int KP, int NP)
{
  int idx = blockIdx.x * 256 + threadIdx.x;
  if (idx >= NP * KP) return;
  int n = idx / KP, k = idx - n * KP;
  WT[idx] = (n < N && k < K) ? f2b(W[(size_t)k * N + n]) : (u16)0;
}

// W2T[(o*8+k)][c] = bf16(convW[o,c,k]), [256][1024] zero-padded
__global__ void conv_w2T(const float* __restrict__ W, u16* __restrict__ WT)
{
  int idx = blockIdx.x * 256 + threadIdx.x;
  if (idx >= 256 * 1024) return;
  int ok = idx >> 10, c = idx & 1023;
  int o = ok >> 3, k = ok & 7;
  WT[idx] = (c < 1000) ? f2b(W[(size_t)o * 8000 + c * 8 + k]) : (u16)0;
}

// fold attention vectors into wt1 rows 780..799
__global__ void fold_att(const float* __restrict__ gat_W,
    const float* __restrict__ asv, const float* __restrict__ adv,
    u16* __restrict__ wt1)
{
  int j = blockIdx.x;
  int k = threadIdx.x;
  if (k >= 96) return;
  float s = 0.f;
  if (k < FO) {
    int h = (j < 10) ? j : j - 10;
    const float* av = ((j < 10) ? asv : adv) + h * FO;
    const float* wr = gat_W + (size_t)k * HID + h * FO;
    for (int f = 0; f < FO; ++f) s += wr[f] * av[f];
  }
  wt1[(size_t)(HID + j) * 96 + k] = f2b(s);
}

// ---------------- CSR build ----------------
__global__ void count_dst(const int* __restrict__ ei, int E, int N, int* __restrict__ cnt)
{
  int e = blockIdx.x * 256 + threadIdx.x;
  if (e >= E + N) return;
  int dst = (e < E) ? ei[E + e] : (e - E);
  atomicAdd(&cnt[dst], 1);
}

__global__ __launch_bounds__(1024) void scan_dinv(const int* __restrict__ cnt,
    int* __restrict__ offs, float* __restrict__ dinv, int N)
{
  __shared__ int part[1024];
  int tid = threadIdx.x;
  int chunk = (N + 1023) >> 10;
  int b0 = tid * chunk, b1 = min(b0 + chunk, N);
  int s = 0;
  for (int i = b0; i < b1; ++i) s += cnt[i];
  part[tid] = s;
  __syncthreads();
  for (int off = 1; off < 1024; off <<= 1) {
    int v = part[tid];
    int add = (tid >= off) ? part[tid - off] : 0;
    __syncthreads();
    part[tid] = v + add;
    __syncthreads();
  }
  int run = (tid > 0) ? part[tid - 1] : 0;
  for (int i = b0; i < b1; ++i) {
    int c = cnt[i];
    offs[i] = run;
    dinv[i] = c > 0 ? rsqrtf((float)c) : 0.f;
    run += c;
  }
  if (tid == 1023) offs[N] = run;
}

__global__ void fill_csr(const int* __restrict__ ei, int E, int N,
    const int* __restrict__ offs, int* __restrict__ fillpos, int* __restrict__ csr_src)
{
  int e = blockIdx.x * 256 + threadIdx.x;
  if (e >= E + N) return;
  int src, dst;
  if (e < E) { src = ei[e]; dst = ei[E + e]; }
  else { src = e - E; dst = e - E; }
  int p = offs[dst] + atomicAdd(&fillpos[dst], 1);
  csr_src[p] = src;
}

// ---------------- GAT gather: single-pass softmax, u16x8 gather ----------------
#define CH 48
__global__ __launch_bounds__(64) void gat_gather(const u16* __restrict__ h,
    const float* __restrict__ att,
    const int* __restrict__ offs, const int* __restrict__ csr_src,
    const float* __restrict__ gat_bias, u16* __restrict__ x1b)
{
  int n = blockIdx.x, lane = threadIdx.x;
  int o0 = offs[n], deg = offs[n + 1] - o0;
  __shared__ float ad[NH], ssum[NH];
  __shared__ float wbuf[CH][NH];
  __shared__ int slist[CH];
  if (lane < NH) { ad[lane] = att[n * 20 + 10 + lane]; ssum[lane] = 0.f; }
  const int s0 = lane, s1 = 64 + lane;
  const bool a1 = s1 < 100;
  int hA0 = min((s0 * 8) / FO, NH - 1), bb0 = FO * ((s0 * 8) / FO + 1) - s0 * 8;
  int hB0 = min((s0 * 8) / FO + 1, NH - 1);
  int hA1 = min((s1 * 8) / FO, NH - 1), bb1 = FO * ((s1 * 8) / FO + 1) - s1 * 8;
  int hB1 = min((s1 * 8) / FO + 1, NH - 1);
  float acc0[8], acc1[8];
#pragma unroll
  for (int j = 0; j < 8; ++j) { acc0[j] = 0.f; acc1[j] = 0.f; }
  __syncthreads();

  for (int e0 = 0; e0 < deg; e0 += CH) {
    int ce = min(CH, deg - e0);
    for (int idx = lane; idx < ce * NH; idx += 64) {
      int e = idx / NH, hd = idx - e * NH;
      int s = csr_src[o0 + e0 + e];
      float l = att[s * 20 + hd] + ad[hd];
      l = l > 0.f ? l : 0.2f * l;
      float w = __expf(l);
      wbuf[e][hd] = w;
      atomicAdd(&ssum[hd], w);
    }
    for (int idx = lane; idx < ce; idx += 64) slist[idx] = csr_src[o0 + e0 + idx];
    __syncthreads();
    for (int e = 0; e < ce; ++e) {
      const u16* hs = h + (size_t)slist[e] * 800;
      u16x8 v0 = *(const u16x8*)(hs + s0 * 8);
      float wA0 = wbuf[e][hA0], wB0 = wbuf[e][hB0];
#pragma unroll
      for (int j = 0; j < 8; ++j)
        acc0[j] += (j < bb0 ? wA0 : wB0) * b2f(v0[j]);
      if (a1) {
        u16x8 v1 = *(const u16x8*)(hs + s1 * 8);
        float wA1 = wbuf[e][hA1], wB1 = wbuf[e][hB1];
#pragma unroll
        for (int j = 0; j < 8; ++j)
          acc1[j] += (j < bb1 ? wA1 : wB1) * b2f(v1[j]);
      }
    }
    __syncthreads();
  }
  float iA0 = 1.f / (ssum[hA0] + 1e-16f), iB0 = 1.f / (ssum[hB0] + 1e-16f);
  u16x8 o0v;
#pragma unroll
  for (int j = 0; j < 8; ++j) {
    int f = s0 * 8 + j;
    float v = acc0[j] * (j < bb0 ? iA0 : iB0) + gat_bias[f];
    o0v[j] = f2b(v > 0.f ? v : 0.f);
  }
  *(u16x8*)(x1b + (size_t)n * 800 + s0 * 8) = o0v;
  if (a1) {
    float iA1 = 1.f / (ssum[hA1] + 1e-16f), iB1 = 1.f / (ssum[hB1] + 1e-16f);
    u16x8 o1v;
#pragma unroll
    for (int j = 0; j < 8; ++j) {
      int f = s1 * 8 + j;
      if (f < HID) {
        float v = acc1[j] * (j < bb1 ? iA1 : iB1) + gat_bias[f];
        o1v[j] = f2b(v > 0.f ? v : 0.f);
      } else o1v[j] = 0;
    }
    *(u16x8*)(x1b + (size_t)n * 800 + s1 * 8) = o1v;
  }
}

// ---------------- GCN gather + per-graph pooling, u16x8 gather ----------------
__global__ __launch_bounds__(256) void gcn_pool(const u16* __restrict__ h2,
    const int* __restrict__ offs, const int* __restrict__ csr_src,
    const float* __restrict__ dinv, const float* __restrict__ gcn_bias,
    const int* __restrict__ batch, int N, u16* __restrict__ gb)
{
  int gi = blockIdx.x, tid = threadIdx.x;
  int grp = tid >> 6, lane = tid & 63;
  __shared__ int se[2];
  __shared__ float smx[HID];
  __shared__ float ssm[HID];
  for (int f = tid; f < HID; f += 256) { smx[f] = 0.f; ssm[f] = 0.f; }
  if (tid < 2) {
    int target = gi + tid;
    int lo = 0, hi = N;
    while (lo < hi) { int mid = (lo + hi) >> 1; if (batch[mid] < target) lo = mid + 1; else hi = mid; }
    se[tid] = lo;
  }
  __syncthreads();
  int s = se[0], e = se[1];
  const int s0 = lane, s1 = 64 + lane;
  const bool a1 = s1 < 100;
  float bv0[8], bv1[8];
#pragma unroll
  for (int j = 0; j < 8; ++j) {
    int f0 = s0 * 8 + j, f1 = s1 * 8 + j;
    bv0[j] = gcn_bias[f0];
    bv1[j] = (a1 && f1 < HID) ? gcn_bias[f1] : 0.f;
  }
  float mx0[8], sm0[8], mx1[8], sm1[8];
#pragma unroll
  for (int j = 0; j < 8; ++j) { mx0[j] = 0.f; sm0[j] = 0.f; mx1[j] = 0.f; sm1[j] = 0.f; }

  for (int n = s + grp; n < e; n += 4) {
    int o0 = offs[n], deg = offs[n + 1] - o0;
    float dn = dinv[n];
    float acc0[8], acc1[8];
#pragma unroll
    for (int j = 0; j < 8; ++j) { acc0[j] = 0.f; acc1[j] = 0.f; }
    for (int ed = 0; ed < deg; ++ed) {
      int src = csr_src[o0 + ed];
      float c = dn * dinv[src];
      const u16* hr = h2 + (size_t)src * 800;
      u16x8 v0 = *(const u16x8*)(hr + s0 * 8);
#pragma unroll
      for (int j = 0; j < 8; ++j) acc0[j] += c * b2f(v0[j]);
      if (a1) {
        u16x8 v1 = *(const u16x8*)(hr + s1 * 8);
#pragma unroll
        for (int j = 0; j < 8; ++j) acc1[j] += c * b2f(v1[j]);
      }
    }
#pragma unroll
    for (int j = 0; j < 8; ++j) {
      float v = acc0[j] + bv0[j];
      v = v > 0.f ? v : 0.f;
      mx0[j] = fmaxf(mx0[j], v); sm0[j] += v;
      float w = acc1[j] + bv1[j];
      w = w > 0.f ? w : 0.f;
      mx1[j] = fmaxf(mx1[j], w); sm1[j] += w;
    }
  }
#pragma unroll
  for (int j = 0; j < 8; ++j) {
    int f0 = s0 * 8 + j;
    atomicMax((unsigned*)&smx[f0], __float_as_uint(mx0[j]));
    atomicAdd(&ssm[f0], sm0[j]);
    int f1 = s1 * 8 + j;
    if (a1 && f1 < HID) {
      atomicMax((unsigned*)&smx[f1], __float_as_uint(mx1[j]));
      atomicAdd(&ssm[f1], sm1[j]);
    }
  }
  __syncthreads();
  float inv = 1.f / fmaxf((float)(e - s), 1.f);
  for (int f = tid; f < HID; f += 256) {
    gb[(size_t)gi * 1568 + f] = f2b(smx[f]);
    gb[(size_t)gi * 1568 + HID + f] = f2b(ssm[f] * inv);
  }
  if (tid < 8) gb[(size_t)gi * 1568 + 1560 + tid] = 0;
}

// ---------------- protein branch ----------------
// Ind[(b*26+v)][c] = (tgt[b,c]==v) ? 1.0bf16 : 0, [B*26][1024]
__global__ __launch_bounds__(256) void build_ind(const int* __restrict__ tgt,
    u16* __restrict__ Ind)
{
  int b = blockIdx.x, tid = threadIdx.x;
  __shared__ unsigned char tl[1000];
  for (int i = tid; i < 1000; i += 256) tl[i] = (unsigned char)tgt[b * 1000 + i];
  __syncthreads();
  u16* out = Ind + (size_t)b * 26 * 1024;
  for (int ci = tid; ci < 26 * 128; ci += 256) {
    int v = ci >> 7, c0 = (ci & 127) << 3;
    u16x8 w;
#pragma unroll
    for (int j = 0; j < 8; ++j) {
      int c = c0 + j;
      w[j] = (c < 1000 && tl[c] == v) ? (u16)0x3F80 : (u16)0;
    }
    *(u16x8*)(out + v * 1024 + c0) = w;
  }
}

// conv from bf16 A [b*26+v][256]: conv[b,o,l] = cb[o] + sum_v sum_k A*emb[v,l+k]
__global__ __launch_bounds__(256) void conv_xt(const u16* __restrict__ Aall,
    const float* __restrict__ embed, const float* __restrict__ cbias,
    u16* __restrict__ out)
{
  int b = blockIdx.x, tid = threadIdx.x;
  __shared__ __align__(16) float Al[6656];
  __shared__ __align__(16) float el[3360];
  const u16* Ab = Aall + (size_t)b * 6656;
  for (int i = tid; i < 6656; i += 256) Al[i] = b2f(Ab[i]);
  for (int i = tid; i < 3328; i += 256) el[i] = embed[i];
  if (tid < 32) el[3328 + tid] = 0.f;
  __syncthreads();
  for (int grp = tid; grp < 512; grp += 256) {
    int o = grp >> 4;
    int l0 = (grp & 15) << 3;
    float cb = cbias[o];
    float acc[8];
#pragma unroll
    for (int j = 0; j < 8; ++j) acc[j] = cb;
    for (int v = 0; v < 26; ++v) {
      const float* ap = &Al[v * 256 + (o << 3)];
      f32x4 a0 = *(const f32x4*)ap;
      f32x4 a1 = *(const f32x4*)(ap + 4);
      const float* ep = &el[v * 128 + l0];
      f32x4 e0 = *(const f32x4*)ep;
      f32x4 e1 = *(const f32x4*)(ep + 4);
      f32x4 e2 = *(const f32x4*)(ep + 8);
      f32x4 e3 = *(const f32x4*)(ep + 12);
      float a[8] = { a0[0], a0[1], a0[2], a0[3], a1[0], a1[1], a1[2], a1[3] };
      float e[16] = { e0[0], e0[1], e0[2], e0[3], e1[0], e1[1], e1[2], e1[3],
                      e2[0], e2[1], e2[2], e2[3], e3[0], e3[1], e3[2], e3[3] };
#pragma unroll
      for (int k = 0; k < 8; ++k)
#pragma unroll
        for (int j = 0; j < 8; ++j) acc[j] += a[k] * e[k + j];
    }
    int base = o * 121 + l0;
#pragma unroll
    for (int j = 0; j < 8; ++j)
      if (l0 + j < 121) out[(size_t)b * 3872 + base + j] = f2b(acc[j]);
  }
}

// ---------------- final row-dot (bf16 input) ----------------
__global__ __launch_bounds__(256) void final_out(const u16* __restrict__ z2,
    const float* __restrict__ W, const float* __restrict__ bias, float* __restrict__ out)
{
  int row = blockIdx.x * 4 + (threadIdx.x >> 6);
  int lane = threadIdx.x & 63;
  const u16* zr = z2 + (size_t)row * 512;
  float s = 0.f;
  for (int i = lane; i < 512; i += 64) s += b2f(zr[i]) * W[i];
#pragma unroll
  for (int off = 32; off > 0; off >>= 1) s += __shfl_down(s, off, 64);
  if (lane == 0) out[row] = s + bias[0];
}

// ---------------- launch ----------------
extern "C" void kernel_launch(void* const* d_in, const int* in_sizes, int n_in,
                              void* d_out, int out_size, void* d_ws, size_t ws_size,
                              hipStream_t stream)
{
  const float* x        = (const float*)d_in[0];
  const int*   ei       = (const int*)d_in[1];
  const int*   batch    = (const int*)d_in[2];
  const int*   tgt      = (const int*)d_in[3];
  const float* gat_W    = (const float*)d_in[4];
  const float* att_src  = (const float*)d_in[5];
  const float* att_dst  = (const float*)d_in[6];
  const float* gat_bias = (const float*)d_in[7];
  const float* gcn_W    = (const float*)d_in[8];
  const float* gcn_bias = (const float*)d_in[9];
  const float* fcg1_W   = (const float*)d_in[10];
  const float* fcg1_b   = (const float*)d_in[11];
  const float* fcg2_W   = (const float*)d_in[12];
  const float* fcg2_b   = (const float*)d_in[13];
  const float* embed    = (const float*)d_in[14];
  const float* convW    = (const float*)d_in[15];
  const float* convb    = (const float*)d_in[16];
  const float* fc1xt_W  = (const float*)d_in[17];
  const float* fc1xt_b  = (const float*)d_in[18];
  const float* fc1_W    = (const float*)d_in[19];
  const float* fc1_b    = (const float*)d_in[20];
  const float* fc2_W    = (const float*)d_in[21];
  const float* fc2_b    = (const float*)d_in[22];
  const float* out_W    = (const float*)d_in[23];
  const float* out_b    = (const float*)d_in[24];

  const int N = in_sizes[0] / FO;      // 40960
  const int E = in_sizes[1] / 2;       // 163840
  const int B = in_sizes[3] / 1000;    // 1024
  const int ET = E + N;

  char* ws = (char*)d_ws;
  size_t off = 0;
  auto alloc = [&](size_t bytes) -> char* {
    char* p = ws + off;
    off = (off + bytes + 255) & ~(size_t)255;
    return p;
  };
  float* buf0  = (float*)alloc((size_t)N * HID * 4);   // h/h2 bf16 -> Ind/A/convflat
  float* buf1  = (float*)alloc((size_t)N * 800 * 2);   // xb -> x1b -> head scratch
  u16*   wt1   = (u16*)alloc((size_t)896 * 96 * 2);
  u16*   wt2   = (u16*)alloc((size_t)896 * 800 * 2);
  u16*   wtg1  = (u16*)alloc((size_t)1536 * 1568 * 2);
  u16*   wtg2  = (u16*)alloc((size_t)128 * 1504 * 2);
  u16*   wtxt  = (u16*)alloc((size_t)128 * 3872 * 2);
  u16*   wtf1  = (u16*)alloc((size_t)1024 * 256 * 2);
  u16*   wtf2  = (u16*)alloc((size_t)512 * 1024 * 2);
  u16*   wtc   = (u16*)alloc((size_t)256 * 1024 * 2);  // conv W2T
  float* att   = (float*)alloc((size_t)N * 20 * 4);
  int*   cnt   = (int*)alloc((size_t)N * 4);
  int*   offs  = (int*)alloc((size_t)(N + 1) * 4);
  int*   fillp = (int*)alloc((size_t)N * 4);
  int*   csr   = (int*)alloc((size_t)ET * 4);
  float* dinv  = (float*)alloc((size_t)N * 4);
  u16*   gb    = (u16*)alloc((size_t)B * 1568 * 2);

  u16*   xb    = (u16*)buf1;                 // dead after gemm #1
  u16*   x1b   = (u16*)buf1;                 // gat_gather -> gemm #2
  u16*   hb    = (u16*)buf0;                 // h / h2 bf16 [N][800]
  // protein aliases in buf0 (free after gcn_pool): Ind 54.5MB | A 13.6MB | conv 7.9MB
  u16*   Ind      = (u16*)buf0;                         // [26624][1024]
  u16*   Ab       = Ind + (size_t)26624 * 1024;         // [26624][256]
  u16*   convflat = Ab + (size_t)26624 * 256;           // [1024][3872]
  // head scratch in buf1 (after gemm #2 consumed x1b)
  u16* g1b = (u16*)buf1;                     // [1024][1504]
  u16* xcb = g1b + (size_t)1024 * 1504;      // [1024][256] (g2 | xt)
  u16* z1b = xcb + (size_t)1024 * 256;       // [1024][1024]
  u16* z2b = z1b + (size_t)1024 * 1024;      // [1024][512]

  hipMemsetAsync(cnt, 0, (size_t)N * 4, stream);
  hipMemsetAsync(fillp, 0, (size_t)N * 4, stream);

  // conversions + attention fold
  conv_x_bf16<<<(N * 96 + 255) / 256, 256, 0, stream>>>(x, xb, N);
  conv_wT_bf16<<<(896 * 96 + 255) / 256, 256, 0, stream>>>(gat_W, wt1, FO, HID, 96, 896);
  fold_att<<<20, 96, 0, stream>>>(gat_W, att_src, att_dst, wt1);
  conv_wT_bf16<<<(896 * 800 + 255) / 256, 256, 0, stream>>>(gcn_W, wt2, HID, HID, 800, 896);
  conv_wT_bf16<<<(1536 * 1568 + 255) / 256, 256, 0, stream>>>(fcg1_W, wtg1, 1560, 1500, 1568, 1536);
  conv_wT_bf16<<<(128 * 1504 + 255) / 256, 256, 0, stream>>>(fcg2_W, wtg2, 1500, 128, 1504, 128);
  conv_wT_bf16<<<(128 * 3872 + 255) / 256, 256, 0, stream>>>(fc1xt_W, wtxt, 3872, 128, 3872, 128);
  conv_wT_bf16<<<(1024 * 256 + 255) / 256, 256, 0, stream>>>(fc1_W, wtf1, 256, 1024, 256, 1024);
  conv_wT_bf16<<<(512 * 1024 + 255) / 256, 256, 0, stream>>>(fc2_W, wtf2, 1024, 512, 1024, 512);
  conv_w2T<<<(256 * 1024 + 255) / 256, 256, 0, stream>>>(convW, wtc);

  // h = x @ gat_W -> hb bf16 [N][800] (cols 780+ zeroed); att dots -> att f32
  gemm_mfma<false, false><<<dim3(7, N / 128), 256, 0, stream>>>(
      xb, wt1, hb, att, nullptr, N, HID, 96, 800);

  int egrid = (ET + 255) / 256;
  count_dst<<<egrid, 256, 0, stream>>>(ei, E, N, cnt);
  scan_dinv<<<1, 1024, 0, stream>>>(cnt, offs, dinv, N);
  fill_csr<<<egrid, 256, 0, stream>>>(ei, E, N, offs, fillp, csr);

  gat_gather<<<N, 64, 0, stream>>>(hb, att, offs, csr, gat_bias, x1b);

  // h2 = x1 @ gcn_W -> hb bf16 [N][800]
  gemm_mfma<false, false><<<dim3(7, N / 128), 256, 0, stream>>>(
      x1b, wt2, hb, nullptr, nullptr, N, HID, 800, 800);

  // fused GCN gather + per-graph max/mean pool -> gb bf16 [B][1568]
  gcn_pool<<<B, 256, 0, stream>>>(hb, offs, csr, dinv, gcn_bias, batch, N, gb);

  // protein branch (buf0 free now): A = Ind @ W2 via MFMA, then tiny conv
  build_ind<<<B, 256, 0, stream>>>(tgt, Ind);
  gemm_mfma<false, false><<<dim3(2, 26624 / 128), 256, 0, stream>>>(
      Ind, wtc, Ab, nullptr, nullptr, 26624, 256, 1024, 256);
  conv_xt<<<B, 256, 0, stream>>>(Ab, embed, convb, convflat);

  // head: all bf16 MFMA with fused bias/act (buf1 free after gemm #2)
  gemm_mfma<true, false><<<dim3(1, B / 128), 256, 0, stream>>>(
      convflat, wtxt, xcb + 128, nullptr, fc1xt_b, B, 128, 3872, 256);
  gemm_mfma<true, true><<<dim3(12, B / 128), 256, 0, stream>>>(
      gb, wtg1, g1b, nullptr, fcg1_b, B, 1500, 1568, 1504);
  gemm_mfma<true, false><<<dim3(1, B / 128), 256, 0, stream>>>(
      g1b, wtg2, xcb, nullptr, fcg2_b, B, 128, 1504, 256);
  gemm_mfma<true, true><<<dim3(8, B / 128), 256, 0, stream>>>(
      xcb, wtf1, z1b, nullptr, fc1_b, B, 1024, 256, 1024);
  gemm_mfma<true, true><<<dim3(4, B / 128), 256, 0, stream>>>(
      z1b, wtf2, z2b, nullptr, fc2_b, B, 512, 1024, 512);

  final_out<<<B / 4, 256, 0, stream>>>(z2b, out_W, out_b, (float*)d_out);
}

// Round 11
// 657.384 us; speedup vs baseline: 7.3193x; 1.2219x over previous
//
#include <hip/hip_runtime.h>

typedef __attribute__((ext_vector_type(4))) float f32x4;
typedef __attribute__((ext_vector_type(8))) short bf16x8;
typedef __attribute__((ext_vector_type(8))) unsigned short u16x8;
typedef unsigned short u16;

#define HID 780
#define NH 10
#define FO 78

__device__ inline u16 f2b(float f) {  // fp32 -> bf16 RNE
  unsigned u = __float_as_uint(f);
  unsigned r = (u + 0x7fff + ((u >> 16) & 1)) >> 16;
  return (u16)r;
}
__device__ inline float b2f(u16 b) { return __uint_as_float(((unsigned)b) << 16); }

// ---------------- bf16 MFMA GEMM, bf16 C out (non-split) ----------------
template<bool BIAS, bool RELU>
__global__ __launch_bounds__(256) void gemm_mfma(const u16* __restrict__ A,
    const u16* __restrict__ BT, u16* __restrict__ C, float* __restrict__ att_out,
    const float* __restrict__ bias, int M, int Ncols, int KP, int ldc)
{
  __shared__ u16 As[128 * 40];
  __shared__ u16 Bs[128 * 40];
  const int tid = threadIdx.x;
  const int row0 = blockIdx.y << 7, col0 = blockIdx.x << 7;
  const int l = tid & 63, wid = tid >> 6;
  const int wr = wid >> 1, wc = wid & 1;
  const int lr = l & 15, lk = l >> 4;
  f32x4 acc[4][4];
#pragma unroll
  for (int i = 0; i < 4; ++i)
#pragma unroll
    for (int j = 0; j < 4; ++j) acc[i][j] = (f32x4){0.f, 0.f, 0.f, 0.f};

  for (int k0 = 0; k0 < KP; k0 += 32) {
    __syncthreads();
#pragma unroll
    for (int i = 0; i < 2; ++i) {
      int c = tid + (i << 8);
      int row = c >> 2, off = c & 3;
      *(uint4*)&As[row * 40 + off * 8] =
          *(const uint4*)(A + (size_t)(row0 + row) * KP + k0 + off * 8);
      *(uint4*)&Bs[row * 40 + off * 8] =
          *(const uint4*)(BT + (size_t)(col0 + row) * KP + k0 + off * 8);
    }
    __syncthreads();
    bf16x8 af[4], bfr[4];
#pragma unroll
    for (int fm = 0; fm < 4; ++fm)
      af[fm] = *(const bf16x8*)&As[(wr * 64 + fm * 16 + lr) * 40 + lk * 8];
#pragma unroll
    for (int fn = 0; fn < 4; ++fn)
      bfr[fn] = *(const bf16x8*)&Bs[(wc * 64 + fn * 16 + lr) * 40 + lk * 8];
#pragma unroll
    for (int fm = 0; fm < 4; ++fm)
#pragma unroll
      for (int fn = 0; fn < 4; ++fn)
        acc[fm][fn] = __builtin_amdgcn_mfma_f32_16x16x32_bf16(af[fm], bfr[fn], acc[fm][fn], 0, 0, 0);
  }
#pragma unroll
  for (int fm = 0; fm < 4; ++fm)
#pragma unroll
    for (int fn = 0; fn < 4; ++fn) {
      int col = col0 + wc * 64 + fn * 16 + lr;
      f32x4 v = acc[fm][fn];
      int rbase = row0 + wr * 64 + fm * 16 + lk * 4;
      if (col < Ncols) {
        float bb = BIAS ? bias[col] : 0.f;
#pragma unroll
        for (int j = 0; j < 4; ++j) {
          float vv = v[j] + bb;
          if (RELU) vv = vv > 0.f ? vv : 0.f;
          C[(size_t)(rbase + j) * ldc + col] = f2b(vv);
        }
      } else {
        if (att_out != nullptr && col < Ncols + 20) {
          int c = col - Ncols;
#pragma unroll
          for (int j = 0; j < 4; ++j)
            att_out[(size_t)(rbase + j) * 20 + c] = v[j];
        }
        if (col < ldc) {
#pragma unroll
          for (int j = 0; j < 4; ++j) C[(size_t)(rbase + j) * ldc + col] = 0;
        }
      }
    }
}

// ---------------- split-K bf16 MFMA GEMM, fp32 atomic partials ----------------
// C fp32 compact [M][Ncols], pre-zeroed. grid.z slices K by kchunk (mult of 32).
__global__ __launch_bounds__(256) void gemm_sk(const u16* __restrict__ A,
    const u16* __restrict__ BT, float* __restrict__ C,
    int M, int Ncols, int KP, int kchunk)
{
  __shared__ u16 As[128 * 40];
  __shared__ u16 Bs[128 * 40];
  const int tid = threadIdx.x;
  const int row0 = blockIdx.y << 7, col0 = blockIdx.x << 7;
  const int kbeg = blockIdx.z * kchunk;
  const int kend = min(KP, kbeg + kchunk);
  const int l = tid & 63, wid = tid >> 6;
  const int wr = wid >> 1, wc = wid & 1;
  const int lr = l & 15, lk = l >> 4;
  f32x4 acc[4][4];
#pragma unroll
  for (int i = 0; i < 4; ++i)
#pragma unroll
    for (int j = 0; j < 4; ++j) acc[i][j] = (f32x4){0.f, 0.f, 0.f, 0.f};

  for (int k0 = kbeg; k0 < kend; k0 += 32) {
    __syncthreads();
#pragma unroll
    for (int i = 0; i < 2; ++i) {
      int c = tid + (i << 8);
      int row = c >> 2, off = c & 3;
      *(uint4*)&As[row * 40 + off * 8] =
          *(const uint4*)(A + (size_t)(row0 + row) * KP + k0 + off * 8);
      *(uint4*)&Bs[row * 40 + off * 8] =
          *(const uint4*)(BT + (size_t)(col0 + row) * KP + k0 + off * 8);
    }
    __syncthreads();
    bf16x8 af[4], bfr[4];
#pragma unroll
    for (int fm = 0; fm < 4; ++fm)
      af[fm] = *(const bf16x8*)&As[(wr * 64 + fm * 16 + lr) * 40 + lk * 8];
#pragma unroll
    for (int fn = 0; fn < 4; ++fn)
      bfr[fn] = *(const bf16x8*)&Bs[(wc * 64 + fn * 16 + lr) * 40 + lk * 8];
#pragma unroll
    for (int fm = 0; fm < 4; ++fm)
#pragma unroll
      for (int fn = 0; fn < 4; ++fn)
        acc[fm][fn] = __builtin_amdgcn_mfma_f32_16x16x32_bf16(af[fm], bfr[fn], acc[fm][fn], 0, 0, 0);
  }
#pragma unroll
  for (int fm = 0; fm < 4; ++fm)
#pragma unroll
    for (int fn = 0; fn < 4; ++fn) {
      int col = col0 + wc * 64 + fn * 16 + lr;
      if (col < Ncols) {
        f32x4 v = acc[fm][fn];
        int rbase = row0 + wr * 64 + fm * 16 + lk * 4;
#pragma unroll
        for (int j = 0; j < 4; ++j)
          atomicAdd(&C[(size_t)(rbase + j) * Ncols + col], v[j]);
      }
    }
}

// fp32 compact [M][N] -> bf16 [M][ldco] with bias/relu, zero-pad cols [N,padTo)
template<bool RELU>
__global__ void bias_act_pad(const float* __restrict__ Cf,
    const float* __restrict__ bias, u16* __restrict__ out,
    int M, int N, int padTo, int ldco)
{
  int idx = blockIdx.x * 256 + threadIdx.x;
  if (idx >= M * padTo) return;
  int r = idx / padTo, c = idx - r * padTo;
  if (c < N) {
    float v = Cf[(size_t)r * N + c] + bias[c];
    if (RELU) v = v > 0.f ? v : 0.f;
    out[(size_t)r * ldco + c] = f2b(v);
  } else {
    out[(size_t)r * ldco + c] = 0;
  }
}

// ---------------- conversions ----------------
__global__ void conv_x_bf16(const float* __restrict__ x, u16* __restrict__ xb, int M)
{
  int idx = blockIdx.x * 256 + threadIdx.x;
  if (idx >= M * 96) return;
  int r = idx / 96, c = idx - r * 96;
  xb[idx] = (c < FO) ? f2b(x[(size_t)r * FO + c]) : (u16)0;
}

__global__ void conv_wT_bf16(const float* __restrict__ W, u16* __restrict__ WT,
                             int K, int N, int KP, int NP)
{
  int idx = blockIdx.x * 256 + threadIdx.x;
  if (idx >= NP * KP) return;
  int n = idx / KP, k = idx - n * KP;
  WT[idx] = (n < N && k < K) ? f2b(W[(size_t)k * N + n]) : (u16)0;
}

// W2T[(o*8+k)][c] = bf16(convW[o,c,k]), [256][1024] zero-padded
__global__ void conv_w2T(const float* __restrict__ W, u16* __restrict__ WT)
{
  int idx = blockIdx.x * 256 + threadIdx.x;
  if (idx >= 256 * 1024) return;
  int ok = idx >> 10, c = idx & 1023;
  int o = ok >> 3, k = ok & 7;
  WT[idx] = (c < 1000) ? f2b(W[(size_t)o * 8000 + c * 8 + k]) : (u16)0;
}

// fold attention vectors into wt1 rows 780..799
__global__ void fold_att(const float* __restrict__ gat_W,
    const float* __restrict__ asv, const float* __restrict__ adv,
    u16* __restrict__ wt1)
{
  int j = blockIdx.x;
  int k = threadIdx.x;
  if (k >= 96) return;
  float s = 0.f;
  if (k < FO) {
    int h = (j < 10) ? j : j - 10;
    const float* av = ((j < 10) ? asv : adv) + h * FO;
    const float* wr = gat_W + (size_t)k * HID + h * FO;
    for (int f = 0; f < FO; ++f) s += wr[f] * av[f];
  }
  wt1[(size_t)(HID + j) * 96 + k] = f2b(s);
}

// ---------------- CSR build ----------------
__global__ void count_dst(const int* __restrict__ ei, int E, int N, int* __restrict__ cnt)
{
  int e = blockIdx.x * 256 + threadIdx.x;
  if (e >= E + N) return;
  int dst = (e < E) ? ei[E + e] : (e - E);
  atomicAdd(&cnt[dst], 1);
}

__global__ __launch_bounds__(1024) void scan_dinv(const int* __restrict__ cnt,
    int* __restrict__ offs, float* __restrict__ dinv, int N)
{
  __shared__ int part[1024];
  int tid = threadIdx.x;
  int chunk = (N + 1023) >> 10;
  int b0 = tid * chunk, b1 = min(b0 + chunk, N);
  int s = 0;
  for (int i = b0; i < b1; ++i) s += cnt[i];
  part[tid] = s;
  __syncthreads();
  for (int off = 1; off < 1024; off <<= 1) {
    int v = part[tid];
    int add = (tid >= off) ? part[tid - off] : 0;
    __syncthreads();
    part[tid] = v + add;
    __syncthreads();
  }
  int run = (tid > 0) ? part[tid - 1] : 0;
  for (int i = b0; i < b1; ++i) {
    int c = cnt[i];
    offs[i] = run;
    dinv[i] = c > 0 ? rsqrtf((float)c) : 0.f;
    run += c;
  }
  if (tid == 1023) offs[N] = run;
}

__global__ void fill_csr(const int* __restrict__ ei, int E, int N,
    const int* __restrict__ offs, int* __restrict__ fillpos, int* __restrict__ csr_src)
{
  int e = blockIdx.x * 256 + threadIdx.x;
  if (e >= E + N) return;
  int src, dst;
  if (e < E) { src = ei[e]; dst = ei[E + e]; }
  else { src = e - E; dst = e - E; }
  int p = offs[dst] + atomicAdd(&fillpos[dst], 1);
  csr_src[p] = src;
}

// ---------------- GAT gather: single-pass softmax, u16x8 gather ----------------
#define CH 48
__global__ __launch_bounds__(64) void gat_gather(const u16* __restrict__ h,
    const float* __restrict__ att,
    const int* __restrict__ offs, const int* __restrict__ csr_src,
    const float* __restrict__ gat_bias, u16* __restrict__ x1b)
{
  int n = blockIdx.x, lane = threadIdx.x;
  int o0 = offs[n], deg = offs[n + 1] - o0;
  __shared__ float ad[NH], ssum[NH];
  __shared__ float wbuf[CH][NH];
  __shared__ int slist[CH];
  if (lane < NH) { ad[lane] = att[n * 20 + 10 + lane]; ssum[lane] = 0.f; }
  const int s0 = lane, s1 = 64 + lane;
  const bool a1 = s1 < 100;
  int hA0 = min((s0 * 8) / FO, NH - 1), bb0 = FO * ((s0 * 8) / FO + 1) - s0 * 8;
  int hB0 = min((s0 * 8) / FO + 1, NH - 1);
  int hA1 = min((s1 * 8) / FO, NH - 1), bb1 = FO * ((s1 * 8) / FO + 1) - s1 * 8;
  int hB1 = min((s1 * 8) / FO + 1, NH - 1);
  float acc0[8], acc1[8];
#pragma unroll
  for (int j = 0; j < 8; ++j) { acc0[j] = 0.f; acc1[j] = 0.f; }
  __syncthreads();

  for (int e0 = 0; e0 < deg; e0 += CH) {
    int ce = min(CH, deg - e0);
    for (int idx = lane; idx < ce * NH; idx += 64) {
      int e = idx / NH, hd = idx - e * NH;
      int s = csr_src[o0 + e0 + e];
      float l = att[s * 20 + hd] + ad[hd];
      l = l > 0.f ? l : 0.2f * l;
      float w = __expf(l);
      wbuf[e][hd] = w;
      atomicAdd(&ssum[hd], w);
    }
    for (int idx = lane; idx < ce; idx += 64) slist[idx] = csr_src[o0 + e0 + idx];
    __syncthreads();
    for (int e = 0; e < ce; ++e) {
      const u16* hs = h + (size_t)slist[e] * 800;
      u16x8 v0 = *(const u16x8*)(hs + s0 * 8);
      float wA0 = wbuf[e][hA0], wB0 = wbuf[e][hB0];
#pragma unroll
      for (int j = 0; j < 8; ++j)
        acc0[j] += (j < bb0 ? wA0 : wB0) * b2f(v0[j]);
      if (a1) {
        u16x8 v1 = *(const u16x8*)(hs + s1 * 8);
        float wA1 = wbuf[e][hA1], wB1 = wbuf[e][hB1];
#pragma unroll
        for (int j = 0; j < 8; ++j)
          acc1[j] += (j < bb1 ? wA1 : wB1) * b2f(v1[j]);
      }
    }
    __syncthreads();
  }
  float iA0 = 1.f / (ssum[hA0] + 1e-16f), iB0 = 1.f / (ssum[hB0] + 1e-16f);
  u16x8 o0v;
#pragma unroll
  for (int j = 0; j < 8; ++j) {
    int f = s0 * 8 + j;
    float v = acc0[j] * (j < bb0 ? iA0 : iB0) + gat_bias[f];
    o0v[j] = f2b(v > 0.f ? v : 0.f);
  }
  *(u16x8*)(x1b + (size_t)n * 800 + s0 * 8) = o0v;
  if (a1) {
    float iA1 = 1.f / (ssum[hA1] + 1e-16f), iB1 = 1.f / (ssum[hB1] + 1e-16f);
    u16x8 o1v;
#pragma unroll
    for (int j = 0; j < 8; ++j) {
      int f = s1 * 8 + j;
      if (f < HID) {
        float v = acc1[j] * (j < bb1 ? iA1 : iB1) + gat_bias[f];
        o1v[j] = f2b(v > 0.f ? v : 0.f);
      } else o1v[j] = 0;
    }
    *(u16x8*)(x1b + (size_t)n * 800 + s1 * 8) = o1v;
  }
}

// ---------------- GCN gather + per-graph pooling, u16x8 gather ----------------
__global__ __launch_bounds__(256) void gcn_pool(const u16* __restrict__ h2,
    const int* __restrict__ offs, const int* __restrict__ csr_src,
    const float* __restrict__ dinv, const float* __restrict__ gcn_bias,
    const int* __restrict__ batch, int N, u16* __restrict__ gb)
{
  int gi = blockIdx.x, tid = threadIdx.x;
  int grp = tid >> 6, lane = tid & 63;
  __shared__ int se[2];
  __shared__ float smx[HID];
  __shared__ float ssm[HID];
  for (int f = tid; f < HID; f += 256) { smx[f] = 0.f; ssm[f] = 0.f; }
  if (tid < 2) {
    int target = gi + tid;
    int lo = 0, hi = N;
    while (lo < hi) { int mid = (lo + hi) >> 1; if (batch[mid] < target) lo = mid + 1; else hi = mid; }
    se[tid] = lo;
  }
  __syncthreads();
  int s = se[0], e = se[1];
  const int s0 = lane, s1 = 64 + lane;
  const bool a1 = s1 < 100;
  float bv0[8], bv1[8];
#pragma unroll
  for (int j = 0; j < 8; ++j) {
    int f0 = s0 * 8 + j, f1 = s1 * 8 + j;
    bv0[j] = gcn_bias[f0];
    bv1[j] = (a1 && f1 < HID) ? gcn_bias[f1] : 0.f;
  }
  float mx0[8], sm0[8], mx1[8], sm1[8];
#pragma unroll
  for (int j = 0; j < 8; ++j) { mx0[j] = 0.f; sm0[j] = 0.f; mx1[j] = 0.f; sm1[j] = 0.f; }

  for (int n = s + grp; n < e; n += 4) {
    int o0 = offs[n], deg = offs[n + 1] - o0;
    float dn = dinv[n];
    float acc0[8], acc1[8];
#pragma unroll
    for (int j = 0; j < 8; ++j) { acc0[j] = 0.f; acc1[j] = 0.f; }
    for (int ed = 0; ed < deg; ++ed) {
      int src = csr_src[o0 + ed];
      float c = dn * dinv[src];
      const u16* hr = h2 + (size_t)src * 800;
      u16x8 v0 = *(const u16x8*)(hr + s0 * 8);
#pragma unroll
      for (int j = 0; j < 8; ++j) acc0[j] += c * b2f(v0[j]);
      if (a1) {
        u16x8 v1 = *(const u16x8*)(hr + s1 * 8);
#pragma unroll
        for (int j = 0; j < 8; ++j) acc1[j] += c * b2f(v1[j]);
      }
    }
#pragma unroll
    for (int j = 0; j < 8; ++j) {
      float v = acc0[j] + bv0[j];
      v = v > 0.f ? v : 0.f;
      mx0[j] = fmaxf(mx0[j], v); sm0[j] += v;
      float w = acc1[j] + bv1[j];
      w = w > 0.f ? w : 0.f;
      mx1[j] = fmaxf(mx1[j], w); sm1[j] += w;
    }
  }
#pragma unroll
  for (int j = 0; j < 8; ++j) {
    int f0 = s0 * 8 + j;
    atomicMax((unsigned*)&smx[f0], __float_as_uint(mx0[j]));
    atomicAdd(&ssm[f0], sm0[j]);
    int f1 = s1 * 8 + j;
    if (a1 && f1 < HID) {
      atomicMax((unsigned*)&smx[f1], __float_as_uint(mx1[j]));
      atomicAdd(&ssm[f1], sm1[j]);
    }
  }
  __syncthreads();
  float inv = 1.f / fmaxf((float)(e - s), 1.f);
  for (int f = tid; f < HID; f += 256) {
    gb[(size_t)gi * 1568 + f] = f2b(smx[f]);
    gb[(size_t)gi * 1568 + HID + f] = f2b(ssm[f] * inv);
  }
  if (tid < 8) gb[(size_t)gi * 1568 + 1560 + tid] = 0;
}

// ---------------- protein branch ----------------
__global__ __launch_bounds__(256) void build_ind(const int* __restrict__ tgt,
    u16* __restrict__ Ind)
{
  int b = blockIdx.x, tid = threadIdx.x;
  __shared__ unsigned char tl[1000];
  for (int i = tid; i < 1000; i += 256) tl[i] = (unsigned char)tgt[b * 1000 + i];
  __syncthreads();
  u16* out = Ind + (size_t)b * 26 * 1024;
  for (int ci = tid; ci < 26 * 128; ci += 256) {
    int v = ci >> 7, c0 = (ci & 127) << 3;
    u16x8 w;
#pragma unroll
    for (int j = 0; j < 8; ++j) {
      int c = c0 + j;
      w[j] = (c < 1000 && tl[c] == v) ? (u16)0x3F80 : (u16)0;
    }
    *(u16x8*)(out + v * 1024 + c0) = w;
  }
}

__global__ __launch_bounds__(256) void conv_xt(const u16* __restrict__ Aall,
    const float* __restrict__ embed, const float* __restrict__ cbias,
    u16* __restrict__ out)
{
  int b = blockIdx.x, tid = threadIdx.x;
  __shared__ __align__(16) float Al[6656];
  __shared__ __align__(16) float el[3360];
  const u16* Ab = Aall + (size_t)b * 6656;
  for (int i = tid; i < 6656; i += 256) Al[i] = b2f(Ab[i]);
  for (int i = tid; i < 3328; i += 256) el[i] = embed[i];
  if (tid < 32) el[3328 + tid] = 0.f;
  __syncthreads();
  for (int grp = tid; grp < 512; grp += 256) {
    int o = grp >> 4;
    int l0 = (grp & 15) << 3;
    float cb = cbias[o];
    float acc[8];
#pragma unroll
    for (int j = 0; j < 8; ++j) acc[j] = cb;
    for (int v = 0; v < 26; ++v) {
      const float* ap = &Al[v * 256 + (o << 3)];
      f32x4 a0 = *(const f32x4*)ap;
      f32x4 a1 = *(const f32x4*)(ap + 4);
      const float* ep = &el[v * 128 + l0];
      f32x4 e0 = *(const f32x4*)ep;
      f32x4 e1 = *(const f32x4*)(ep + 4);
      f32x4 e2 = *(const f32x4*)(ep + 8);
      f32x4 e3 = *(const f32x4*)(ep + 12);
      float a[8] = { a0[0], a0[1], a0[2], a0[3], a1[0], a1[1], a1[2], a1[3] };
      float e[16] = { e0[0], e0[1], e0[2], e0[3], e1[0], e1[1], e1[2], e1[3],
                      e2[0], e2[1], e2[2], e2[3], e3[0], e3[1], e3[2], e3[3] };
#pragma unroll
      for (int k = 0; k < 8; ++k)
#pragma unroll
        for (int j = 0; j < 8; ++j) acc[j] += a[k] * e[k + j];
    }
    int base = o * 121 + l0;
#pragma unroll
    for (int j = 0; j < 8; ++j)
      if (l0 + j < 121) out[(size_t)b * 3872 + base + j] = f2b(acc[j]);
  }
}

// ---------------- final row-dot (bf16 input) ----------------
__global__ __launch_bounds__(256) void final_out(const u16* __restrict__ z2,
    const float* __restrict__ W, const float* __restrict__ bias, float* __restrict__ out)
{
  int row = blockIdx.x * 4 + (threadIdx.x >> 6);
  int lane = threadIdx.x & 63;
  const u16* zr = z2 + (size_t)row * 512;
  float s = 0.f;
  for (int i = lane; i < 512; i += 64) s += b2f(zr[i]) * W[i];
#pragma unroll
  for (int off = 32; off > 0; off >>= 1) s += __shfl_down(s, off, 64);
  if (lane == 0) out[row] = s + bias[0];
}

// ---------------- launch ----------------
extern "C" void kernel_launch(void* const* d_in, const int* in_sizes, int n_in,
                              void* d_out, int out_size, void* d_ws, size_t ws_size,
                              hipStream_t stream)
{
  const float* x        = (const float*)d_in[0];
  const int*   ei       = (const int*)d_in[1];
  const int*   batch    = (const int*)d_in[2];
  const int*   tgt      = (const int*)d_in[3];
  const float* gat_W    = (const float*)d_in[4];
  const float* att_src  = (const float*)d_in[5];
  const float* att_dst  = (const float*)d_in[6];
  const float* gat_bias = (const float*)d_in[7];
  const float* gcn_W    = (const float*)d_in[8];
  const float* gcn_bias = (const float*)d_in[9];
  const float* fcg1_W   = (const float*)d_in[10];
  const float* fcg1_b   = (const float*)d_in[11];
  const float* fcg2_W   = (const float*)d_in[12];
  const float* fcg2_b   = (const float*)d_in[13];
  const float* embed    = (const float*)d_in[14];
  const float* convW    = (const float*)d_in[15];
  const float* convb    = (const float*)d_in[16];
  const float* fc1xt_W  = (const float*)d_in[17];
  const float* fc1xt_b  = (const float*)d_in[18];
  const float* fc1_W    = (const float*)d_in[19];
  const float* fc1_b    = (const float*)d_in[20];
  const float* fc2_W    = (const float*)d_in[21];
  const float* fc2_b    = (const float*)d_in[22];
  const float* out_W    = (const float*)d_in[23];
  const float* out_b    = (const float*)d_in[24];

  const int N = in_sizes[0] / FO;      // 40960
  const int E = in_sizes[1] / 2;       // 163840
  const int B = in_sizes[3] / 1000;    // 1024
  const int ET = E + N;

  char* ws = (char*)d_ws;
  size_t off = 0;
  auto alloc = [&](size_t bytes) -> char* {
    char* p = ws + off;
    off = (off + bytes + 255) & ~(size_t)255;
    return p;
  };
  float* buf0  = (float*)alloc((size_t)N * HID * 4);   // h/h2 -> Ind/A/conv + f32 scratch
  float* buf1  = (float*)alloc((size_t)N * 800 * 2);   // xb -> x1b -> head scratch
  u16*   wt1   = (u16*)alloc((size_t)896 * 96 * 2);
  u16*   wt2   = (u16*)alloc((size_t)896 * 800 * 2);
  u16*   wtg1  = (u16*)alloc((size_t)1536 * 1568 * 2);
  u16*   wtg2  = (u16*)alloc((size_t)128 * 1504 * 2);
  u16*   wtxt  = (u16*)alloc((size_t)128 * 3872 * 2);
  u16*   wtf1  = (u16*)alloc((size_t)1024 * 256 * 2);
  u16*   wtf2  = (u16*)alloc((size_t)512 * 1024 * 2);
  u16*   wtc   = (u16*)alloc((size_t)256 * 1024 * 2);
  float* att   = (float*)alloc((size_t)N * 20 * 4);
  int*   cnt   = (int*)alloc((size_t)N * 4);
  int*   offs  = (int*)alloc((size_t)(N + 1) * 4);
  int*   fillp = (int*)alloc((size_t)N * 4);
  int*   csr   = (int*)alloc((size_t)ET * 4);
  float* dinv  = (float*)alloc((size_t)N * 4);
  u16*   gb    = (u16*)alloc((size_t)B * 1568 * 2);

  u16*   xb    = (u16*)buf1;                 // dead after gemm #1
  u16*   x1b   = (u16*)buf1;                 // gat_gather -> gemm #2
  u16*   hb    = (u16*)buf0;                 // h / h2 bf16 [N][800]
  // protein aliases in buf0 (free after gcn_pool)
  u16*   Ind      = (u16*)buf0;                         // [26624][1024]  54.5MB
  u16*   Ab       = Ind + (size_t)26624 * 1024;         // [26624][256]   13.6MB
  u16*   convflat = Ab + (size_t)26624 * 256;           // [1024][3872]    7.9MB
  // fp32 split-K scratch, contiguous after convflat (~13.5MB; buf0 is 127.8MB)
  float* g1f = (float*)(convflat + (size_t)1024 * 3872);
  float* xtf = g1f + (size_t)1024 * 1500;
  float* g2f = xtf + (size_t)1024 * 128;
  float* z1f = g2f + (size_t)1024 * 128;
  float* z2f = z1f + (size_t)1024 * 1024;
  size_t skBytes = ((size_t)1024 * (1500 + 128 + 128 + 1024 + 512)) * 4;
  // head bf16 buffers in buf1 (after gemm #2 consumed x1b)
  u16* g1b = (u16*)buf1;                     // [1024][1504]
  u16* xcb = g1b + (size_t)1024 * 1504;      // [1024][256] (g2 | xt)
  u16* z1b = xcb + (size_t)1024 * 256;       // [1024][1024]
  u16* z2b = z1b + (size_t)1024 * 1024;      // [1024][512]

  hipMemsetAsync(cnt, 0, (size_t)N * 4, stream);
  hipMemsetAsync(fillp, 0, (size_t)N * 4, stream);

  // conversions + attention fold
  conv_x_bf16<<<(N * 96 + 255) / 256, 256, 0, stream>>>(x, xb, N);
  conv_wT_bf16<<<(896 * 96 + 255) / 256, 256, 0, stream>>>(gat_W, wt1, FO, HID, 96, 896);
  fold_att<<<20, 96, 0, stream>>>(gat_W, att_src, att_dst, wt1);
  conv_wT_bf16<<<(896 * 800 + 255) / 256, 256, 0, stream>>>(gcn_W, wt2, HID, HID, 800, 896);
  conv_wT_bf16<<<(1536 * 1568 + 255) / 256, 256, 0, stream>>>(fcg1_W, wtg1, 1560, 1500, 1568, 1536);
  conv_wT_bf16<<<(128 * 1504 + 255) / 256, 256, 0, stream>>>(fcg2_W, wtg2, 1500, 128, 1504, 128);
  conv_wT_bf16<<<(128 * 3872 + 255) / 256, 256, 0, stream>>>(fc1xt_W, wtxt, 3872, 128, 3872, 128);
  conv_wT_bf16<<<(1024 * 256 + 255) / 256, 256, 0, stream>>>(fc1_W, wtf1, 256, 1024, 256, 1024);
  conv_wT_bf16<<<(512 * 1024 + 255) / 256, 256, 0, stream>>>(fc2_W, wtf2, 1024, 512, 1024, 512);
  conv_w2T<<<(256 * 1024 + 255) / 256, 256, 0, stream>>>(convW, wtc);

  // h = x @ gat_W -> hb bf16 [N][800]; att dots -> att f32
  gemm_mfma<false, false><<<dim3(7, N / 128), 256, 0, stream>>>(
      xb, wt1, hb, att, nullptr, N, HID, 96, 800);

  int egrid = (ET + 255) / 256;
  count_dst<<<egrid, 256, 0, stream>>>(ei, E, N, cnt);
  scan_dinv<<<1, 1024, 0, stream>>>(cnt, offs, dinv, N);
  fill_csr<<<egrid, 256, 0, stream>>>(ei, E, N, offs, fillp, csr);

  gat_gather<<<N, 64, 0, stream>>>(hb, att, offs, csr, gat_bias, x1b);

  // h2 = x1 @ gcn_W -> hb bf16 [N][800]
  gemm_mfma<false, false><<<dim3(7, N / 128), 256, 0, stream>>>(
      x1b, wt2, hb, nullptr, nullptr, N, HID, 800, 800);

  // fused GCN gather + per-graph max/mean pool -> gb bf16 [B][1568]
  gcn_pool<<<B, 256, 0, stream>>>(hb, offs, csr, dinv, gcn_bias, batch, N, gb);

  // protein branch (buf0 free now): A = Ind @ W2 via MFMA, then tiny conv
  build_ind<<<B, 256, 0, stream>>>(tgt, Ind);
  gemm_mfma<false, false><<<dim3(2, 26624 / 128), 256, 0, stream>>>(
      Ind, wtc, Ab, nullptr, nullptr, 26624, 256, 1024, 256);
  conv_xt<<<B, 256, 0, stream>>>(Ab, embed, convb, convflat);

  // ---- head: split-K MFMA GEMMs (fp32 atomics) + bias/act epilogues ----
  hipMemsetAsync(g1f, 0, skBytes, stream);

  // xt = convflat @ fc1xt_W : K=3872 split 16 -> 128 blocks
  gemm_sk<<<dim3(1, B / 128, 16), 256, 0, stream>>>(convflat, wtxt, xtf, B, 128, 3872, 256);
  bias_act_pad<false><<<(B * 128 + 255) / 256, 256, 0, stream>>>(
      xtf, fc1xt_b, xcb + 128, B, 128, 128, 256);

  // g1 = relu(g @ fcg1_W) : K=1568 split 2 -> 192 blocks
  gemm_sk<<<dim3(12, B / 128, 2), 256, 0, stream>>>(gb, wtg1, g1f, B, 1500, 1568, 800);
  bias_act_pad<true><<<(B * 1504 + 255) / 256, 256, 0, stream>>>(
      g1f, fcg1_b, g1b, B, 1500, 1504, 1504);

  // g2 = g1 @ fcg2_W : K=1504 split 8 -> 64 blocks
  gemm_sk<<<dim3(1, B / 128, 8), 256, 0, stream>>>(g1b, wtg2, g2f, B, 128, 1504, 192);
  bias_act_pad<false><<<(B * 128 + 255) / 256, 256, 0, stream>>>(
      g2f, fcg2_b, xcb, B, 128, 128, 256);

  // z1 = relu(xc @ fc1_W) : K=256 split 2 -> 128 blocks
  gemm_sk<<<dim3(8, B / 128, 2), 256, 0, stream>>>(xcb, wtf1, z1f, B, 1024, 256, 128);
  bias_act_pad<true><<<(B * 1024 + 255) / 256, 256, 0, stream>>>(
      z1f, fc1_b, z1b, B, 1024, 1024, 1024);

  // z2 = relu(z1 @ fc2_W) : K=1024 split 4 -> 128 blocks
  gemm_sk<<<dim3(4, B / 128, 4), 256, 0, stream>>>(z1b, wtf2, z2f, B, 512, 1024, 256);
  bias_act_pad<true><<<(B * 512 + 255) / 256, 256, 0, stream>>>(
      z2f, fc2_b, z2b, B, 512, 512, 512);

  final_out<<<B / 4, 256, 0, stream>>>(z2b, out_W, out_b, (float*)d_out);
}

// Round 12
// 621.213 us; speedup vs baseline: 7.7455x; 1.0582x over previous
//
#include <hip/hip_runtime.h>

typedef __attribute__((ext_vector_type(4))) float f32x4;
typedef __attribute__((ext_vector_type(8))) short bf16x8;
typedef __attribute__((ext_vector_type(8))) unsigned short u16x8;
typedef unsigned short u16;

#define HID 780
#define NH 10
#define FO 78

__device__ inline u16 f2b(float f) {  // fp32 -> bf16 RNE
  unsigned u = __float_as_uint(f);
  unsigned r = (u + 0x7fff + ((u >> 16) & 1)) >> 16;
  return (u16)r;
}
__device__ inline float b2f(u16 b) { return __uint_as_float(((unsigned)b) << 16); }

// XCD-chunked swizzle of the full linear block id (bijective when nwg%8==0).
__device__ inline int swz_bid() {
  int gx = gridDim.x, gy = gridDim.y, gz = gridDim.z;
  int nwg = gx * gy * gz;
  int bid = (blockIdx.z * gy + blockIdx.y) * gx + blockIdx.x;
  if ((nwg & 7) == 0) bid = (bid & 7) * (nwg >> 3) + (bid >> 3);
  return bid;
}

// ---------------- bf16 MFMA GEMM, bf16 C out (non-split) ----------------
template<bool BIAS, bool RELU>
__global__ __launch_bounds__(256) void gemm_mfma(const u16* __restrict__ A,
    const u16* __restrict__ BT, u16* __restrict__ C, float* __restrict__ att_out,
    const float* __restrict__ bias, int M, int Ncols, int KP, int ldc)
{
  __shared__ u16 As[128 * 40];
  __shared__ u16 Bs[128 * 40];
  const int tid = threadIdx.x;
  int t = swz_bid();
  const int bx = t % gridDim.x, by = t / gridDim.x;
  const int row0 = by << 7, col0 = bx << 7;
  const int l = tid & 63, wid = tid >> 6;
  const int wr = wid >> 1, wc = wid & 1;
  const int lr = l & 15, lk = l >> 4;
  f32x4 acc[4][4];
#pragma unroll
  for (int i = 0; i < 4; ++i)
#pragma unroll
    for (int j = 0; j < 4; ++j) acc[i][j] = (f32x4){0.f, 0.f, 0.f, 0.f};

  for (int k0 = 0; k0 < KP; k0 += 32) {
    __syncthreads();
#pragma unroll
    for (int i = 0; i < 2; ++i) {
      int c = tid + (i << 8);
      int row = c >> 2, off = c & 3;
      *(uint4*)&As[row * 40 + off * 8] =
          *(const uint4*)(A + (size_t)(row0 + row) * KP + k0 + off * 8);
      *(uint4*)&Bs[row * 40 + off * 8] =
          *(const uint4*)(BT + (size_t)(col0 + row) * KP + k0 + off * 8);
    }
    __syncthreads();
    bf16x8 af[4], bfr[4];
#pragma unroll
    for (int fm = 0; fm < 4; ++fm)
      af[fm] = *(const bf16x8*)&As[(wr * 64 + fm * 16 + lr) * 40 + lk * 8];
#pragma unroll
    for (int fn = 0; fn < 4; ++fn)
      bfr[fn] = *(const bf16x8*)&Bs[(wc * 64 + fn * 16 + lr) * 40 + lk * 8];
#pragma unroll
    for (int fm = 0; fm < 4; ++fm)
#pragma unroll
      for (int fn = 0; fn < 4; ++fn)
        acc[fm][fn] = __builtin_amdgcn_mfma_f32_16x16x32_bf16(af[fm], bfr[fn], acc[fm][fn], 0, 0, 0);
  }
#pragma unroll
  for (int fm = 0; fm < 4; ++fm)
#pragma unroll
    for (int fn = 0; fn < 4; ++fn) {
      int col = col0 + wc * 64 + fn * 16 + lr;
      f32x4 v = acc[fm][fn];
      int rbase = row0 + wr * 64 + fm * 16 + lk * 4;
      if (col < Ncols) {
        float bb = BIAS ? bias[col] : 0.f;
#pragma unroll
        for (int j = 0; j < 4; ++j) {
          float vv = v[j] + bb;
          if (RELU) vv = vv > 0.f ? vv : 0.f;
          C[(size_t)(rbase + j) * ldc + col] = f2b(vv);
        }
      } else {
        if (att_out != nullptr && col < Ncols + 20) {
          int c = col - Ncols;
#pragma unroll
          for (int j = 0; j < 4; ++j)
            att_out[(size_t)(rbase + j) * 20 + c] = v[j];
        }
        if (col < ldc) {
#pragma unroll
          for (int j = 0; j < 4; ++j) C[(size_t)(rbase + j) * ldc + col] = 0;
        }
      }
    }
}

// ---------------- split-K bf16 MFMA GEMM, fp32 atomic partials ----------------
__global__ __launch_bounds__(256) void gemm_sk(const u16* __restrict__ A,
    const u16* __restrict__ BT, float* __restrict__ C,
    int M, int Ncols, int KP, int kchunk)
{
  __shared__ u16 As[128 * 40];
  __shared__ u16 Bs[128 * 40];
  const int tid = threadIdx.x;
  int t = swz_bid();
  const int bx = t % gridDim.x;
  const int by = (t / gridDim.x) % gridDim.y;
  const int bz = t / (gridDim.x * gridDim.y);
  const int row0 = by << 7, col0 = bx << 7;
  const int kbeg = bz * kchunk;
  const int kend = min(KP, kbeg + kchunk);
  const int l = tid & 63, wid = tid >> 6;
  const int wr = wid >> 1, wc = wid & 1;
  const int lr = l & 15, lk = l >> 4;
  f32x4 acc[4][4];
#pragma unroll
  for (int i = 0; i < 4; ++i)
#pragma unroll
    for (int j = 0; j < 4; ++j) acc[i][j] = (f32x4){0.f, 0.f, 0.f, 0.f};

  for (int k0 = kbeg; k0 < kend; k0 += 32) {
    __syncthreads();
#pragma unroll
    for (int i = 0; i < 2; ++i) {
      int c = tid + (i << 8);
      int row = c >> 2, off = c & 3;
      *(uint4*)&As[row * 40 + off * 8] =
          *(const uint4*)(A + (size_t)(row0 + row) * KP + k0 + off * 8);
      *(uint4*)&Bs[row * 40 + off * 8] =
          *(const uint4*)(BT + (size_t)(col0 + row) * KP + k0 + off * 8);
    }
    __syncthreads();
    bf16x8 af[4], bfr[4];
#pragma unroll
    for (int fm = 0; fm < 4; ++fm)
      af[fm] = *(const bf16x8*)&As[(wr * 64 + fm * 16 + lr) * 40 + lk * 8];
#pragma unroll
    for (int fn = 0; fn < 4; ++fn)
      bfr[fn] = *(const bf16x8*)&Bs[(wc * 64 + fn * 16 + lr) * 40 + lk * 8];
#pragma unroll
    for (int fm = 0; fm < 4; ++fm)
#pragma unroll
      for (int fn = 0; fn < 4; ++fn)
        acc[fm][fn] = __builtin_amdgcn_mfma_f32_16x16x32_bf16(af[fm], bfr[fn], acc[fm][fn], 0, 0, 0);
  }
#pragma unroll
  for (int fm = 0; fm < 4; ++fm)
#pragma unroll
    for (int fn = 0; fn < 4; ++fn) {
      int col = col0 + wc * 64 + fn * 16 + lr;
      if (col < Ncols) {
        f32x4 v = acc[fm][fn];
        int rbase = row0 + wr * 64 + fm * 16 + lk * 4;
#pragma unroll
        for (int j = 0; j < 4; ++j)
          atomicAdd(&C[(size_t)(rbase + j) * Ncols + col], v[j]);
      }
    }
}

// fp32 compact [M][N] -> bf16 [M][ldco] with bias/relu, zero-pad cols [N,padTo)
template<bool RELU>
__global__ void bias_act_pad(const float* __restrict__ Cf,
    const float* __restrict__ bias, u16* __restrict__ out,
    int M, int N, int padTo, int ldco)
{
  int idx = blockIdx.x * 256 + threadIdx.x;
  if (idx >= M * padTo) return;
  int r = idx / padTo, c = idx - r * padTo;
  if (c < N) {
    float v = Cf[(size_t)r * N + c] + bias[c];
    if (RELU) v = v > 0.f ? v : 0.f;
    out[(size_t)r * ldco + c] = f2b(v);
  } else {
    out[(size_t)r * ldco + c] = 0;
  }
}

// ---------------- conversions ----------------
__global__ void conv_x_bf16(const float* __restrict__ x, u16* __restrict__ xb, int M)
{
  int idx = blockIdx.x * 256 + threadIdx.x;
  if (idx >= M * 96) return;
  int r = idx / 96, c = idx - r * 96;
  xb[idx] = (c < FO) ? f2b(x[(size_t)r * FO + c]) : (u16)0;
}

// LDS-tiled transpose: WT[n][k] (NP x KP) = bf16(W[k][n]), zero-padded.
// grid: (ceil(NP/32), ceil(KP/32)), 256 threads.
__global__ void conv_wT_bf16(const float* __restrict__ W, u16* __restrict__ WT,
                             int K, int N, int KP, int NP)
{
  __shared__ u16 tbuf[32][33];
  int tn0 = blockIdx.x << 5, tk0 = blockIdx.y << 5;
  int lx = threadIdx.x & 31, ly = threadIdx.x >> 5;
#pragma unroll
  for (int r = 0; r < 32; r += 8) {
    int k = tk0 + ly + r, n = tn0 + lx;
    tbuf[ly + r][lx] = (k < K && n < N) ? f2b(W[(size_t)k * N + n]) : (u16)0;
  }
  __syncthreads();
#pragma unroll
  for (int r = 0; r < 32; r += 8) {
    int n = tn0 + ly + r, k = tk0 + lx;
    if (n < NP && k < KP) WT[(size_t)n * KP + k] = tbuf[lx][ly + r];
  }
}

// W2T[(o*8+k)][c] = bf16(convW[o,c,k]), [256][1024] zero-padded
__global__ void conv_w2T(const float* __restrict__ W, u16* __restrict__ WT)
{
  int idx = blockIdx.x * 256 + threadIdx.x;
  if (idx >= 256 * 1024) return;
  int ok = idx >> 10, c = idx & 1023;
  int o = ok >> 3, k = ok & 7;
  WT[idx] = (c < 1000) ? f2b(W[(size_t)o * 8000 + c * 8 + k]) : (u16)0;
}

// fold attention vectors into wt1 rows 780..799
__global__ void fold_att(const float* __restrict__ gat_W,
    const float* __restrict__ asv, const float* __restrict__ adv,
    u16* __restrict__ wt1)
{
  int j = blockIdx.x;
  int k = threadIdx.x;
  if (k >= 96) return;
  float s = 0.f;
  if (k < FO) {
    int h = (j < 10) ? j : j - 10;
    const float* av = ((j < 10) ? asv : adv) + h * FO;
    const float* wr = gat_W + (size_t)k * HID + h * FO;
    for (int f = 0; f < FO; ++f) s += wr[f] * av[f];
  }
  wt1[(size_t)(HID + j) * 96 + k] = f2b(s);
}

// ---------------- CSR build ----------------
__global__ void count_dst(const int* __restrict__ ei, int E, int N, int* __restrict__ cnt)
{
  int e = blockIdx.x * 256 + threadIdx.x;
  if (e >= E + N) return;
  int dst = (e < E) ? ei[E + e] : (e - E);
  atomicAdd(&cnt[dst], 1);
}

__global__ __launch_bounds__(1024) void scan_dinv(const int* __restrict__ cnt,
    int* __restrict__ offs, float* __restrict__ dinv, int N)
{
  __shared__ int part[1024];
  int tid = threadIdx.x;
  int chunk = (N + 1023) >> 10;
  int b0 = tid * chunk, b1 = min(b0 + chunk, N);
  int s = 0;
  for (int i = b0; i < b1; ++i) s += cnt[i];
  part[tid] = s;
  __syncthreads();
  for (int off = 1; off < 1024; off <<= 1) {
    int v = part[tid];
    int add = (tid >= off) ? part[tid - off] : 0;
    __syncthreads();
    part[tid] = v + add;
    __syncthreads();
  }
  int run = (tid > 0) ? part[tid - 1] : 0;
  for (int i = b0; i < b1; ++i) {
    int c = cnt[i];
    offs[i] = run;
    dinv[i] = c > 0 ? rsqrtf((float)c) : 0.f;
    run += c;
  }
  if (tid == 1023) offs[N] = run;
}

__global__ void fill_csr(const int* __restrict__ ei, int E, int N,
    const int* __restrict__ offs, int* __restrict__ fillpos, int* __restrict__ csr_src)
{
  int e = blockIdx.x * 256 + threadIdx.x;
  if (e >= E + N) return;
  int src, dst;
  if (e < E) { src = ei[e]; dst = ei[E + e]; }
  else { src = e - E; dst = e - E; }
  int p = offs[dst] + atomicAdd(&fillpos[dst], 1);
  csr_src[p] = src;
}

// ---------------- GAT gather: single-pass softmax, u16x8 gather ----------------
#define CH 48
__global__ __launch_bounds__(64) void gat_gather(const u16* __restrict__ h,
    const float* __restrict__ att,
    const int* __restrict__ offs, const int* __restrict__ csr_src,
    const float* __restrict__ gat_bias, u16* __restrict__ x1b)
{
  int n = blockIdx.x, lane = threadIdx.x;
  int o0 = offs[n], deg = offs[n + 1] - o0;
  __shared__ float ad[NH], ssum[NH];
  __shared__ float wbuf[CH][NH];
  __shared__ int slist[CH];
  if (lane < NH) { ad[lane] = att[n * 20 + 10 + lane]; ssum[lane] = 0.f; }
  const int s0 = lane, s1 = 64 + lane;
  const bool a1 = s1 < 100;
  int hA0 = min((s0 * 8) / FO, NH - 1), bb0 = FO * ((s0 * 8) / FO + 1) - s0 * 8;
  int hB0 = min((s0 * 8) / FO + 1, NH - 1);
  int hA1 = min((s1 * 8) / FO, NH - 1), bb1 = FO * ((s1 * 8) / FO + 1) - s1 * 8;
  int hB1 = min((s1 * 8) / FO + 1, NH - 1);
  float acc0[8], acc1[8];
#pragma unroll
  for (int j = 0; j < 8; ++j) { acc0[j] = 0.f; acc1[j] = 0.f; }
  __syncthreads();

  for (int e0 = 0; e0 < deg; e0 += CH) {
    int ce = min(CH, deg - e0);
    for (int idx = lane; idx < ce * NH; idx += 64) {
      int e = idx / NH, hd = idx - e * NH;
      int s = csr_src[o0 + e0 + e];
      float l = att[s * 20 + hd] + ad[hd];
      l = l > 0.f ? l : 0.2f * l;
      float w = __expf(l);
      wbuf[e][hd] = w;
      atomicAdd(&ssum[hd], w);
    }
    for (int idx = lane; idx < ce; idx += 64) slist[idx] = csr_src[o0 + e0 + idx];
    __syncthreads();
    for (int e = 0; e < ce; ++e) {
      const u16* hs = h + (size_t)slist[e] * 800;
      u16x8 v0 = *(const u16x8*)(hs + s0 * 8);
      float wA0 = wbuf[e][hA0], wB0 = wbuf[e][hB0];
#pragma unroll
      for (int j = 0; j < 8; ++j)
        acc0[j] += (j < bb0 ? wA0 : wB0) * b2f(v0[j]);
      if (a1) {
        u16x8 v1 = *(const u16x8*)(hs + s1 * 8);
        float wA1 = wbuf[e][hA1], wB1 = wbuf[e][hB1];
#pragma unroll
        for (int j = 0; j < 8; ++j)
          acc1[j] += (j < bb1 ? wA1 : wB1) * b2f(v1[j]);
      }
    }
    __syncthreads();
  }
  float iA0 = 1.f / (ssum[hA0] + 1e-16f), iB0 = 1.f / (ssum[hB0] + 1e-16f);
  u16x8 o0v;
#pragma unroll
  for (int j = 0; j < 8; ++j) {
    int f = s0 * 8 + j;
    float v = acc0[j] * (j < bb0 ? iA0 : iB0) + gat_bias[f];
    o0v[j] = f2b(v > 0.f ? v : 0.f);
  }
  *(u16x8*)(x1b + (size_t)n * 800 + s0 * 8) = o0v;
  if (a1) {
    float iA1 = 1.f / (ssum[hA1] + 1e-16f), iB1 = 1.f / (ssum[hB1] + 1e-16f);
    u16x8 o1v;
#pragma unroll
    for (int j = 0; j < 8; ++j) {
      int f = s1 * 8 + j;
      if (f < HID) {
        float v = acc1[j] * (j < bb1 ? iA1 : iB1) + gat_bias[f];
        o1v[j] = f2b(v > 0.f ? v : 0.f);
      } else o1v[j] = 0;
    }
    *(u16x8*)(x1b + (size_t)n * 800 + s1 * 8) = o1v;
  }
}

// ---------------- GCN gather + per-graph pooling, u16x8 gather ----------------
__global__ __launch_bounds__(256) void gcn_pool(const u16* __restrict__ h2,
    const int* __restrict__ offs, const int* __restrict__ csr_src,
    const float* __restrict__ dinv, const float* __restrict__ gcn_bias,
    const int* __restrict__ batch, int N, u16* __restrict__ gb)
{
  int gi = blockIdx.x, tid = threadIdx.x;
  int grp = tid >> 6, lane = tid & 63;
  __shared__ int se[2];
  __shared__ float smx[HID];
  __shared__ float ssm[HID];
  for (int f = tid; f < HID; f += 256) { smx[f] = 0.f; ssm[f] = 0.f; }
  if (tid < 2) {
    int target = gi + tid;
    int lo = 0, hi = N;
    while (lo < hi) { int mid = (lo + hi) >> 1; if (batch[mid] < target) lo = mid + 1; else hi = mid; }
    se[tid] = lo;
  }
  __syncthreads();
  int s = se[0], e = se[1];
  const int s0 = lane, s1 = 64 + lane;
  const bool a1 = s1 < 100;
  float bv0[8], bv1[8];
#pragma unroll
  for (int j = 0; j < 8; ++j) {
    int f0 = s0 * 8 + j, f1 = s1 * 8 + j;
    bv0[j] = gcn_bias[f0];
    bv1[j] = (a1 && f1 < HID) ? gcn_bias[f1] : 0.f;
  }
  float mx0[8], sm0[8], mx1[8], sm1[8];
#pragma unroll
  for (int j = 0; j < 8; ++j) { mx0[j] = 0.f; sm0[j] = 0.f; mx1[j] = 0.f; sm1[j] = 0.f; }

  for (int n = s + grp; n < e; n += 4) {
    int o0 = offs[n], deg = offs[n + 1] - o0;
    float dn = dinv[n];
    float acc0[8], acc1[8];
#pragma unroll
    for (int j = 0; j < 8; ++j) { acc0[j] = 0.f; acc1[j] = 0.f; }
    for (int ed = 0; ed < deg; ++ed) {
      int src = csr_src[o0 + ed];
      float c = dn * dinv[src];
      const u16* hr = h2 + (size_t)src * 800;
      u16x8 v0 = *(const u16x8*)(hr + s0 * 8);
#pragma unroll
      for (int j = 0; j < 8; ++j) acc0[j] += c * b2f(v0[j]);
      if (a1) {
        u16x8 v1 = *(const u16x8*)(hr + s1 * 8);
#pragma unroll
        for (int j = 0; j < 8; ++j) acc1[j] += c * b2f(v1[j]);
      }
    }
#pragma unroll
    for (int j = 0; j < 8; ++j) {
      float v = acc0[j] + bv0[j];
      v = v > 0.f ? v : 0.f;
      mx0[j] = fmaxf(mx0[j], v); sm0[j] += v;
      float w = acc1[j] + bv1[j];
      w = w > 0.f ? w : 0.f;
      mx1[j] = fmaxf(mx1[j], w); sm1[j] += w;
    }
  }
#pragma unroll
  for (int j = 0; j < 8; ++j) {
    int f0 = s0 * 8 + j;
    atomicMax((unsigned*)&smx[f0], __float_as_uint(mx0[j]));
    atomicAdd(&ssm[f0], sm0[j]);
    int f1 = s1 * 8 + j;
    if (a1 && f1 < HID) {
      atomicMax((unsigned*)&smx[f1], __float_as_uint(mx1[j]));
      atomicAdd(&ssm[f1], sm1[j]);
    }
  }
  __syncthreads();
  float inv = 1.f / fmaxf((float)(e - s), 1.f);
  for (int f = tid; f < HID; f += 256) {
    gb[(size_t)gi * 1568 + f] = f2b(smx[f]);
    gb[(size_t)gi * 1568 + HID + f] = f2b(ssm[f] * inv);
  }
  if (tid < 8) gb[(size_t)gi * 1568 + 1560 + tid] = 0;
}

// ---------------- protein branch ----------------
__global__ __launch_bounds__(256) void build_ind(const int* __restrict__ tgt,
    u16* __restrict__ Ind)
{
  int b = blockIdx.x, tid = threadIdx.x;
  __shared__ unsigned char tl[1000];
  for (int i = tid; i < 1000; i += 256) tl[i] = (unsigned char)tgt[b * 1000 + i];
  __syncthreads();
  u16* out = Ind + (size_t)b * 26 * 1024;
  for (int ci = tid; ci < 26 * 128; ci += 256) {
    int v = ci >> 7, c0 = (ci & 127) << 3;
    u16x8 w;
#pragma unroll
    for (int j = 0; j < 8; ++j) {
      int c = c0 + j;
      w[j] = (c < 1000 && tl[c] == v) ? (u16)0x3F80 : (u16)0;
    }
    *(u16x8*)(out + v * 1024 + c0) = w;
  }
}

__global__ __launch_bounds__(256) void conv_xt(const u16* __restrict__ Aall,
    const float* __restrict__ embed, const float* __restrict__ cbias,
    u16* __restrict__ out)
{
  int b = blockIdx.x, tid = threadIdx.x;
  __shared__ __align__(16) float Al[6656];
  __shared__ __align__(16) float el[3360];
  const u16* Ab = Aall + (size_t)b * 6656;
  for (int i = tid; i < 6656; i += 256) Al[i] = b2f(Ab[i]);
  for (int i = tid; i < 3328; i += 256) el[i] = embed[i];
  if (tid < 32) el[3328 + tid] = 0.f;
  __syncthreads();
  for (int grp = tid; grp < 512; grp += 256) {
    int o = grp >> 4;
    int l0 = (grp & 15) << 3;
    float cb = cbias[o];
    float acc[8];
#pragma unroll
    for (int j = 0; j < 8; ++j) acc[j] = cb;
    for (int v = 0; v < 26; ++v) {
      const float* ap = &Al[v * 256 + (o << 3)];
      f32x4 a0 = *(const f32x4*)ap;
      f32x4 a1 = *(const f32x4*)(ap + 4);
      const float* ep = &el[v * 128 + l0];
      f32x4 e0 = *(const f32x4*)ep;
      f32x4 e1 = *(const f32x4*)(ep + 4);
      f32x4 e2 = *(const f32x4*)(ep + 8);
      f32x4 e3 = *(const f32x4*)(ep + 12);
      float a[8] = { a0[0], a0[1], a0[2], a0[3], a1[0], a1[1], a1[2], a1[3] };
      float e[16] = { e0[0], e0[1], e0[2], e0[3], e1[0], e1[1], e1[2], e1[3],
                      e2[0], e2[1], e2[2], e2[3], e3[0], e3[1], e3[2], e3[3] };
#pragma unroll
      for (int k = 0; k < 8; ++k)
#pragma unroll
        for (int j = 0; j < 8; ++j) acc[j] += a[k] * e[k + j];
    }
    int base = o * 121 + l0;
#pragma unroll
    for (int j = 0; j < 8; ++j)
      if (l0 + j < 121) out[(size_t)b * 3872 + base + j] = f2b(acc[j]);
  }
}

// ---------------- final row-dot (bf16 input) ----------------
__global__ __launch_bounds__(256) void final_out(const u16* __restrict__ z2,
    const float* __restrict__ W, const float* __restrict__ bias, float* __restrict__ out)
{
  int row = blockIdx.x * 4 + (threadIdx.x >> 6);
  int lane = threadIdx.x & 63;
  const u16* zr = z2 + (size_t)row * 512;
  float s = 0.f;
  for (int i = lane; i < 512; i += 64) s += b2f(zr[i]) * W[i];
#pragma unroll
  for (int off = 32; off > 0; off >>= 1) s += __shfl_down(s, off, 64);
  if (lane == 0) out[row] = s + bias[0];
}

// ---------------- launch ----------------
extern "C" void kernel_launch(void* const* d_in, const int* in_sizes, int n_in,
                              void* d_out, int out_size, void* d_ws, size_t ws_size,
                              hipStream_t stream)
{
  const float* x        = (const float*)d_in[0];
  const int*   ei       = (const int*)d_in[1];
  const int*   batch    = (const int*)d_in[2];
  const int*   tgt      = (const int*)d_in[3];
  const float* gat_W    = (const float*)d_in[4];
  const float* att_src  = (const float*)d_in[5];
  const float* att_dst  = (const float*)d_in[6];
  const float* gat_bias = (const float*)d_in[7];
  const float* gcn_W    = (const float*)d_in[8];
  const float* gcn_bias = (const float*)d_in[9];
  const float* fcg1_W   = (const float*)d_in[10];
  const float* fcg1_b   = (const float*)d_in[11];
  const float* fcg2_W   = (const float*)d_in[12];
  const float* fcg2_b   = (const float*)d_in[13];
  const float* embed    = (const float*)d_in[14];
  const float* convW    = (const float*)d_in[15];
  const float* convb    = (const float*)d_in[16];
  const float* fc1xt_W  = (const float*)d_in[17];
  const float* fc1xt_b  = (const float*)d_in[18];
  const float* fc1_W    = (const float*)d_in[19];
  const float* fc1_b    = (const float*)d_in[20];
  const float* fc2_W    = (const float*)d_in[21];
  const float* fc2_b    = (const float*)d_in[22];
  const float* out_W    = (const float*)d_in[23];
  const float* out_b    = (const float*)d_in[24];

  const int N = in_sizes[0] / FO;      // 40960
  const int E = in_sizes[1] / 2;       // 163840
  const int B = in_sizes[3] / 1000;    // 1024
  const int ET = E + N;

  char* ws = (char*)d_ws;
  size_t off = 0;
  auto alloc = [&](size_t bytes) -> char* {
    char* p = ws + off;
    off = (off + bytes + 255) & ~(size_t)255;
    return p;
  };
  float* buf0  = (float*)alloc((size_t)N * HID * 4);   // h/h2 -> Ind/A/conv + f32 scratch
  float* buf1  = (float*)alloc((size_t)N * 800 * 2);   // xb -> x1b -> head scratch
  u16*   wt1   = (u16*)alloc((size_t)896 * 96 * 2);
  u16*   wt2   = (u16*)alloc((size_t)896 * 800 * 2);
  u16*   wtg1  = (u16*)alloc((size_t)1536 * 1568 * 2);
  u16*   wtg2  = (u16*)alloc((size_t)128 * 1504 * 2);
  u16*   wtxt  = (u16*)alloc((size_t)128 * 3872 * 2);
  u16*   wtf1  = (u16*)alloc((size_t)1024 * 256 * 2);
  u16*   wtf2  = (u16*)alloc((size_t)512 * 1024 * 2);
  u16*   wtc   = (u16*)alloc((size_t)256 * 1024 * 2);
  float* att   = (float*)alloc((size_t)N * 20 * 4);
  int*   cnt   = (int*)alloc((size_t)N * 4);
  int*   offs  = (int*)alloc((size_t)(N + 1) * 4);
  int*   fillp = (int*)alloc((size_t)N * 4);
  int*   csr   = (int*)alloc((size_t)ET * 4);
  float* dinv  = (float*)alloc((size_t)N * 4);
  u16*   gb    = (u16*)alloc((size_t)B * 1568 * 2);

  u16*   xb    = (u16*)buf1;
  u16*   x1b   = (u16*)buf1;
  u16*   hb    = (u16*)buf0;
  u16*   Ind      = (u16*)buf0;                         // [26624][1024]
  u16*   Ab       = Ind + (size_t)26624 * 1024;         // [26624][256]
  u16*   convflat = Ab + (size_t)26624 * 256;           // [1024][3872]
  float* g1f = (float*)(convflat + (size_t)1024 * 3872);
  float* xtf = g1f + (size_t)1024 * 1500;
  float* g2f = xtf + (size_t)1024 * 128;
  float* z1f = g2f + (size_t)1024 * 128;
  float* z2f = z1f + (size_t)1024 * 1024;
  size_t skBytes = ((size_t)1024 * (1500 + 128 + 128 + 1024 + 512)) * 4;
  u16* g1b = (u16*)buf1;                     // [1024][1504]
  u16* xcb = g1b + (size_t)1024 * 1504;      // [1024][256] (g2 | xt)
  u16* z1b = xcb + (size_t)1024 * 256;       // [1024][1024]
  u16* z2b = z1b + (size_t)1024 * 1024;      // [1024][512]

  hipMemsetAsync(cnt, 0, (size_t)N * 4, stream);
  hipMemsetAsync(fillp, 0, (size_t)N * 4, stream);

  // conversions + attention fold (tiled transposes)
  conv_x_bf16<<<(N * 96 + 255) / 256, 256, 0, stream>>>(x, xb, N);
  conv_wT_bf16<<<dim3(896 / 32, 96 / 32), 256, 0, stream>>>(gat_W, wt1, FO, HID, 96, 896);
  fold_att<<<20, 96, 0, stream>>>(gat_W, att_src, att_dst, wt1);
  conv_wT_bf16<<<dim3(896 / 32, 800 / 32), 256, 0, stream>>>(gcn_W, wt2, HID, HID, 800, 896);
  conv_wT_bf16<<<dim3(1536 / 32, 1568 / 32), 256, 0, stream>>>(fcg1_W, wtg1, 1560, 1500, 1568, 1536);
  conv_wT_bf16<<<dim3(128 / 32, 1504 / 32), 256, 0, stream>>>(fcg2_W, wtg2, 1500, 128, 1504, 128);
  conv_wT_bf16<<<dim3(128 / 32, 3872 / 32), 256, 0, stream>>>(fc1xt_W, wtxt, 3872, 128, 3872, 128);
  conv_wT_bf16<<<dim3(1024 / 32, 256 / 32), 256, 0, stream>>>(fc1_W, wtf1, 256, 1024, 256, 1024);
  conv_wT_bf16<<<dim3(512 / 32, 1024 / 32), 256, 0, stream>>>(fc2_W, wtf2, 1024, 512, 1024, 512);
  conv_w2T<<<(256 * 1024 + 255) / 256, 256, 0, stream>>>(convW, wtc);

  // h = x @ gat_W -> hb bf16 [N][800]; att dots -> att f32
  gemm_mfma<false, false><<<dim3(7, N / 128), 256, 0, stream>>>(
      xb, wt1, hb, att, nullptr, N, HID, 96, 800);

  int egrid = (ET + 255) / 256;
  count_dst<<<egrid, 256, 0, stream>>>(ei, E, N, cnt);
  scan_dinv<<<1, 1024, 0, stream>>>(cnt, offs, dinv, N);
  fill_csr<<<egrid, 256, 0, stream>>>(ei, E, N, offs, fillp, csr);

  gat_gather<<<N, 64, 0, stream>>>(hb, att, offs, csr, gat_bias, x1b);

  // h2 = x1 @ gcn_W -> hb bf16 [N][800]
  gemm_mfma<false, false><<<dim3(7, N / 128), 256, 0, stream>>>(
      x1b, wt2, hb, nullptr, nullptr, N, HID, 800, 800);

  // fused GCN gather + per-graph max/mean pool -> gb bf16 [B][1568]
  gcn_pool<<<B, 256, 0, stream>>>(hb, offs, csr, dinv, gcn_bias, batch, N, gb);

  // protein branch: A = Ind @ W2 via MFMA, then tiny conv
  build_ind<<<B, 256, 0, stream>>>(tgt, Ind);
  gemm_mfma<false, false><<<dim3(2, 26624 / 128), 256, 0, stream>>>(
      Ind, wtc, Ab, nullptr, nullptr, 26624, 256, 1024, 256);
  conv_xt<<<B, 256, 0, stream>>>(Ab, embed, convb, convflat);

  // ---- head: split-K MFMA GEMMs (fp32 atomics) + bias/act epilogues ----
  hipMemsetAsync(g1f, 0, skBytes, stream);

  gemm_sk<<<dim3(1, B / 128, 16), 256, 0, stream>>>(convflat, wtxt, xtf, B, 128, 3872, 256);
  bias_act_pad<false><<<(B * 128 + 255) / 256, 256, 0, stream>>>(
      xtf, fc1xt_b, xcb + 128, B, 128, 128, 256);

  gemm_sk<<<dim3(12, B / 128, 2), 256, 0, stream>>>(gb, wtg1, g1f, B, 1500, 1568, 800);
  bias_act_pad<true><<<(B * 1504 + 255) / 256, 256, 0, stream>>>(
      g1f, fcg1_b, g1b, B, 1500, 1504, 1504);

  gemm_sk<<<dim3(1, B / 128, 8), 256, 0, stream>>>(g1b, wtg2, g2f, B, 128, 1504, 192);
  bias_act_pad<false><<<(B * 128 + 255) / 256, 256, 0, stream>>>(
      g2f, fcg2_b, xcb, B, 128, 128, 256);

  gemm_sk<<<dim3(8, B / 128, 2), 256, 0, stream>>>(xcb, wtf1, z1f, B, 1024, 256, 128);
  bias_act_pad<true><<<(B * 1024 + 255) / 256, 256, 0, stream>>>(
      z1f, fc1_b, z1b, B, 1024, 1024, 1024);

  gemm_sk<<<dim3(4, B / 128, 4), 256, 0, stream>>>(z1b, wtf2, z2f, B, 512, 1024, 256);
  bias_act_pad<true><<<(B * 512 + 255) / 256, 256, 0, stream>>>(
      z2f, fc2_b, z2b, B, 512, 512, 512);

  final_out<<<B / 4, 256, 0, stream>>>(z2b, out_W, out_b, (float*)d_out);
}

// Round 13
// 611.407 us; speedup vs baseline: 7.8697x; 1.0160x over previous
//
#include <hip/hip_runtime.h>

typedef __attribute__((ext_vector_type(4))) float f32x4;
typedef __attribute__((ext_vector_type(8))) short bf16x8;
typedef __attribute__((ext_vector_type(8))) unsigned short u16x8;
typedef unsigned short u16;

#define HID 780
#define NH 10
#define FO 78

__device__ inline u16 f2b(float f) {  // fp32 -> bf16 RNE
  unsigned u = __float_as_uint(f);
  unsigned r = (u + 0x7fff + ((u >> 16) & 1)) >> 16;
  return (u16)r;
}
__device__ inline float b2f(u16 b) { return __uint_as_float(((unsigned)b) << 16); }

// async global->LDS, 16B per lane; lds dest = (wave-uniform) l + lane*16
__device__ inline void gld16(const u16* g, u16* l) {
  __builtin_amdgcn_global_load_lds(
      (const __attribute__((address_space(1))) unsigned int*)g,
      (__attribute__((address_space(3))) unsigned int*)l, 16, 0, 0);
}

// XCD-chunked swizzle of the full linear block id (bijective when nwg%8==0).
__device__ inline int swz_bid() {
  int gx = gridDim.x, gy = gridDim.y, gz = gridDim.z;
  int nwg = gx * gy * gz;
  int bid = (blockIdx.z * gy + blockIdx.y) * gx + blockIdx.x;
  if ((nwg & 7) == 0) bid = (bid & 7) * (nwg >> 3) + (bid >> 3);
  return bid;
}

// ---------------- bf16 MFMA GEMM, bf16 C out (non-split) ----------------
// LDS linear [128][32] u16 per K-step; staged via global_load_lds (width 16).
template<bool BIAS, bool RELU>
__global__ __launch_bounds__(256) void gemm_mfma(const u16* __restrict__ A,
    const u16* __restrict__ BT, u16* __restrict__ C, float* __restrict__ att_out,
    const float* __restrict__ bias, int M, int Ncols, int KP, int ldc)
{
  __shared__ u16 As[128 * 32];
  __shared__ u16 Bs[128 * 32];
  const int tid = threadIdx.x;
  int t = swz_bid();
  const int bx = t % gridDim.x, by = t / gridDim.x;
  const int row0 = by << 7, col0 = bx << 7;
  const int l = tid & 63, wid = tid >> 6;
  const int wr = wid >> 1, wc = wid & 1;
  const int lr = l & 15, lk = l >> 4;
  f32x4 acc[4][4];
#pragma unroll
  for (int i = 0; i < 4; ++i)
#pragma unroll
    for (int j = 0; j < 4; ++j) acc[i][j] = (f32x4){0.f, 0.f, 0.f, 0.f};

  for (int k0 = 0; k0 < KP; k0 += 32) {
    __syncthreads();
#pragma unroll
    for (int i = 0; i < 2; ++i) {
      int cbase = (i << 8) + (wid << 6);     // wave-uniform
      int c = cbase + l;
      gld16(A + (size_t)(row0 + (c >> 2)) * KP + k0 + ((c & 3) << 3), &As[cbase << 3]);
      gld16(BT + (size_t)(col0 + (c >> 2)) * KP + k0 + ((c & 3) << 3), &Bs[cbase << 3]);
    }
    __syncthreads();
    bf16x8 af[4], bfr[4];
#pragma unroll
    for (int fm = 0; fm < 4; ++fm)
      af[fm] = *(const bf16x8*)&As[((wr * 64 + fm * 16 + lr) << 5) + (lk << 3)];
#pragma unroll
    for (int fn = 0; fn < 4; ++fn)
      bfr[fn] = *(const bf16x8*)&Bs[((wc * 64 + fn * 16 + lr) << 5) + (lk << 3)];
#pragma unroll
    for (int fm = 0; fm < 4; ++fm)
#pragma unroll
      for (int fn = 0; fn < 4; ++fn)
        acc[fm][fn] = __builtin_amdgcn_mfma_f32_16x16x32_bf16(af[fm], bfr[fn], acc[fm][fn], 0, 0, 0);
  }
#pragma unroll
  for (int fm = 0; fm < 4; ++fm)
#pragma unroll
    for (int fn = 0; fn < 4; ++fn) {
      int col = col0 + wc * 64 + fn * 16 + lr;
      f32x4 v = acc[fm][fn];
      int rbase = row0 + wr * 64 + fm * 16 + lk * 4;
      if (col < Ncols) {
        float bb = BIAS ? bias[col] : 0.f;
#pragma unroll
        for (int j = 0; j < 4; ++j) {
          float vv = v[j] + bb;
          if (RELU) vv = vv > 0.f ? vv : 0.f;
          C[(size_t)(rbase + j) * ldc + col] = f2b(vv);
        }
      } else {
        if (att_out != nullptr && col < Ncols + 20) {
          int c = col - Ncols;
#pragma unroll
          for (int j = 0; j < 4; ++j)
            att_out[(size_t)(rbase + j) * 20 + c] = v[j];
        }
        if (col < ldc) {
#pragma unroll
          for (int j = 0; j < 4; ++j) C[(size_t)(rbase + j) * ldc + col] = 0;
        }
      }
    }
}

// ---------------- split-K bf16 MFMA GEMM, fp32 atomic partials ----------------
__global__ __launch_bounds__(256) void gemm_sk(const u16* __restrict__ A,
    const u16* __restrict__ BT, float* __restrict__ C,
    int M, int Ncols, int KP, int kchunk)
{
  __shared__ u16 As[128 * 32];
  __shared__ u16 Bs[128 * 32];
  const int tid = threadIdx.x;
  int t = swz_bid();
  const int bx = t % gridDim.x;
  const int by = (t / gridDim.x) % gridDim.y;
  const int bz = t / (gridDim.x * gridDim.y);
  const int row0 = by << 7, col0 = bx << 7;
  const int kbeg = bz * kchunk;
  const int kend = min(KP, kbeg + kchunk);
  const int l = tid & 63, wid = tid >> 6;
  const int wr = wid >> 1, wc = wid & 1;
  const int lr = l & 15, lk = l >> 4;
  f32x4 acc[4][4];
#pragma unroll
  for (int i = 0; i < 4; ++i)
#pragma unroll
    for (int j = 0; j < 4; ++j) acc[i][j] = (f32x4){0.f, 0.f, 0.f, 0.f};

  for (int k0 = kbeg; k0 < kend; k0 += 32) {
    __syncthreads();
#pragma unroll
    for (int i = 0; i < 2; ++i) {
      int cbase = (i << 8) + (wid << 6);
      int c = cbase + l;
      gld16(A + (size_t)(row0 + (c >> 2)) * KP + k0 + ((c & 3) << 3), &As[cbase << 3]);
      gld16(BT + (size_t)(col0 + (c >> 2)) * KP + k0 + ((c & 3) << 3), &Bs[cbase << 3]);
    }
    __syncthreads();
    bf16x8 af[4], bfr[4];
#pragma unroll
    for (int fm = 0; fm < 4; ++fm)
      af[fm] = *(const bf16x8*)&As[((wr * 64 + fm * 16 + lr) << 5) + (lk << 3)];
#pragma unroll
    for (int fn = 0; fn < 4; ++fn)
      bfr[fn] = *(const bf16x8*)&Bs[((wc * 64 + fn * 16 + lr) << 5) + (lk << 3)];
#pragma unroll
    for (int fm = 0; fm < 4; ++fm)
#pragma unroll
      for (int fn = 0; fn < 4; ++fn)
        acc[fm][fn] = __builtin_amdgcn_mfma_f32_16x16x32_bf16(af[fm], bfr[fn], acc[fm][fn], 0, 0, 0);
  }
#pragma unroll
  for (int fm = 0; fm < 4; ++fm)
#pragma unroll
    for (int fn = 0; fn < 4; ++fn) {
      int col = col0 + wc * 64 + fn * 16 + lr;
      if (col < Ncols) {
        f32x4 v = acc[fm][fn];
        int rbase = row0 + wr * 64 + fm * 16 + lk * 4;
#pragma unroll
        for (int j = 0; j < 4; ++j)
          atomicAdd(&C[(size_t)(rbase + j) * Ncols + col], v[j]);
      }
    }
}

// fp32 compact [M][N] -> bf16 [M][ldco] with bias/relu, zero-pad cols [N,padTo)
template<bool RELU>
__global__ void bias_act_pad(const float* __restrict__ Cf,
    const float* __restrict__ bias, u16* __restrict__ out,
    int M, int N, int padTo, int ldco)
{
  int idx = blockIdx.x * 256 + threadIdx.x;
  if (idx >= M * padTo) return;
  int r = idx / padTo, c = idx - r * padTo;
  if (c < N) {
    float v = Cf[(size_t)r * N + c] + bias[c];
    if (RELU) v = v > 0.f ? v : 0.f;
    out[(size_t)r * ldco + c] = f2b(v);
  } else {
    out[(size_t)r * ldco + c] = 0;
  }
}

// ---------------- conversions ----------------
__global__ void conv_x_bf16(const float* __restrict__ x, u16* __restrict__ xb, int M)
{
  int idx = blockIdx.x * 256 + threadIdx.x;
  if (idx >= M * 96) return;
  int r = idx / 96, c = idx - r * 96;
  xb[idx] = (c < FO) ? f2b(x[(size_t)r * FO + c]) : (u16)0;
}

// LDS-tiled transpose: WT[n][k] (NP x KP) = bf16(W[k][n]), zero-padded.
__global__ void conv_wT_bf16(const float* __restrict__ W, u16* __restrict__ WT,
                             int K, int N, int KP, int NP)
{
  __shared__ u16 tbuf[32][33];
  int tn0 = blockIdx.x << 5, tk0 = blockIdx.y << 5;
  int lx = threadIdx.x & 31, ly = threadIdx.x >> 5;
#pragma unroll
  for (int r = 0; r < 32; r += 8) {
    int k = tk0 + ly + r, n = tn0 + lx;
    tbuf[ly + r][lx] = (k < K && n < N) ? f2b(W[(size_t)k * N + n]) : (u16)0;
  }
  __syncthreads();
#pragma unroll
  for (int r = 0; r < 32; r += 8) {
    int n = tn0 + ly + r, k = tk0 + lx;
    if (n < NP && k < KP) WT[(size_t)n * KP + k] = tbuf[lx][ly + r];
  }
}

// W2T[(o*8+k)][c] = bf16(convW[o,c,k]), [256][1024] zero-padded
__global__ void conv_w2T(const float* __restrict__ W, u16* __restrict__ WT)
{
  int idx = blockIdx.x * 256 + threadIdx.x;
  if (idx >= 256 * 1024) return;
  int ok = idx >> 10, c = idx & 1023;
  int o = ok >> 3, k = ok & 7;
  WT[idx] = (c < 1000) ? f2b(W[(size_t)o * 8000 + c * 8 + k]) : (u16)0;
}

// fold attention vectors into wt1 rows 780..799
__global__ void fold_att(const float* __restrict__ gat_W,
    const float* __restrict__ asv, const float* __restrict__ adv,
    u16* __restrict__ wt1)
{
  int j = blockIdx.x;
  int k = threadIdx.x;
  if (k >= 96) return;
  float s = 0.f;
  if (k < FO) {
    int h = (j < 10) ? j : j - 10;
    const float* av = ((j < 10) ? asv : adv) + h * FO;
    const float* wr = gat_W + (size_t)k * HID + h * FO;
    for (int f = 0; f < FO; ++f) s += wr[f] * av[f];
  }
  wt1[(size_t)(HID + j) * 96 + k] = f2b(s);
}

// ---------------- CSR build ----------------
__global__ void count_dst(const int* __restrict__ ei, int E, int N, int* __restrict__ cnt)
{
  int e = blockIdx.x * 256 + threadIdx.x;
  if (e >= E + N) return;
  int dst = (e < E) ? ei[E + e] : (e - E);
  atomicAdd(&cnt[dst], 1);
}

__global__ __launch_bounds__(1024) void scan_dinv(const int* __restrict__ cnt,
    int* __restrict__ offs, float* __restrict__ dinv, int N)
{
  __shared__ int part[1024];
  int tid = threadIdx.x;
  int chunk = (N + 1023) >> 10;
  int b0 = tid * chunk, b1 = min(b0 + chunk, N);
  int s = 0;
  for (int i = b0; i < b1; ++i) s += cnt[i];
  part[tid] = s;
  __syncthreads();
  for (int off = 1; off < 1024; off <<= 1) {
    int v = part[tid];
    int add = (tid >= off) ? part[tid - off] : 0;
    __syncthreads();
    part[tid] = v + add;
    __syncthreads();
  }
  int run = (tid > 0) ? part[tid - 1] : 0;
  for (int i = b0; i < b1; ++i) {
    int c = cnt[i];
    offs[i] = run;
    dinv[i] = c > 0 ? rsqrtf((float)c) : 0.f;
    run += c;
  }
  if (tid == 1023) offs[N] = run;
}

__global__ void fill_csr(const int* __restrict__ ei, int E, int N,
    const int* __restrict__ offs, int* __restrict__ fillpos, int* __restrict__ csr_src)
{
  int e = blockIdx.x * 256 + threadIdx.x;
  if (e >= E + N) return;
  int src, dst;
  if (e < E) { src = ei[e]; dst = ei[E + e]; }
  else { src = e - E; dst = e - E; }
  int p = offs[dst] + atomicAdd(&fillpos[dst], 1);
  csr_src[p] = src;
}

// ---------------- GAT gather: single-pass softmax, u16x8 gather ----------------
#define CH 48
__global__ __launch_bounds__(64) void gat_gather(const u16* __restrict__ h,
    const float* __restrict__ att,
    const int* __restrict__ offs, const int* __restrict__ csr_src,
    const float* __restrict__ gat_bias, u16* __restrict__ x1b)
{
  int n = blockIdx.x, lane = threadIdx.x;
  int o0 = offs[n], deg = offs[n + 1] - o0;
  __shared__ float ad[NH], ssum[NH];
  __shared__ float wbuf[CH][NH];
  __shared__ int slist[CH];
  if (lane < NH) { ad[lane] = att[n * 20 + 10 + lane]; ssum[lane] = 0.f; }
  const int s0 = lane, s1 = 64 + lane;
  const bool a1 = s1 < 100;
  int hA0 = min((s0 * 8) / FO, NH - 1), bb0 = FO * ((s0 * 8) / FO + 1) - s0 * 8;
  int hB0 = min((s0 * 8) / FO + 1, NH - 1);
  int hA1 = min((s1 * 8) / FO, NH - 1), bb1 = FO * ((s1 * 8) / FO + 1) - s1 * 8;
  int hB1 = min((s1 * 8) / FO + 1, NH - 1);
  float acc0[8], acc1[8];
#pragma unroll
  for (int j = 0; j < 8; ++j) { acc0[j] = 0.f; acc1[j] = 0.f; }
  __syncthreads();

  for (int e0 = 0; e0 < deg; e0 += CH) {
    int ce = min(CH, deg - e0);
    for (int idx = lane; idx < ce * NH; idx += 64) {
      int e = idx / NH, hd = idx - e * NH;
      int s = csr_src[o0 + e0 + e];
      float l = att[s * 20 + hd] + ad[hd];
      l = l > 0.f ? l : 0.2f * l;
      float w = __expf(l);
      wbuf[e][hd] = w;
      atomicAdd(&ssum[hd], w);
    }
    for (int idx = lane; idx < ce; idx += 64) slist[idx] = csr_src[o0 + e0 + idx];
    __syncthreads();
    for (int e = 0; e < ce; ++e) {
      const u16* hs = h + (size_t)slist[e] * 800;
      u16x8 v0 = *(const u16x8*)(hs + s0 * 8);
      float wA0 = wbuf[e][hA0], wB0 = wbuf[e][hB0];
#pragma unroll
      for (int j = 0; j < 8; ++j)
        acc0[j] += (j < bb0 ? wA0 : wB0) * b2f(v0[j]);
      if (a1) {
        u16x8 v1 = *(const u16x8*)(hs + s1 * 8);
        float wA1 = wbuf[e][hA1], wB1 = wbuf[e][hB1];
#pragma unroll
        for (int j = 0; j < 8; ++j)
          acc1[j] += (j < bb1 ? wA1 : wB1) * b2f(v1[j]);
      }
    }
    __syncthreads();
  }
  float iA0 = 1.f / (ssum[hA0] + 1e-16f), iB0 = 1.f / (ssum[hB0] + 1e-16f);
  u16x8 o0v;
#pragma unroll
  for (int j = 0; j < 8; ++j) {
    int f = s0 * 8 + j;
    float v = acc0[j] * (j < bb0 ? iA0 : iB0) + gat_bias[f];
    o0v[j] = f2b(v > 0.f ? v : 0.f);
  }
  *(u16x8*)(x1b + (size_t)n * 800 + s0 * 8) = o0v;
  if (a1) {
    float iA1 = 1.f / (ssum[hA1] + 1e-16f), iB1 = 1.f / (ssum[hB1] + 1e-16f);
    u16x8 o1v;
#pragma unroll
    for (int j = 0; j < 8; ++j) {
      int f = s1 * 8 + j;
      if (f < HID) {
        float v = acc1[j] * (j < bb1 ? iA1 : iB1) + gat_bias[f];
        o1v[j] = f2b(v > 0.f ? v : 0.f);
      } else o1v[j] = 0;
    }
    *(u16x8*)(x1b + (size_t)n * 800 + s1 * 8) = o1v;
  }
}

// ---------------- GCN gather + per-graph pooling, u16x8 gather ----------------
__global__ __launch_bounds__(256) void gcn_pool(const u16* __restrict__ h2,
    const int* __restrict__ offs, const int* __restrict__ csr_src,
    const float* __restrict__ dinv, const float* __restrict__ gcn_bias,
    const int* __restrict__ batch, int N, u16* __restrict__ gb)
{
  int gi = blockIdx.x, tid = threadIdx.x;
  int grp = tid >> 6, lane = tid & 63;
  __shared__ int se[2];
  __shared__ float smx[HID];
  __shared__ float ssm[HID];
  for (int f = tid; f < HID; f += 256) { smx[f] = 0.f; ssm[f] = 0.f; }
  if (tid < 2) {
    int target = gi + tid;
    int lo = 0, hi = N;
    while (lo < hi) { int mid = (lo + hi) >> 1; if (batch[mid] < target) lo = mid + 1; else hi = mid; }
    se[tid] = lo;
  }
  __syncthreads();
  int s = se[0], e = se[1];
  const int s0 = lane, s1 = 64 + lane;
  const bool a1 = s1 < 100;
  float bv0[8], bv1[8];
#pragma unroll
  for (int j = 0; j < 8; ++j) {
    int f0 = s0 * 8 + j, f1 = s1 * 8 + j;
    bv0[j] = gcn_bias[f0];
    bv1[j] = (a1 && f1 < HID) ? gcn_bias[f1] : 0.f;
  }
  float mx0[8], sm0[8], mx1[8], sm1[8];
#pragma unroll
  for (int j = 0; j < 8; ++j) { mx0[j] = 0.f; sm0[j] = 0.f; mx1[j] = 0.f; sm1[j] = 0.f; }

  for (int n = s + grp; n < e; n += 4) {
    int o0 = offs[n], deg = offs[n + 1] - o0;
    float dn = dinv[n];
    float acc0[8], acc1[8];
#pragma unroll
    for (int j = 0; j < 8; ++j) { acc0[j] = 0.f; acc1[j] = 0.f; }
    for (int ed = 0; ed < deg; ++ed) {
      int src = csr_src[o0 + ed];
      float c = dn * dinv[src];
      const u16* hr = h2 + (size_t)src * 800;
      u16x8 v0 = *(const u16x8*)(hr + s0 * 8);
#pragma unroll
      for (int j = 0; j < 8; ++j) acc0[j] += c * b2f(v0[j]);
      if (a1) {
        u16x8 v1 = *(const u16x8*)(hr + s1 * 8);
#pragma unroll
        for (int j = 0; j < 8; ++j) acc1[j] += c * b2f(v1[j]);
      }
    }
#pragma unroll
    for (int j = 0; j < 8; ++j) {
      float v = acc0[j] + bv0[j];
      v = v > 0.f ? v : 0.f;
      mx0[j] = fmaxf(mx0[j], v); sm0[j] += v;
      float w = acc1[j] + bv1[j];
      w = w > 0.f ? w : 0.f;
      mx1[j] = fmaxf(mx1[j], w); sm1[j] += w;
    }
  }
#pragma unroll
  for (int j = 0; j < 8; ++j) {
    int f0 = s0 * 8 + j;
    atomicMax((unsigned*)&smx[f0], __float_as_uint(mx0[j]));
    atomicAdd(&ssm[f0], sm0[j]);
    int f1 = s1 * 8 + j;
    if (a1 && f1 < HID) {
      atomicMax((unsigned*)&smx[f1], __float_as_uint(mx1[j]));
      atomicAdd(&ssm[f1], sm1[j]);
    }
  }
  __syncthreads();
  float inv = 1.f / fmaxf((float)(e - s), 1.f);
  for (int f = tid; f < HID; f += 256) {
    gb[(size_t)gi * 1568 + f] = f2b(smx[f]);
    gb[(size_t)gi * 1568 + HID + f] = f2b(ssm[f] * inv);
  }
  if (tid < 8) gb[(size_t)gi * 1568 + 1560 + tid] = 0;
}

// ---------------- protein branch ----------------
__global__ __launch_bounds__(256) void build_ind(const int* __restrict__ tgt,
    u16* __restrict__ Ind)
{
  int b = blockIdx.x, tid = threadIdx.x;
  __shared__ unsigned char tl[1000];
  for (int i = tid; i < 1000; i += 256) tl[i] = (unsigned char)tgt[b * 1000 + i];
  __syncthreads();
  u16* out = Ind + (size_t)b * 26 * 1024;
  for (int ci = tid; ci < 26 * 128; ci += 256) {
    int v = ci >> 7, c0 = (ci & 127) << 3;
    u16x8 w;
#pragma unroll
    for (int j = 0; j < 8; ++j) {
      int c = c0 + j;
      w[j] = (c < 1000 && tl[c] == v) ? (u16)0x3F80 : (u16)0;
    }
    *(u16x8*)(out + v * 1024 + c0) = w;
  }
}

__global__ __launch_bounds__(256) void conv_xt(const u16* __restrict__ Aall,
    const float* __restrict__ embed, const float* __restrict__ cbias,
    u16* __restrict__ out)
{
  int b = blockIdx.x, tid = threadIdx.x;
  __shared__ __align__(16) float Al[6656];
  __shared__ __align__(16) float el[3360];
  const u16* Ab = Aall + (size_t)b * 6656;
  for (int i = tid; i < 6656; i += 256) Al[i] = b2f(Ab[i]);
  for (int i = tid; i < 3328; i += 256) el[i] = embed[i];
  if (tid < 32) el[3328 + tid] = 0.f;
  __syncthreads();
  for (int grp = tid; grp < 512; grp += 256) {
    int o = grp >> 4;
    int l0 = (grp & 15) << 3;
    float cb = cbias[o];
    float acc[8];
#pragma unroll
    for (int j = 0; j < 8; ++j) acc[j] = cb;
    for (int v = 0; v < 26; ++v) {
      const float* ap = &Al[v * 256 + (o << 3)];
      f32x4 a0 = *(const f32x4*)ap;
      f32x4 a1 = *(const f32x4*)(ap + 4);
      const float* ep = &el[v * 128 + l0];
      f32x4 e0 = *(const f32x4*)ep;
      f32x4 e1 = *(const f32x4*)(ep + 4);
      f32x4 e2 = *(const f32x4*)(ep + 8);
      f32x4 e3 = *(const f32x4*)(ep + 12);
      float a[8] = { a0[0], a0[1], a0[2], a0[3], a1[0], a1[1], a1[2], a1[3] };
      float e[16] = { e0[0], e0[1], e0[2], e0[3], e1[0], e1[1], e1[2], e1[3],
                      e2[0], e2[1], e2[2], e2[3], e3[0], e3[1], e3[2], e3[3] };
#pragma unroll
      for (int k = 0; k < 8; ++k)
#pragma unroll
        for (int j = 0; j < 8; ++j) acc[j] += a[k] * e[k + j];
    }
    int base = o * 121 + l0;
#pragma unroll
    for (int j = 0; j < 8; ++j)
      if (l0 + j < 121) out[(size_t)b * 3872 + base + j] = f2b(acc[j]);
  }
}

// ---------------- final row-dot (bf16 input) ----------------
__global__ __launch_bounds__(256) void final_out(const u16* __restrict__ z2,
    const float* __restrict__ W, const float* __restrict__ bias, float* __restrict__ out)
{
  int row = blockIdx.x * 4 + (threadIdx.x >> 6);
  int lane = threadIdx.x & 63;
  const u16* zr = z2 + (size_t)row * 512;
  float s = 0.f;
  for (int i = lane; i < 512; i += 64) s += b2f(zr[i]) * W[i];
#pragma unroll
  for (int off = 32; off > 0; off >>= 1) s += __shfl_down(s, off, 64);
  if (lane == 0) out[row] = s + bias[0];
}

// ---------------- launch ----------------
extern "C" void kernel_launch(void* const* d_in, const int* in_sizes, int n_in,
                              void* d_out, int out_size, void* d_ws, size_t ws_size,
                              hipStream_t stream)
{
  const float* x        = (const float*)d_in[0];
  const int*   ei       = (const int*)d_in[1];
  const int*   batch    = (const int*)d_in[2];
  const int*   tgt      = (const int*)d_in[3];
  const float* gat_W    = (const float*)d_in[4];
  const float* att_src  = (const float*)d_in[5];
  const float* att_dst  = (const float*)d_in[6];
  const float* gat_bias = (const float*)d_in[7];
  const float* gcn_W    = (const float*)d_in[8];
  const float* gcn_bias = (const float*)d_in[9];
  const float* fcg1_W   = (const float*)d_in[10];
  const float* fcg1_b   = (const float*)d_in[11];
  const float* fcg2_W   = (const float*)d_in[12];
  const float* fcg2_b   = (const float*)d_in[13];
  const float* embed    = (const float*)d_in[14];
  const float* convW    = (const float*)d_in[15];
  const float* convb    = (const float*)d_in[16];
  const float* fc1xt_W  = (const float*)d_in[17];
  const float* fc1xt_b  = (const float*)d_in[18];
  const float* fc1_W    = (const float*)d_in[19];
  const float* fc1_b    = (const float*)d_in[20];
  const float* fc2_W    = (const float*)d_in[21];
  const float* fc2_b    = (const float*)d_in[22];
  const float* out_W    = (const float*)d_in[23];
  const float* out_b    = (const float*)d_in[24];

  const int N = in_sizes[0] / FO;      // 40960
  const int E = in_sizes[1] / 2;       // 163840
  const int B = in_sizes[3] / 1000;    // 1024
  const int ET = E + N;

  char* ws = (char*)d_ws;
  size_t off = 0;
  auto alloc = [&](size_t bytes) -> char* {
    char* p = ws + off;
    off = (off + bytes + 255) & ~(size_t)255;
    return p;
  };
  float* buf0  = (float*)alloc((size_t)N * HID * 4);   // h/h2 -> Ind/A/conv + f32 scratch
  float* buf1  = (float*)alloc((size_t)N * 800 * 2);   // xb -> x1b -> head scratch
  u16*   wt1   = (u16*)alloc((size_t)896 * 96 * 2);
  u16*   wt2   = (u16*)alloc((size_t)896 * 800 * 2);
  u16*   wtg1  = (u16*)alloc((size_t)1536 * 1568 * 2);
  u16*   wtg2  = (u16*)alloc((size_t)128 * 1504 * 2);
  u16*   wtxt  = (u16*)alloc((size_t)128 * 3872 * 2);
  u16*   wtf1  = (u16*)alloc((size_t)1024 * 256 * 2);
  u16*   wtf2  = (u16*)alloc((size_t)512 * 1024 * 2);
  u16*   wtc   = (u16*)alloc((size_t)256 * 1024 * 2);
  float* att   = (float*)alloc((size_t)N * 20 * 4);
  int*   cnt   = (int*)alloc((size_t)N * 4);
  int*   offs  = (int*)alloc((size_t)(N + 1) * 4);
  int*   fillp = (int*)alloc((size_t)N * 4);
  int*   csr   = (int*)alloc((size_t)ET * 4);
  float* dinv  = (float*)alloc((size_t)N * 4);
  u16*   gb    = (u16*)alloc((size_t)B * 1568 * 2);

  u16*   xb    = (u16*)buf1;
  u16*   x1b   = (u16*)buf1;
  u16*   hb    = (u16*)buf0;
  u16*   Ind      = (u16*)buf0;                         // [26624][1024]
  u16*   Ab       = Ind + (size_t)26624 * 1024;         // [26624][256]
  u16*   convflat = Ab + (size_t)26624 * 256;           // [1024][3872]
  float* g1f = (float*)(convflat + (size_t)1024 * 3872);
  float* xtf = g1f + (size_t)1024 * 1500;
  float* g2f = xtf + (size_t)1024 * 128;
  float* z1f = g2f + (size_t)1024 * 128;
  float* z2f = z1f + (size_t)1024 * 1024;
  size_t skBytes = ((size_t)1024 * (1500 + 128 + 128 + 1024 + 512)) * 4;
  u16* g1b = (u16*)buf1;                     // [1024][1504]
  u16* xcb = g1b + (size_t)1024 * 1504;      // [1024][256] (g2 | xt)
  u16* z1b = xcb + (size_t)1024 * 256;       // [1024][1024]
  u16* z2b = z1b + (size_t)1024 * 1024;      // [1024][512]

  hipMemsetAsync(cnt, 0, (size_t)N * 4, stream);
  hipMemsetAsync(fillp, 0, (size_t)N * 4, stream);

  // conversions + attention fold (tiled transposes)
  conv_x_bf16<<<(N * 96 + 255) / 256, 256, 0, stream>>>(x, xb, N);
  conv_wT_bf16<<<dim3(896 / 32, 96 / 32), 256, 0, stream>>>(gat_W, wt1, FO, HID, 96, 896);
  fold_att<<<20, 96, 0, stream>>>(gat_W, att_src, att_dst, wt1);
  conv_wT_bf16<<<dim3(896 / 32, 800 / 32), 256, 0, stream>>>(gcn_W, wt2, HID, HID, 800, 896);
  conv_wT_bf16<<<dim3(1536 / 32, 1568 / 32), 256, 0, stream>>>(fcg1_W, wtg1, 1560, 1500, 1568, 1536);
  conv_wT_bf16<<<dim3(128 / 32, 1504 / 32), 256, 0, stream>>>(fcg2_W, wtg2, 1500, 128, 1504, 128);
  conv_wT_bf16<<<dim3(128 / 32, 3872 / 32), 256, 0, stream>>>(fc1xt_W, wtxt, 3872, 128, 3872, 128);
  conv_wT_bf16<<<dim3(1024 / 32, 256 / 32), 256, 0, stream>>>(fc1_W, wtf1, 256, 1024, 256, 1024);
  conv_wT_bf16<<<dim3(512 / 32, 1024 / 32), 256, 0, stream>>>(fc2_W, wtf2, 1024, 512, 1024, 512);
  conv_w2T<<<(256 * 1024 + 255) / 256, 256, 0, stream>>>(convW, wtc);

  // h = x @ gat_W -> hb bf16 [N][800]; att dots -> att f32
  gemm_mfma<false, false><<<dim3(7, N / 128), 256, 0, stream>>>(
      xb, wt1, hb, att, nullptr, N, HID, 96, 800);

  int egrid = (ET + 255) / 256;
  count_dst<<<egrid, 256, 0, stream>>>(ei, E, N, cnt);
  scan_dinv<<<1, 1024, 0, stream>>>(cnt, offs, dinv, N);
  fill_csr<<<egrid, 256, 0, stream>>>(ei, E, N, offs, fillp, csr);

  gat_gather<<<N, 64, 0, stream>>>(hb, att, offs, csr, gat_bias, x1b);

  // h2 = x1 @ gcn_W -> hb bf16 [N][800]
  gemm_mfma<false, false><<<dim3(7, N / 128), 256, 0, stream>>>(
      x1b, wt2, hb, nullptr, nullptr, N, HID, 800, 800);

  // fused GCN gather + per-graph max/mean pool -> gb bf16 [B][1568]
  gcn_pool<<<B, 256, 0, stream>>>(hb, offs, csr, dinv, gcn_bias, batch, N, gb);

  // protein branch: A = Ind @ W2 via MFMA, then tiny conv
  build_ind<<<B, 256, 0, stream>>>(tgt, Ind);
  gemm_mfma<false, false><<<dim3(2, 26624 / 128), 256, 0, stream>>>(
      Ind, wtc, Ab, nullptr, nullptr, 26624, 256, 1024, 256);
  conv_xt<<<B, 256, 0, stream>>>(Ab, embed, convb, convflat);

  // ---- head: split-K MFMA GEMMs (fp32 atomics) + bias/act epilogues ----
  hipMemsetAsync(g1f, 0, skBytes, stream);

  gemm_sk<<<dim3(1, B / 128, 16), 256, 0, stream>>>(convflat, wtxt, xtf, B, 128, 3872, 256);
  bias_act_pad<false><<<(B * 128 + 255) / 256, 256, 0, stream>>>(
      xtf, fc1xt_b, xcb + 128, B, 128, 128, 256);

  gemm_sk<<<dim3(12, B / 128, 2), 256, 0, stream>>>(gb, wtg1, g1f, B, 1500, 1568, 800);
  bias_act_pad<true><<<(B * 1504 + 255) / 256, 256, 0, stream>>>(
      g1f, fcg1_b, g1b, B, 1500, 1504, 1504);

  gemm_sk<<<dim3(1, B / 128, 8), 256, 0, stream>>>(g1b, wtg2, g2f, B, 128, 1504, 192);
  bias_act_pad<false><<<(B * 128 + 255) / 256, 256, 0, stream>>>(
      g2f, fcg2_b, xcb, B, 128, 128, 256);

  gemm_sk<<<dim3(8, B / 128, 2), 256, 0, stream>>>(xcb, wtf1, z1f, B, 1024, 256, 128);
  bias_act_pad<true><<<(B * 1024 + 255) / 256, 256, 0, stream>>>(
      z1f, fc1_b, z1b, B, 1024, 1024, 1024);

  gemm_sk<<<dim3(4, B / 128, 4), 256, 0, stream>>>(z1b, wtf2, z2f, B, 512, 1024, 256);
  bias_act_pad<true><<<(B * 512 + 255) / 256, 256, 0, stream>>>(
      z2f, fc2_b, z2b, B, 512, 512, 512);

  final_out<<<B / 4, 256, 0, stream>>>(z2b, out_W, out_b, (float*)d_out);
}

// Round 14
// 596.449 us; speedup vs baseline: 8.0671x; 1.0251x over previous
//
#include <hip/hip_runtime.h>

typedef __attribute__((ext_vector_type(4))) float f32x4;
typedef __attribute__((ext_vector_type(8))) short bf16x8;
typedef __attribute__((ext_vector_type(8))) unsigned short u16x8;
typedef unsigned short u16;

#define HID 780
#define NH 10
#define FO 78

__device__ inline u16 f2b(float f) {  // fp32 -> bf16 RNE
  unsigned u = __float_as_uint(f);
  unsigned r = (u + 0x7fff + ((u >> 16) & 1)) >> 16;
  return (u16)r;
}
__device__ inline float b2f(u16 b) { return __uint_as_float(((unsigned)b) << 16); }

// async global->LDS, 16B per lane; lds dest = (wave-uniform base) + lane*16
__device__ inline void gld16(const u16* g, u16* l) {
  __builtin_amdgcn_global_load_lds(
      (const __attribute__((address_space(1))) unsigned int*)g,
      (__attribute__((address_space(3))) unsigned int*)l, 16, 0, 0);
}

// XCD-chunked swizzle of the full linear block id (bijective when nwg%8==0).
__device__ inline int swz_bid() {
  int gx = gridDim.x, gy = gridDim.y, gz = gridDim.z;
  int nwg = gx * gy * gz;
  int bid = (blockIdx.z * gy + blockIdx.y) * gx + blockIdx.x;
  if ((nwg & 7) == 0) bid = (bid & 7) * (nwg >> 3) + (bid >> 3);
  return bid;
}

// ---------------- bf16 MFMA GEMM, bf16 C out, 2-phase pipelined ----------------
// LDS double-buffered linear [128][32] u16; staged via global_load_lds width=16.
template<bool BIAS, bool RELU>
__global__ __launch_bounds__(256) void gemm_mfma(const u16* __restrict__ A,
    const u16* __restrict__ BT, u16* __restrict__ C, float* __restrict__ att_out,
    const float* __restrict__ bias, int M, int Ncols, int KP, int ldc)
{
  __shared__ u16 As[2][128 * 32];
  __shared__ u16 Bs[2][128 * 32];
  const int tid = threadIdx.x;
  int t = swz_bid();
  const int bx = t % gridDim.x, by = t / gridDim.x;
  const int row0 = by << 7, col0 = bx << 7;
  const int l = tid & 63, wid = tid >> 6;
  const int wr = wid >> 1, wc = wid & 1;
  const int lr = l & 15, lk = l >> 4;
  // per-lane staging addresses (two 256-element chunks)
  const int c0 = (wid << 6) + l, c1 = 256 + c0;
  const u16* gA0 = A + (size_t)(row0 + (c0 >> 2)) * KP + ((c0 & 3) << 3);
  const u16* gA1 = A + (size_t)(row0 + (c1 >> 2)) * KP + ((c1 & 3) << 3);
  const u16* gB0 = BT + (size_t)(col0 + (c0 >> 2)) * KP + ((c0 & 3) << 3);
  const u16* gB1 = BT + (size_t)(col0 + (c1 >> 2)) * KP + ((c1 & 3) << 3);
  const int d0 = (wid << 6) << 3, d1 = (256 + (wid << 6)) << 3;  // wave-uniform LDS dest

  f32x4 acc[4][4];
#pragma unroll
  for (int i = 0; i < 4; ++i)
#pragma unroll
    for (int j = 0; j < 4; ++j) acc[i][j] = (f32x4){0.f, 0.f, 0.f, 0.f};

  // prologue: stage tile 0
  gld16(gA0, &As[0][d0]); gld16(gA1, &As[0][d1]);
  gld16(gB0, &Bs[0][d0]); gld16(gB1, &Bs[0][d1]);
  __syncthreads();

  int cur = 0;
  for (int k0 = 0; k0 < KP; k0 += 32) {
    if (k0 + 32 < KP) {
      int nx = cur ^ 1, kn = k0 + 32;
      gld16(gA0 + kn, &As[nx][d0]); gld16(gA1 + kn, &As[nx][d1]);
      gld16(gB0 + kn, &Bs[nx][d0]); gld16(gB1 + kn, &Bs[nx][d1]);
    }
    const u16* Ac = As[cur];
    const u16* Bc = Bs[cur];
    bf16x8 af[4], bfr[4];
#pragma unroll
    for (int fm = 0; fm < 4; ++fm)
      af[fm] = *(const bf16x8*)&Ac[((wr * 64 + fm * 16 + lr) << 5) + (lk << 3)];
#pragma unroll
    for (int fn = 0; fn < 4; ++fn)
      bfr[fn] = *(const bf16x8*)&Bc[((wc * 64 + fn * 16 + lr) << 5) + (lk << 3)];
#pragma unroll
    for (int fm = 0; fm < 4; ++fm)
#pragma unroll
      for (int fn = 0; fn < 4; ++fn)
        acc[fm][fn] = __builtin_amdgcn_mfma_f32_16x16x32_bf16(af[fm], bfr[fn], acc[fm][fn], 0, 0, 0);
    __syncthreads();   // drains vmcnt -> next tile resident
    cur ^= 1;
  }
#pragma unroll
  for (int fm = 0; fm < 4; ++fm)
#pragma unroll
    for (int fn = 0; fn < 4; ++fn) {
      int col = col0 + wc * 64 + fn * 16 + lr;
      f32x4 v = acc[fm][fn];
      int rbase = row0 + wr * 64 + fm * 16 + lk * 4;
      if (col < Ncols) {
        float bb = BIAS ? bias[col] : 0.f;
#pragma unroll
        for (int j = 0; j < 4; ++j) {
          float vv = v[j] + bb;
          if (RELU) vv = vv > 0.f ? vv : 0.f;
          C[(size_t)(rbase + j) * ldc + col] = f2b(vv);
        }
      } else {
        if (att_out != nullptr && col < Ncols + 20) {
          int c = col - Ncols;
#pragma unroll
          for (int j = 0; j < 4; ++j)
            att_out[(size_t)(rbase + j) * 20 + c] = v[j];
        }
        if (col < ldc) {
#pragma unroll
          for (int j = 0; j < 4; ++j) C[(size_t)(rbase + j) * ldc + col] = 0;
        }
      }
    }
}

// ---------------- split-K bf16 MFMA GEMM, fp32 atomic partials, 2-phase ----------------
__global__ __launch_bounds__(256) void gemm_sk(const u16* __restrict__ A,
    const u16* __restrict__ BT, float* __restrict__ C,
    int M, int Ncols, int KP, int kchunk)
{
  __shared__ u16 As[2][128 * 32];
  __shared__ u16 Bs[2][128 * 32];
  const int tid = threadIdx.x;
  int t = swz_bid();
  const int bx = t % gridDim.x;
  const int by = (t / gridDim.x) % gridDim.y;
  const int bz = t / (gridDim.x * gridDim.y);
  const int row0 = by << 7, col0 = bx << 7;
  const int kbeg = bz * kchunk;
  const int kend = min(KP, kbeg + kchunk);
  const int l = tid & 63, wid = tid >> 6;
  const int wr = wid >> 1, wc = wid & 1;
  const int lr = l & 15, lk = l >> 4;
  const int c0 = (wid << 6) + l, c1 = 256 + c0;
  const u16* gA0 = A + (size_t)(row0 + (c0 >> 2)) * KP + ((c0 & 3) << 3) + kbeg;
  const u16* gA1 = A + (size_t)(row0 + (c1 >> 2)) * KP + ((c1 & 3) << 3) + kbeg;
  const u16* gB0 = BT + (size_t)(col0 + (c0 >> 2)) * KP + ((c0 & 3) << 3) + kbeg;
  const u16* gB1 = BT + (size_t)(col0 + (c1 >> 2)) * KP + ((c1 & 3) << 3) + kbeg;
  const int d0 = (wid << 6) << 3, d1 = (256 + (wid << 6)) << 3;

  f32x4 acc[4][4];
#pragma unroll
  for (int i = 0; i < 4; ++i)
#pragma unroll
    for (int j = 0; j < 4; ++j) acc[i][j] = (f32x4){0.f, 0.f, 0.f, 0.f};

  gld16(gA0, &As[0][d0]); gld16(gA1, &As[0][d1]);
  gld16(gB0, &Bs[0][d0]); gld16(gB1, &Bs[0][d1]);
  __syncthreads();

  int cur = 0;
  for (int k0 = kbeg; k0 < kend; k0 += 32) {
    if (k0 + 32 < kend) {
      int nx = cur ^ 1, kn = k0 + 32 - kbeg;
      gld16(gA0 + kn, &As[nx][d0]); gld16(gA1 + kn, &As[nx][d1]);
      gld16(gB0 + kn, &Bs[nx][d0]); gld16(gB1 + kn, &Bs[nx][d1]);
    }
    const u16* Ac = As[cur];
    const u16* Bc = Bs[cur];
    bf16x8 af[4], bfr[4];
#pragma unroll
    for (int fm = 0; fm < 4; ++fm)
      af[fm] = *(const bf16x8*)&Ac[((wr * 64 + fm * 16 + lr) << 5) + (lk << 3)];
#pragma unroll
    for (int fn = 0; fn < 4; ++fn)
      bfr[fn] = *(const bf16x8*)&Bc[((wc * 64 + fn * 16 + lr) << 5) + (lk << 3)];
#pragma unroll
    for (int fm = 0; fm < 4; ++fm)
#pragma unroll
      for (int fn = 0; fn < 4; ++fn)
        acc[fm][fn] = __builtin_amdgcn_mfma_f32_16x16x32_bf16(af[fm], bfr[fn], acc[fm][fn], 0, 0, 0);
    __syncthreads();
    cur ^= 1;
  }
#pragma unroll
  for (int fm = 0; fm < 4; ++fm)
#pragma unroll
    for (int fn = 0; fn < 4; ++fn) {
      int col = col0 + wc * 64 + fn * 16 + lr;
      if (col < Ncols) {
        f32x4 v = acc[fm][fn];
        int rbase = row0 + wr * 64 + fm * 16 + lk * 4;
#pragma unroll
        for (int j = 0; j < 4; ++j)
          atomicAdd(&C[(size_t)(rbase + j) * Ncols + col], v[j]);
      }
    }
}

// fp32 compact [M][N] -> bf16 [M][ldco] with bias/relu, zero-pad cols [N,padTo)
template<bool RELU>
__global__ void bias_act_pad(const float* __restrict__ Cf,
    const float* __restrict__ bias, u16* __restrict__ out,
    int M, int N, int padTo, int ldco)
{
  int idx = blockIdx.x * 256 + threadIdx.x;
  if (idx >= M * padTo) return;
  int r = idx / padTo, c = idx - r * padTo;
  if (c < N) {
    float v = Cf[(size_t)r * N + c] + bias[c];
    if (RELU) v = v > 0.f ? v : 0.f;
    out[(size_t)r * ldco + c] = f2b(v);
  } else {
    out[(size_t)r * ldco + c] = 0;
  }
}

// ---------------- conversions ----------------
__global__ void conv_x_bf16(const float* __restrict__ x, u16* __restrict__ xb, int M)
{
  int idx = blockIdx.x * 256 + threadIdx.x;
  if (idx >= M * 96) return;
  int r = idx / 96, c = idx - r * 96;
  xb[idx] = (c < FO) ? f2b(x[(size_t)r * FO + c]) : (u16)0;
}

// LDS-tiled transpose: WT[n][k] (NP x KP) = bf16(W[k][n]), zero-padded.
__global__ void conv_wT_bf16(const float* __restrict__ W, u16* __restrict__ WT,
                             int K, int N, int KP, int NP)
{
  __shared__ u16 tbuf[32][33];
  int tn0 = blockIdx.x << 5, tk0 = blockIdx.y << 5;
  int lx = threadIdx.x & 31, ly = threadIdx.x >> 5;
#pragma unroll
  for (int r = 0; r < 32; r += 8) {
    int k = tk0 + ly + r, n = tn0 + lx;
    tbuf[ly + r][lx] = (k < K && n < N) ? f2b(W[(size_t)k * N + n]) : (u16)0;
  }
  __syncthreads();
#pragma unroll
  for (int r = 0; r < 32; r += 8) {
    int n = tn0 + ly + r, k = tk0 + lx;
    if (n < NP && k < KP) WT[(size_t)n * KP + k] = tbuf[lx][ly + r];
  }
}

// W2T[(o*8+k)][c] = bf16(convW[o,c,k]), [256][1024] zero-padded
__global__ void conv_w2T(const float* __restrict__ W, u16* __restrict__ WT)
{
  int idx = blockIdx.x * 256 + threadIdx.x;
  if (idx >= 256 * 1024) return;
  int ok = idx >> 10, c = idx & 1023;
  int o = ok >> 3, k = ok & 7;
  WT[idx] = (c < 1000) ? f2b(W[(size_t)o * 8000 + c * 8 + k]) : (u16)0;
}

// fold attention vectors into wt1 rows 780..799
__global__ void fold_att(const float* __restrict__ gat_W,
    const float* __restrict__ asv, const float* __restrict__ adv,
    u16* __restrict__ wt1)
{
  int j = blockIdx.x;
  int k = threadIdx.x;
  if (k >= 96) return;
  float s = 0.f;
  if (k < FO) {
    int h = (j < 10) ? j : j - 10;
    const float* av = ((j < 10) ? asv : adv) + h * FO;
    const float* wr = gat_W + (size_t)k * HID + h * FO;
    for (int f = 0; f < FO; ++f) s += wr[f] * av[f];
  }
  wt1[(size_t)(HID + j) * 96 + k] = f2b(s);
}

// ---------------- CSR build ----------------
__global__ void count_dst(const int* __restrict__ ei, int E, int N, int* __restrict__ cnt)
{
  int e = blockIdx.x * 256 + threadIdx.x;
  if (e >= E + N) return;
  int dst = (e < E) ? ei[E + e] : (e - E);
  atomicAdd(&cnt[dst], 1);
}

__global__ __launch_bounds__(1024) void scan_dinv(const int* __restrict__ cnt,
    int* __restrict__ offs, float* __restrict__ dinv, int N)
{
  __shared__ int part[1024];
  int tid = threadIdx.x;
  int chunk = (N + 1023) >> 10;
  int b0 = tid * chunk, b1 = min(b0 + chunk, N);
  int s = 0;
  for (int i = b0; i < b1; ++i) s += cnt[i];
  part[tid] = s;
  __syncthreads();
  for (int off = 1; off < 1024; off <<= 1) {
    int v = part[tid];
    int add = (tid >= off) ? part[tid - off] : 0;
    __syncthreads();
    part[tid] = v + add;
    __syncthreads();
  }
  int run = (tid > 0) ? part[tid - 1] : 0;
  for (int i = b0; i < b1; ++i) {
    int c = cnt[i];
    offs[i] = run;
    dinv[i] = c > 0 ? rsqrtf((float)c) : 0.f;
    run += c;
  }
  if (tid == 1023) offs[N] = run;
}

__global__ void fill_csr(const int* __restrict__ ei, int E, int N,
    const int* __restrict__ offs, int* __restrict__ fillpos, int* __restrict__ csr_src)
{
  int e = blockIdx.x * 256 + threadIdx.x;
  if (e >= E + N) return;
  int src, dst;
  if (e < E) { src = ei[e]; dst = ei[E + e]; }
  else { src = e - E; dst = e - E; }
  int p = offs[dst] + atomicAdd(&fillpos[dst], 1);
  csr_src[p] = src;
}

// ---------------- GAT gather: single-pass softmax, u16x8 gather ----------------
#define CH 48
__global__ __launch_bounds__(64) void gat_gather(const u16* __restrict__ h,
    const float* __restrict__ att,
    const int* __restrict__ offs, const int* __restrict__ csr_src,
    const float* __restrict__ gat_bias, u16* __restrict__ x1b)
{
  int n = blockIdx.x, lane = threadIdx.x;
  int o0 = offs[n], deg = offs[n + 1] - o0;
  __shared__ float ad[NH], ssum[NH];
  __shared__ float wbuf[CH][NH];
  __shared__ int slist[CH];
  if (lane < NH) { ad[lane] = att[n * 20 + 10 + lane]; ssum[lane] = 0.f; }
  const int s0 = lane, s1 = 64 + lane;
  const bool a1 = s1 < 100;
  int hA0 = min((s0 * 8) / FO, NH - 1), bb0 = FO * ((s0 * 8) / FO + 1) - s0 * 8;
  int hB0 = min((s0 * 8) / FO + 1, NH - 1);
  int hA1 = min((s1 * 8) / FO, NH - 1), bb1 = FO * ((s1 * 8) / FO + 1) - s1 * 8;
  int hB1 = min((s1 * 8) / FO + 1, NH - 1);
  float acc0[8], acc1[8];
#pragma unroll
  for (int j = 0; j < 8; ++j) { acc0[j] = 0.f; acc1[j] = 0.f; }
  __syncthreads();

  for (int e0 = 0; e0 < deg; e0 += CH) {
    int ce = min(CH, deg - e0);
    for (int idx = lane; idx < ce * NH; idx += 64) {
      int e = idx / NH, hd = idx - e * NH;
      int s = csr_src[o0 + e0 + e];
      float l = att[s * 20 + hd] + ad[hd];
      l = l > 0.f ? l : 0.2f * l;
      float w = __expf(l);
      wbuf[e][hd] = w;
      atomicAdd(&ssum[hd], w);
    }
    for (int idx = lane; idx < ce; idx += 64) slist[idx] = csr_src[o0 + e0 + idx];
    __syncthreads();
    for (int e = 0; e < ce; ++e) {
      const u16* hs = h + (size_t)slist[e] * 800;
      u16x8 v0 = *(const u16x8*)(hs + s0 * 8);
      float wA0 = wbuf[e][hA0], wB0 = wbuf[e][hB0];
#pragma unroll
      for (int j = 0; j < 8; ++j)
        acc0[j] += (j < bb0 ? wA0 : wB0) * b2f(v0[j]);
      if (a1) {
        u16x8 v1 = *(const u16x8*)(hs + s1 * 8);
        float wA1 = wbuf[e][hA1], wB1 = wbuf[e][hB1];
#pragma unroll
        for (int j = 0; j < 8; ++j)
          acc1[j] += (j < bb1 ? wA1 : wB1) * b2f(v1[j]);
      }
    }
    __syncthreads();
  }
  float iA0 = 1.f / (ssum[hA0] + 1e-16f), iB0 = 1.f / (ssum[hB0] + 1e-16f);
  u16x8 o0v;
#pragma unroll
  for (int j = 0; j < 8; ++j) {
    int f = s0 * 8 + j;
    float v = acc0[j] * (j < bb0 ? iA0 : iB0) + gat_bias[f];
    o0v[j] = f2b(v > 0.f ? v : 0.f);
  }
  *(u16x8*)(x1b + (size_t)n * 800 + s0 * 8) = o0v;
  if (a1) {
    float iA1 = 1.f / (ssum[hA1] + 1e-16f), iB1 = 1.f / (ssum[hB1] + 1e-16f);
    u16x8 o1v;
#pragma unroll
    for (int j = 0; j < 8; ++j) {
      int f = s1 * 8 + j;
      if (f < HID) {
        float v = acc1[j] * (j < bb1 ? iA1 : iB1) + gat_bias[f];
        o1v[j] = f2b(v > 0.f ? v : 0.f);
      } else o1v[j] = 0;
    }
    *(u16x8*)(x1b + (size_t)n * 800 + s1 * 8) = o1v;
  }
}

// ---------------- GCN gather + per-graph pooling, u16x8 gather ----------------
__global__ __launch_bounds__(256) void gcn_pool(const u16* __restrict__ h2,
    const int* __restrict__ offs, const int* __restrict__ csr_src,
    const float* __restrict__ dinv, const float* __restrict__ gcn_bias,
    const int* __restrict__ batch, int N, u16* __restrict__ gb)
{
  int gi = blockIdx.x, tid = threadIdx.x;
  int grp = tid >> 6, lane = tid & 63;
  __shared__ int se[2];
  __shared__ float smx[HID];
  __shared__ float ssm[HID];
  for (int f = tid; f < HID; f += 256) { smx[f] = 0.f; ssm[f] = 0.f; }
  if (tid < 2) {
    int target = gi + tid;
    int lo = 0, hi = N;
    while (lo < hi) { int mid = (lo + hi) >> 1; if (batch[mid] < target) lo = mid + 1; else hi = mid; }
    se[tid] = lo;
  }
  __syncthreads();
  int s = se[0], e = se[1];
  const int s0 = lane, s1 = 64 + lane;
  const bool a1 = s1 < 100;
  float bv0[8], bv1[8];
#pragma unroll
  for (int j = 0; j < 8; ++j) {
    int f0 = s0 * 8 + j, f1 = s1 * 8 + j;
    bv0[j] = gcn_bias[f0];
    bv1[j] = (a1 && f1 < HID) ? gcn_bias[f1] : 0.f;
  }
  float mx0[8], sm0[8], mx1[8], sm1[8];
#pragma unroll
  for (int j = 0; j < 8; ++j) { mx0[j] = 0.f; sm0[j] = 0.f; mx1[j] = 0.f; sm1[j] = 0.f; }

  for (int n = s + grp; n < e; n += 4) {
    int o0 = offs[n], deg = offs[n + 1] - o0;
    float dn = dinv[n];
    float acc0[8], acc1[8];
#pragma unroll
    for (int j = 0; j < 8; ++j) { acc0[j] = 0.f; acc1[j] = 0.f; }
    for (int ed = 0; ed < deg; ++ed) {
      int src = csr_src[o0 + ed];
      float c = dn * dinv[src];
      const u16* hr = h2 + (size_t)src * 800;
      u16x8 v0 = *(const u16x8*)(hr + s0 * 8);
#pragma unroll
      for (int j = 0; j < 8; ++j) acc0[j] += c * b2f(v0[j]);
      if (a1) {
        u16x8 v1 = *(const u16x8*)(hr + s1 * 8);
#pragma unroll
        for (int j = 0; j < 8; ++j) acc1[j] += c * b2f(v1[j]);
      }
    }
#pragma unroll
    for (int j = 0; j < 8; ++j) {
      float v = acc0[j] + bv0[j];
      v = v > 0.f ? v : 0.f;
      mx0[j] = fmaxf(mx0[j], v); sm0[j] += v;
      float w = acc1[j] + bv1[j];
      w = w > 0.f ? w : 0.f;
      mx1[j] = fmaxf(mx1[j], w); sm1[j] += w;
    }
  }
#pragma unroll
  for (int j = 0; j < 8; ++j) {
    int f0 = s0 * 8 + j;
    atomicMax((unsigned*)&smx[f0], __float_as_uint(mx0[j]));
    atomicAdd(&ssm[f0], sm0[j]);
    int f1 = s1 * 8 + j;
    if (a1 && f1 < HID) {
      atomicMax((unsigned*)&smx[f1], __float_as_uint(mx1[j]));
      atomicAdd(&ssm[f1], sm1[j]);
    }
  }
  __syncthreads();
  float inv = 1.f / fmaxf((float)(e - s), 1.f);
  for (int f = tid; f < HID; f += 256) {
    gb[(size_t)gi * 1568 + f] = f2b(smx[f]);
    gb[(size_t)gi * 1568 + HID + f] = f2b(ssm[f] * inv);
  }
  if (tid < 8) gb[(size_t)gi * 1568 + 1560 + tid] = 0;
}

// ---------------- protein branch ----------------
__global__ __launch_bounds__(256) void build_ind(const int* __restrict__ tgt,
    u16* __restrict__ Ind)
{
  int b = blockIdx.x, tid = threadIdx.x;
  __shared__ unsigned char tl[1000];
  for (int i = tid; i < 1000; i += 256) tl[i] = (unsigned char)tgt[b * 1000 + i];
  __syncthreads();
  u16* out = Ind + (size_t)b * 26 * 1024;
  for (int ci = tid; ci < 26 * 128; ci += 256) {
    int v = ci >> 7, c0 = (ci & 127) << 3;
    u16x8 w;
#pragma unroll
    for (int j = 0; j < 8; ++j) {
      int c = c0 + j;
      w[j] = (c < 1000 && tl[c] == v) ? (u16)0x3F80 : (u16)0;
    }
    *(u16x8*)(out + v * 1024 + c0) = w;
  }
}

__global__ __launch_bounds__(256) void conv_xt(const u16* __restrict__ Aall,
    const float* __restrict__ embed, const float* __restrict__ cbias,
    u16* __restrict__ out)
{
  int b = blockIdx.x, tid = threadIdx.x;
  __shared__ __align__(16) float Al[6656];
  __shared__ __align__(16) float el[3360];
  const u16* Ab = Aall + (size_t)b * 6656;
  for (int i = tid; i < 6656; i += 256) Al[i] = b2f(Ab[i]);
  for (int i = tid; i < 3328; i += 256) el[i] = embed[i];
  if (tid < 32) el[3328 + tid] = 0.f;
  __syncthreads();
  for (int grp = tid; grp < 512; grp += 256) {
    int o = grp >> 4;
    int l0 = (grp & 15) << 3;
    float cb = cbias[o];
    float acc[8];
#pragma unroll
    for (int j = 0; j < 8; ++j) acc[j] = cb;
    for (int v = 0; v < 26; ++v) {
      const float* ap = &Al[v * 256 + (o << 3)];
      f32x4 a0 = *(const f32x4*)ap;
      f32x4 a1 = *(const f32x4*)(ap + 4);
      const float* ep = &el[v * 128 + l0];
      f32x4 e0 = *(const f32x4*)ep;
      f32x4 e1 = *(const f32x4*)(ep + 4);
      f32x4 e2 = *(const f32x4*)(ep + 8);
      f32x4 e3 = *(const f32x4*)(ep + 12);
      float a[8] = { a0[0], a0[1], a0[2], a0[3], a1[0], a1[1], a1[2], a1[3] };
      float e[16] = { e0[0], e0[1], e0[2], e0[3], e1[0], e1[1], e1[2], e1[3],
                      e2[0], e2[1], e2[2], e2[3], e3[0], e3[1], e3[2], e3[3] };
#pragma unroll
      for (int k = 0; k < 8; ++k)
#pragma unroll
        for (int j = 0; j < 8; ++j) acc[j] += a[k] * e[k + j];
    }
    int base = o * 121 + l0;
#pragma unroll
    for (int j = 0; j < 8; ++j)
      if (l0 + j < 121) out[(size_t)b * 3872 + base + j] = f2b(acc[j]);
  }
}

// ---------------- final row-dot (bf16 input) ----------------
__global__ __launch_bounds__(256) void final_out(const u16* __restrict__ z2,
    const float* __restrict__ W, const float* __restrict__ bias, float* __restrict__ out)
{
  int row = blockIdx.x * 4 + (threadIdx.x >> 6);
  int lane = threadIdx.x & 63;
  const u16* zr = z2 + (size_t)row * 512;
  float s = 0.f;
  for (int i = lane; i < 512; i += 64) s += b2f(zr[i]) * W[i];
#pragma unroll
  for (int off = 32; off > 0; off >>= 1) s += __shfl_down(s, off, 64);
  if (lane == 0) out[row] = s + bias[0];
}

// ---------------- launch ----------------
extern "C" void kernel_launch(void* const* d_in, const int* in_sizes, int n_in,
                              void* d_out, int out_size, void* d_ws, size_t ws_size,
                              hipStream_t stream)
{
  const float* x        = (const float*)d_in[0];
  const int*   ei       = (const int*)d_in[1];
  const int*   batch    = (const int*)d_in[2];
  const int*   tgt      = (const int*)d_in[3];
  const float* gat_W    = (const float*)d_in[4];
  const float* att_src  = (const float*)d_in[5];
  const float* att_dst  = (const float*)d_in[6];
  const float* gat_bias = (const float*)d_in[7];
  const float* gcn_W    = (const float*)d_in[8];
  const float* gcn_bias = (const float*)d_in[9];
  const float* fcg1_W   = (const float*)d_in[10];
  const float* fcg1_b   = (const float*)d_in[11];
  const float* fcg2_W   = (const float*)d_in[12];
  const float* fcg2_b   = (const float*)d_in[13];
  const float* embed    = (const float*)d_in[14];
  const float* convW    = (const float*)d_in[15];
  const float* convb    = (const float*)d_in[16];
  const float* fc1xt_W  = (const float*)d_in[17];
  const float* fc1xt_b  = (const float*)d_in[18];
  const float* fc1_W    = (const float*)d_in[19];
  const float* fc1_b    = (const float*)d_in[20];
  const float* fc2_W    = (const float*)d_in[21];
  const float* fc2_b    = (const float*)d_in[22];
  const float* out_W    = (const float*)d_in[23];
  const float* out_b    = (const float*)d_in[24];

  const int N = in_sizes[0] / FO;      // 40960
  const int E = in_sizes[1] / 2;       // 163840
  const int B = in_sizes[3] / 1000;    // 1024
  const int ET = E + N;

  char* ws = (char*)d_ws;
  size_t off = 0;
  auto alloc = [&](size_t bytes) -> char* {
    char* p = ws + off;
    off = (off + bytes + 255) & ~(size_t)255;
    return p;
  };
  float* buf0  = (float*)alloc((size_t)N * HID * 4);   // h/h2 -> Ind/A/conv + f32 scratch
  float* buf1  = (float*)alloc((size_t)N * 800 * 2);   // xb -> x1b -> head scratch
  u16*   wt1   = (u16*)alloc((size_t)896 * 96 * 2);
  u16*   wt2   = (u16*)alloc((size_t)896 * 800 * 2);
  u16*   wtg1  = (u16*)alloc((size_t)1536 * 1568 * 2);
  u16*   wtg2  = (u16*)alloc((size_t)128 * 1504 * 2);
  u16*   wtxt  = (u16*)alloc((size_t)128 * 3872 * 2);
  u16*   wtf1  = (u16*)alloc((size_t)1024 * 256 * 2);
  u16*   wtf2  = (u16*)alloc((size_t)512 * 1024 * 2);
  u16*   wtc   = (u16*)alloc((size_t)256 * 1024 * 2);
  float* att   = (float*)alloc((size_t)N * 20 * 4);
  int*   cnt   = (int*)alloc((size_t)N * 4);
  int*   offs  = (int*)alloc((size_t)(N + 1) * 4);
  int*   fillp = (int*)alloc((size_t)N * 4);
  int*   csr   = (int*)alloc((size_t)ET * 4);
  float* dinv  = (float*)alloc((size_t)N * 4);
  u16*   gb    = (u16*)alloc((size_t)B * 1568 * 2);

  u16*   xb    = (u16*)buf1;
  u16*   x1b   = (u16*)buf1;
  u16*   hb    = (u16*)buf0;
  u16*   Ind      = (u16*)buf0;                         // [26624][1024]
  u16*   Ab       = Ind + (size_t)26624 * 1024;         // [26624][256]
  u16*   convflat = Ab + (size_t)26624 * 256;           // [1024][3872]
  float* g1f = (float*)(convflat + (size_t)1024 * 3872);
  float* xtf = g1f + (size_t)1024 * 1500;
  float* g2f = xtf + (size_t)1024 * 128;
  float* z1f = g2f + (size_t)1024 * 128;
  float* z2f = z1f + (size_t)1024 * 1024;
  size_t skBytes = ((size_t)1024 * (1500 + 128 + 128 + 1024 + 512)) * 4;
  u16* g1b = (u16*)buf1;                     // [1024][1504]
  u16* xcb = g1b + (size_t)1024 * 1504;      // [1024][256] (g2 | xt)
  u16* z1b = xcb + (size_t)1024 * 256;       // [1024][1024]
  u16* z2b = z1b + (size_t)1024 * 1024;      // [1024][512]

  hipMemsetAsync(cnt, 0, (size_t)N * 4, stream);
  hipMemsetAsync(fillp, 0, (size_t)N * 4, stream);

  // conversions + attention fold (tiled transposes)
  conv_x_bf16<<<(N * 96 + 255) / 256, 256, 0, stream>>>(x, xb, N);
  conv_wT_bf16<<<dim3(896 / 32, 96 / 32), 256, 0, stream>>>(gat_W, wt1, FO, HID, 96, 896);
  fold_att<<<20, 96, 0, stream>>>(gat_W, att_src, att_dst, wt1);
  conv_wT_bf16<<<dim3(896 / 32, 800 / 32), 256, 0, stream>>>(gcn_W, wt2, HID, HID, 800, 896);
  conv_wT_bf16<<<dim3(1536 / 32, 1568 / 32), 256, 0, stream>>>(fcg1_W, wtg1, 1560, 1500, 1568, 1536);
  conv_wT_bf16<<<dim3(128 / 32, 1504 / 32), 256, 0, stream>>>(fcg2_W, wtg2, 1500, 128, 1504, 128);
  conv_wT_bf16<<<dim3(128 / 32, 3872 / 32), 256, 0, stream>>>(fc1xt_W, wtxt, 3872, 128, 3872, 128);
  conv_wT_bf16<<<dim3(1024 / 32, 256 / 32), 256, 0, stream>>>(fc1_W, wtf1, 256, 1024, 256, 1024);
  conv_wT_bf16<<<dim3(512 / 32, 1024 / 32), 256, 0, stream>>>(fc2_W, wtf2, 1024, 512, 1024, 512);
  conv_w2T<<<(256 * 1024 + 255) / 256, 256, 0, stream>>>(convW, wtc);

  // h = x @ gat_W -> hb bf16 [N][800]; att dots -> att f32
  gemm_mfma<false, false><<<dim3(7, N / 128), 256, 0, stream>>>(
      xb, wt1, hb, att, nullptr, N, HID, 96, 800);

  int egrid = (ET + 255) / 256;
  count_dst<<<egrid, 256, 0, stream>>>(ei, E, N, cnt);
  scan_dinv<<<1, 1024, 0, stream>>>(cnt, offs, dinv, N);
  fill_csr<<<egrid, 256, 0, stream>>>(ei, E, N, offs, fillp, csr);

  gat_gather<<<N, 64, 0, stream>>>(hb, att, offs, csr, gat_bias, x1b);

  // h2 = x1 @ gcn_W -> hb bf16 [N][800]
  gemm_mfma<false, false><<<dim3(7, N / 128), 256, 0, stream>>>(
      x1b, wt2, hb, nullptr, nullptr, N, HID, 800, 800);

  // fused GCN gather + per-graph max/mean pool -> gb bf16 [B][1568]
  gcn_pool<<<B, 256, 0, stream>>>(hb, offs, csr, dinv, gcn_bias, batch, N, gb);

  // protein branch: A = Ind @ W2 via MFMA, then tiny conv
  build_ind<<<B, 256, 0, stream>>>(tgt, Ind);
  gemm_mfma<false, false><<<dim3(2, 26624 / 128), 256, 0, stream>>>(
      Ind, wtc, Ab, nullptr, nullptr, 26624, 256, 1024, 256);
  conv_xt<<<B, 256, 0, stream>>>(Ab, embed, convb, convflat);

  // ---- head: split-K MFMA GEMMs (fp32 atomics) + bias/act epilogues ----
  hipMemsetAsync(g1f, 0, skBytes, stream);

  gemm_sk<<<dim3(1, B / 128, 16), 256, 0, stream>>>(convflat, wtxt, xtf, B, 128, 3872, 256);
  bias_act_pad<false><<<(B * 128 + 255) / 256, 256, 0, stream>>>(
      xtf, fc1xt_b, xcb + 128, B, 128, 128, 256);

  gemm_sk<<<dim3(12, B / 128, 2), 256, 0, stream>>>(gb, wtg1, g1f, B, 1500, 1568, 800);
  bias_act_pad<true><<<(B * 1504 + 255) / 256, 256, 0, stream>>>(
      g1f, fcg1_b, g1b, B, 1500, 1504, 1504);

  gemm_sk<<<dim3(1, B / 128, 8), 256, 0, stream>>>(g1b, wtg2, g2f, B, 128, 1504, 192);
  bias_act_pad<false><<<(B * 128 + 255) / 256, 256, 0, stream>>>(
      g2f, fcg2_b, xcb, B, 128, 128, 256);

  gemm_sk<<<dim3(8, B / 128, 2), 256, 0, stream>>>(xcb, wtf1, z1f, B, 1024, 256, 128);
  bias_act_pad<true><<<(B * 1024 + 255) / 256, 256, 0, stream>>>(
      z1f, fc1_b, z1b, B, 1024, 1024, 1024);

  gemm_sk<<<dim3(4, B / 128, 4), 256, 0, stream>>>(z1b, wtf2, z2f, B, 512, 1024, 256);
  bias_act_pad<true><<<(B * 512 + 255) / 256, 256, 0, stream>>>(
      z2f, fc2_b, z2b, B, 512, 512, 512);

  final_out<<<B / 4, 256, 0, stream>>>(z2b, out_W, out_b, (float*)d_out);
}